// Round 3
// baseline (12395.486 us; speedup 1.0000x reference)
//
#include <hip/hip_runtime.h>
#include <math.h>

#define E_CNT 200000
typedef unsigned short bfu;

__device__ __forceinline__ float gelu_f(float x) {
    return 0.5f * x * (1.0f + erff(x * 0.70710678118654752f));
}
__device__ __forceinline__ unsigned fkey(float x) {
    unsigned u = __float_as_uint(x);
    return (u & 0x80000000u) ? ~u : (u | 0x80000000u);
}
__device__ __forceinline__ float funkey(unsigned k) {
    unsigned u = (k & 0x80000000u) ? (k ^ 0x80000000u) : ~k;
    return __uint_as_float(u);
}
__device__ __forceinline__ float bf2f(bfu u) { return __uint_as_float(((unsigned)u) << 16); }
__device__ __forceinline__ bfu f2bf(float f) {
    unsigned u = __float_as_uint(f);
    unsigned r = u + 0x7FFFu + ((u >> 16) & 1u);
    return (bfu)(r >> 16);
}

template<typename T> struct VecIO;
template<> struct VecIO<float> {
    static __device__ __forceinline__ float4 ld(const float* p) { return *(const float4*)p; }
    static __device__ __forceinline__ void st(float* p, float4 v) { *(float4*)p = v; }
    static __device__ __forceinline__ float ld1(const float* p) { return *p; }
};
template<> struct VecIO<bfu> {
    static __device__ __forceinline__ float4 ld(const bfu* p) {
        uint2 u = *(const uint2*)p;
        float4 r;
        r.x = __uint_as_float(u.x << 16);
        r.y = __uint_as_float(u.x & 0xFFFF0000u);
        r.z = __uint_as_float(u.y << 16);
        r.w = __uint_as_float(u.y & 0xFFFF0000u);
        return r;
    }
    static __device__ __forceinline__ void st(bfu* p, float4 v) {
        uint2 u;
        u.x = ((unsigned)f2bf(v.x)) | (((unsigned)f2bf(v.y)) << 16);
        u.y = ((unsigned)f2bf(v.z)) | (((unsigned)f2bf(v.w)) << 16);
        *(uint2*)p = u;
    }
    static __device__ __forceinline__ float ld1(const bfu* p) { return bf2f(*p); }
};

__global__ __launch_bounds__(256) void fill_val(float* p, int n, float v) {
    int i = blockIdx.x * 256 + threadIdx.x;
    if (i < n) p[i] = v;
}

// ---- Y[N,128] = actout( actin(X)[N,C] @ W[128,C]^T + b ) ----
// ACTIN: 0 none, 2 = x/den then gelu (den per local row*4+head). ACTOUT: 0 none, 1 relu.
template<typename TX, typename TY, int C, int ACTIN, int ACTOUT>
__global__ __launch_bounds__(256) void gemm_xwt(
    const TX* __restrict__ X, const float* __restrict__ W,
    const float* __restrict__ bias, TY* __restrict__ Y, int N,
    const float* __restrict__ den)
{
    __shared__ __align__(16) float Wt[32][132];  // [c][j]
    __shared__ __align__(16) float Xt[32][36];   // [c][r]
    const int tid = threadIdx.x;
    const int r0 = blockIdx.x * 32;
    const int rg = tid >> 5, cg = tid & 31;
    float acc[4][4];
    #pragma unroll
    for (int i = 0; i < 4; ++i)
        #pragma unroll
        for (int j = 0; j < 4; ++j) acc[i][j] = 0.f;

    for (int c0 = 0; c0 < C; c0 += 32) {
        __syncthreads();
        #pragma unroll
        for (int k = 0; k < 4; ++k) {
            int v = tid + k * 256;
            int j = v >> 3, c4 = (v & 7) * 4;
            float4 w = *(const float4*)(W + (size_t)j * C + c0 + c4);
            Wt[c4 + 0][j] = w.x; Wt[c4 + 1][j] = w.y;
            Wt[c4 + 2][j] = w.z; Wt[c4 + 3][j] = w.w;
        }
        {
            int r = tid >> 3, c4 = (tid & 7) * 4;
            int row = r0 + r;
            float4 x = make_float4(0.f, 0.f, 0.f, 0.f);
            if (row < N) {
                x = VecIO<TX>::ld(X + (size_t)row * C + c0 + c4);
                if (ACTIN == 2) {
                    float rd = 1.f / fmaxf(den[row * 4 + ((c0 + c4) >> 5)], 1e-16f);
                    x.x = gelu_f(x.x * rd); x.y = gelu_f(x.y * rd);
                    x.z = gelu_f(x.z * rd); x.w = gelu_f(x.w * rd);
                }
            }
            Xt[c4 + 0][r] = x.x; Xt[c4 + 1][r] = x.y;
            Xt[c4 + 2][r] = x.z; Xt[c4 + 3][r] = x.w;
        }
        __syncthreads();
        #pragma unroll
        for (int cc = 0; cc < 32; ++cc) {
            float4 xv = *(const float4*)(&Xt[cc][rg * 4]);
            float4 wv = *(const float4*)(&Wt[cc][cg * 4]);
            acc[0][0] = fmaf(xv.x, wv.x, acc[0][0]);
            acc[0][1] = fmaf(xv.x, wv.y, acc[0][1]);
            acc[0][2] = fmaf(xv.x, wv.z, acc[0][2]);
            acc[0][3] = fmaf(xv.x, wv.w, acc[0][3]);
            acc[1][0] = fmaf(xv.y, wv.x, acc[1][0]);
            acc[1][1] = fmaf(xv.y, wv.y, acc[1][1]);
            acc[1][2] = fmaf(xv.y, wv.z, acc[1][2]);
            acc[1][3] = fmaf(xv.y, wv.w, acc[1][3]);
            acc[2][0] = fmaf(xv.z, wv.x, acc[2][0]);
            acc[2][1] = fmaf(xv.z, wv.y, acc[2][1]);
            acc[2][2] = fmaf(xv.z, wv.z, acc[2][2]);
            acc[2][3] = fmaf(xv.z, wv.w, acc[2][3]);
            acc[3][0] = fmaf(xv.w, wv.x, acc[3][0]);
            acc[3][1] = fmaf(xv.w, wv.y, acc[3][1]);
            acc[3][2] = fmaf(xv.w, wv.z, acc[3][2]);
            acc[3][3] = fmaf(xv.w, wv.w, acc[3][3]);
        }
    }
    float4 bv = *(const float4*)(bias + cg * 4);
    #pragma unroll
    for (int ri = 0; ri < 4; ++ri) {
        int row = r0 + rg * 4 + ri;
        if (row >= N) continue;
        float4 ov;
        ov.x = acc[ri][0] + bv.x; ov.y = acc[ri][1] + bv.y;
        ov.z = acc[ri][2] + bv.z; ov.w = acc[ri][3] + bv.w;
        if (ACTOUT == 1) {
            ov.x = fmaxf(ov.x, 0.f); ov.y = fmaxf(ov.y, 0.f);
            ov.z = fmaxf(ov.z, 0.f); ov.w = fmaxf(ov.w, 0.f);
        }
        VecIO<TY>::st(Y + (size_t)row * 128 + cg * 4, ov);
    }
}

// ---- combined Q-side weights: WQA[r][h*32+d][c] = sum_f a[r,h,d,f] Wq[dst_r][h*32+f][c] ----
__global__ __launch_bounds__(256) void build_wqa(
    const float* __restrict__ kqvW_l, const float* __restrict__ kqvb_l,
    const float* __restrict__ a_l, float* __restrict__ WQA, float* __restrict__ BQA,
    const int* __restrict__ rdst)
{
    int r = blockIdx.x >> 2, h = blockIdx.x & 3;
    int dt = rdst[r];
    const float* Wq = kqvW_l + ((size_t)dt * 3 + 1) * 16384;
    const float* bq = kqvb_l + ((size_t)dt * 3 + 1) * 128;
    const float* A = a_l + (size_t)r * 4096 + h * 1024;  // [d][f]
    __shared__ float As[32][33];
    __shared__ float Ws[32][129];
    int tid = threadIdx.x;
    for (int v = tid; v < 1024; v += 256) As[v >> 5][v & 31] = A[v];
    for (int v = tid; v < 4096; v += 256)
        Ws[v >> 7][v & 127] = Wq[(size_t)(h * 32 + (v >> 7)) * 128 + (v & 127)];
    __syncthreads();
    int c = tid & 127, half = tid >> 7;
    for (int d = half; d < 32; d += 2) {
        float acc = 0.f;
        #pragma unroll
        for (int f = 0; f < 32; ++f) acc = fmaf(As[d][f], Ws[f][c], acc);
        WQA[((size_t)r * 128 + h * 32 + d) * 128 + c] = acc;
    }
    if (tid < 32) {
        int d = tid;
        float acc = 0.f;
        #pragma unroll
        for (int f = 0; f < 32; ++f) acc = fmaf(As[d][f], bq[h * 32 + f], acc);
        BQA[(size_t)r * 128 + h * 32 + d] = acc;
    }
}

// ---- combined V-side weights: WVM[r][h*32+f][c] = sum_d m[r,h,d,f] Wv[src_r][h*32+d][c] ----
__global__ __launch_bounds__(256) void build_wvm(
    const float* __restrict__ kqvW_l, const float* __restrict__ kqvb_l,
    const float* __restrict__ m_l, float* __restrict__ WVM, float* __restrict__ BVM,
    const int* __restrict__ rsrc)
{
    int r = blockIdx.x >> 2, h = blockIdx.x & 3;
    int st = rsrc[r];
    const float* Wv = kqvW_l + ((size_t)st * 3 + 2) * 16384;
    const float* bv = kqvb_l + ((size_t)st * 3 + 2) * 128;
    const float* M = m_l + (size_t)r * 4096 + h * 1024;  // [d][f]
    __shared__ float Ms[32][33];
    __shared__ float Ws[32][129];
    int tid = threadIdx.x;
    for (int v = tid; v < 1024; v += 256) Ms[v >> 5][v & 31] = M[v];
    for (int v = tid; v < 4096; v += 256)
        Ws[v >> 7][v & 127] = Wv[(size_t)(h * 32 + (v >> 7)) * 128 + (v & 127)];
    __syncthreads();
    int c = tid & 127, half = tid >> 7;
    for (int f = half; f < 32; f += 2) {
        float acc = 0.f;
        #pragma unroll
        for (int d = 0; d < 32; ++d) acc = fmaf(Ms[d][f], Ws[d][c], acc);
        WVM[((size_t)r * 128 + h * 32 + f) * 128 + c] = acc;
    }
    if (tid < 32) {
        int f = tid;
        float acc = 0.f;
        #pragma unroll
        for (int d = 0; d < 32; ++d) acc = fmaf(Ms[d][f], bv[h * 32 + d], acc);
        BVM[(size_t)r * 128 + h * 32 + f] = acc;
    }
}

__global__ __launch_bounds__(256) void edge_logits_k(
    const bfu* __restrict__ K, const bfu* __restrict__ Qa,
    const int* __restrict__ src, const int* __restrict__ dst,
    const float* __restrict__ prel, float* __restrict__ logits,
    unsigned* __restrict__ mxk)
{
    int idx = blockIdx.x * 256 + threadIdx.x;
    if (idx >= E_CNT * 4) return;
    int e = idx >> 2, h = idx & 3;
    int s = src[e], d = dst[e];
    const bfu* kp = K + (size_t)s * 128 + h * 32;
    const bfu* qp = Qa + (size_t)d * 128 + h * 32;
    float acc = 0.f;
    #pragma unroll
    for (int i = 0; i < 8; ++i) {
        float4 a = VecIO<bfu>::ld(kp + i * 4);
        float4 b = VecIO<bfu>::ld(qp + i * 4);
        acc += a.x * b.x + a.y * b.y + a.z * b.z + a.w * b.w;
    }
    float lg = acc * prel[h] * 0.17677669529663687f;
    logits[idx] = lg;
    atomicMax(&mxk[d * 4 + h], fkey(lg));
}

// unnormalized scatter: den += w, agg += w*Vm  (normalize later in epilogue GEMM)
__global__ __launch_bounds__(256) void edge_scatter2(
    const bfu* __restrict__ Vm, const int* __restrict__ src,
    const int* __restrict__ dst, const float* __restrict__ logits,
    const unsigned* __restrict__ mxk, float* __restrict__ den,
    float* __restrict__ agg)
{
    int idx = blockIdx.x * 256 + threadIdx.x;
    if (idx >= E_CNT * 32) return;
    int e = idx >> 5, u = idx & 31, h = u >> 3, fg = u & 7;
    int sd = src[e], dd = dst[e];
    float w = expf(logits[e * 4 + h] - funkey(mxk[dd * 4 + h]));
    if (fg == 0) atomicAdd(&den[dd * 4 + h], w);
    float4 v = VecIO<bfu>::ld(Vm + (size_t)sd * 128 + h * 32 + fg * 4);
    float* ap = agg + (size_t)dd * 128 + h * 32 + fg * 4;
    atomicAdd(ap + 0, w * v.x);
    atomicAdd(ap + 1, w * v.y);
    atomicAdd(ap + 2, w * v.z);
    atomicAdd(ap + 3, w * v.w);
}

// ---- z = (sg*o + (1-sg)*x) + x ; relu(LN(z)) ----
template<typename TX, typename TY>
__global__ __launch_bounds__(256) void ln_skip_relu(
    const float* __restrict__ O, const TX* __restrict__ Xr,
    const float* __restrict__ skp, const float* __restrict__ g,
    const float* __restrict__ bb, TY* __restrict__ Y, int N)
{
    int node = blockIdx.x * 4 + (threadIdx.x >> 6);
    int ln = threadIdx.x & 63;
    if (node >= N) return;
    float sg = 1.f / (1.f + expf(-skp[0]));
    size_t base = (size_t)node * 128;
    float o0 = O[base + ln], o1 = O[base + ln + 64];
    float x0 = VecIO<TX>::ld1(Xr + base + ln);
    float x1 = VecIO<TX>::ld1(Xr + base + ln + 64);
    float z0 = sg * o0 + (1.f - sg) * x0 + x0;
    float z1 = sg * o1 + (1.f - sg) * x1 + x1;
    float s = z0 + z1, q = z0 * z0 + z1 * z1;
    #pragma unroll
    for (int off = 32; off > 0; off >>= 1) {
        s += __shfl_xor(s, off);
        q += __shfl_xor(q, off);
    }
    float mean = s * (1.f / 128.f);
    float var = q * (1.f / 128.f) - mean * mean;
    float inv = rsqrtf(var + 1e-5f);
    float y0 = fmaxf((z0 - mean) * inv * g[ln] + bb[ln], 0.f);
    float y1 = fmaxf((z1 - mean) * inv * g[ln + 64] + bb[ln + 64], 0.f);
    if (sizeof(TY) == 2) {
        ((bfu*)Y)[base + ln] = f2bf(y0);
        ((bfu*)Y)[base + ln + 64] = f2bf(y1);
    } else {
        ((float*)Y)[base + ln] = y0;
        ((float*)Y)[base + ln + 64] = y1;
    }
}

// ---- fusion: 4 nodes/block, 128 threads. L0/L1 bf16, L2 f32 (aliases out) ----
__global__ __launch_bounds__(128) void fusion_kernel(
    const bfu* __restrict__ L0, const bfu* __restrict__ L1,
    const float* __restrict__ L2,
    const float* __restrict__ finW, const float* __restrict__ finB,
    const float* __restrict__ foutW, const float* __restrict__ foutB,
    const float* __restrict__ g, const float* __restrict__ bb,
    float* __restrict__ out, int N)
{
    __shared__ __align__(16) float seq[4][3][128];
    __shared__ __align__(16) float qkv[4][3][384];
    __shared__ __align__(16) float WLt[64][132];
    __shared__ __align__(16) float omean[4][128];
    __shared__ __align__(16) float macc[4][128];
    const int tid = threadIdx.x;
    const int n0 = blockIdx.x * 4;

    for (int v = tid; v < 1536; v += 128) {
        int n = v / 384, rem = v % 384, p = rem >> 7, c = rem & 127;
        int node = n0 + n;
        float val = 0.f;
        if (node < N) {
            if (p == 0) val = bf2f(L0[(size_t)node * 128 + c]);
            else if (p == 1) val = bf2f(L1[(size_t)node * 128 + c]);
            else val = L2[(size_t)node * 128 + c];
        }
        seq[n][p][c] = val;
    }
    __syncthreads();

    const int u = tid >> 6, jl = tid & 63;
    for (int ch = 0; ch < 6; ++ch) {
        __syncthreads();
        #pragma unroll
        for (int k = 0; k < 16; ++k) {
            int v4 = k * 128 + tid;
            int jj = v4 >> 5, c4 = (v4 & 31) * 4;
            float4 w = *(const float4*)(finW + (size_t)(ch * 64 + jj) * 128 + c4);
            *(float4*)(&WLt[jj][c4]) = w;
        }
        __syncthreads();
        int j = ch * 64 + jl;
        float fb = finB[j];
        #pragma unroll
        for (int q = 0; q < 3; ++q) {
            int pr0 = u * 6 + q * 2, pr1 = pr0 + 1;
            int na = pr0 / 3, pa = pr0 % 3;
            int nb = pr1 / 3, pb = pr1 % 3;
            float a0 = fb, a1 = fb;
            for (int c4 = 0; c4 < 128; c4 += 4) {
                float4 wv = *(const float4*)(&WLt[jl][c4]);
                float4 s0 = *(const float4*)(&seq[na][pa][c4]);
                float4 s1 = *(const float4*)(&seq[nb][pb][c4]);
                a0 += wv.x * s0.x + wv.y * s0.y + wv.z * s0.z + wv.w * s0.w;
                a1 += wv.x * s1.x + wv.y * s1.y + wv.z * s1.z + wv.w * s1.w;
            }
            qkv[na][pa][j] = a0;
            qkv[nb][pb][j] = a1;
        }
    }
    __syncthreads();

    if (tid < 48) {
        int n = tid / 12, rem = tid % 12, h = rem / 3, qi = rem % 3;
        float s0 = 0.f, s1 = 0.f, s2 = 0.f;
        for (int d = 0; d < 32; ++d) {
            float qv = qkv[n][qi][h * 32 + d];
            s0 = fmaf(qv, qkv[n][0][128 + h * 32 + d], s0);
            s1 = fmaf(qv, qkv[n][1][128 + h * 32 + d], s1);
            s2 = fmaf(qv, qkv[n][2][128 + h * 32 + d], s2);
        }
        s0 *= 0.17677669529663687f; s1 *= 0.17677669529663687f; s2 *= 0.17677669529663687f;
        float mx = fmaxf(s0, fmaxf(s1, s2));
        float e0 = expf(s0 - mx), e1 = expf(s1 - mx), e2 = expf(s2 - mx);
        float inv = 1.f / (e0 + e1 + e2);
        for (int d = 0; d < 32; ++d) {
            float o = (e0 * qkv[n][0][256 + h * 32 + d] +
                       e1 * qkv[n][1][256 + h * 32 + d] +
                       e2 * qkv[n][2][256 + h * 32 + d]) * inv;
            seq[n][qi][h * 32 + d] = o;
        }
    }
    __syncthreads();

    for (int v = tid; v < 512; v += 128) {
        int n = v >> 7, c = v & 127;
        omean[n][c] = (seq[n][0][c] + seq[n][1][c] + seq[n][2][c]) * (1.f / 3.f);
    }
    __syncthreads();

    for (int ch = 0; ch < 2; ++ch) {
        __syncthreads();
        #pragma unroll
        for (int k = 0; k < 16; ++k) {
            int v4 = k * 128 + tid;
            int jj = v4 >> 5, c4 = (v4 & 31) * 4;
            float4 w = *(const float4*)(foutW + (size_t)(ch * 64 + jj) * 128 + c4);
            *(float4*)(&WLt[jj][c4]) = w;
        }
        __syncthreads();
        int j = ch * 64 + jl;
        float fb = foutB[j];
        float a0 = fb, a1 = fb;
        int na = u * 2, nb = na + 1;
        for (int c4 = 0; c4 < 128; c4 += 4) {
            float4 wv = *(const float4*)(&WLt[jl][c4]);
            float4 s0 = *(const float4*)(&omean[na][c4]);
            float4 s1 = *(const float4*)(&omean[nb][c4]);
            a0 += wv.x * s0.x + wv.y * s0.y + wv.z * s0.z + wv.w * s0.w;
            a1 += wv.x * s1.x + wv.y * s1.y + wv.z * s1.z + wv.w * s1.w;
        }
        macc[na][j] = a0;
        macc[nb][j] = a1;
    }
    __syncthreads();

    const int wv2 = tid >> 6, ln = tid & 63;
    for (int nn = 0; nn < 2; ++nn) {
        int n = wv2 * 2 + nn;
        int node = n0 + n;
        if (node >= N) continue;
        float z0 = macc[n][ln], z1 = macc[n][ln + 64];
        float s = z0 + z1, q = z0 * z0 + z1 * z1;
        #pragma unroll
        for (int off = 32; off > 0; off >>= 1) {
            s += __shfl_xor(s, off);
            q += __shfl_xor(q, off);
        }
        float mean = s * (1.f / 128.f);
        float var = q * (1.f / 128.f) - mean * mean;
        float inv = rsqrtf(var + 1e-5f);
        out[(size_t)node * 128 + ln] = (z0 - mean) * inv * g[ln] + bb[ln];
        out[(size_t)node * 128 + ln + 64] = (z1 - mean) * inv * g[ln + 64] + bb[ln + 64];
    }
}

extern "C" void kernel_launch(void* const* d_in, const int* in_sizes, int n_in,
                              void* d_out, int out_size, void* d_ws, size_t ws_size,
                              hipStream_t stream)
{
    const float* x_pest   = (const float*)d_in[0];
    const float* x_dis    = (const float*)d_in[1];
    const float* x_plant  = (const float*)d_in[2];
    const int*   edges    = (const int*)d_in[3];
    const float* proj_W   = (const float*)d_in[4];
    const float* proj_b   = (const float*)d_in[5];
    const float* event_emb= (const float*)d_in[6];
    const float* kqv_W    = (const float*)d_in[7];
    const float* kqv_b    = (const float*)d_in[8];
    const float* out_W    = (const float*)d_in[9];
    const float* out_b    = (const float*)d_in[10];
    const float* skip     = (const float*)d_in[11];
    const float* a_rel    = (const float*)d_in[12];
    const float* m_rel    = (const float*)d_in[13];
    const float* p_rel    = (const float*)d_in[14];
    const float* blk_ln_g = (const float*)d_in[15];
    const float* blk_ln_b = (const float*)d_in[16];
    const float* fin_W    = (const float*)d_in[17];
    const float* fin_b    = (const float*)d_in[18];
    const float* fout_W   = (const float*)d_in[19];
    const float* fout_b   = (const float*)d_in[20];
    const float* f_ln_g   = (const float*)d_in[21];
    const float* f_ln_b   = (const float*)d_in[22];
    float* out = (float*)d_out;

    static const int NT[4]  = {30000, 20000, 25000, 50000};
    static const int OFF[4] = {0, 30000, 50000, 75000};
    // relation r: src HSRC[r] -> dst HDST[r]
    // per-dst groups: dt -> {(r,src)} ; each dst has exactly 2 incoming rels
    static const int DG[4][2][2] = { {{1,1},{4,3}}, {{0,0},{2,2}}, {{3,1},{6,3}}, {{5,0},{7,2}} };

    // byte-based ws allocation (256B aligned)
    char* wsb = (char*)d_ws;
    size_t ob = 0;
    auto alc = [&](size_t bytes) -> void* {
        void* p = wsb + ob; ob += (bytes + 255) & ~(size_t)255; return p;
    };
    bfu* LK0 = (bfu*)alc((size_t)75000 * 128 * 2);
    bfu* LK1 = (bfu*)alc((size_t)75000 * 128 * 2);
    bfu* KS  = (bfu*)alc((size_t)50000 * 128 * 2);
    bfu* QA  = (bfu*)alc((size_t)50000 * 128 * 2);
    float* LG = (float*)alc((size_t)2 * E_CNT * 4 * 4);
    unsigned* MX = (unsigned*)alc((size_t)50000 * 4 * 4);
    float* DEN = (float*)alc((size_t)50000 * 4 * 4);
    float* AGG = (float*)alc((size_t)50000 * 128 * 4);
    float* WQA = (float*)alc((size_t)8 * 16384 * 4);
    float* BQA = (float*)alc((size_t)8 * 128 * 4);
    float* WVM = (float*)alc((size_t)8 * 16384 * 4);
    float* BVM = (float*)alc((size_t)8 * 128 * 4);
    int* RSRC = (int*)alc(8 * 4);
    int* RDST = (int*)alc(8 * 4);
    if (ws_size < ob) {  // sentinel: ws too small -> absmax = 1e30 (not NaN)
        fill_val<<<(out_size + 255) / 256, 256, 0, stream>>>(out, out_size, 1e30f);
        return;
    }
    {   // push relation maps to device (tiny, d2d-safe via async copy from constants)
        static const int h_rsrc[8] = {0, 1, 2, 1, 3, 0, 3, 2};
        static const int h_rdst[8] = {1, 0, 1, 2, 0, 3, 2, 3};
        hipMemcpyAsync(RSRC, h_rsrc, 32, hipMemcpyHostToDevice, stream);
        hipMemcpyAsync(RDST, h_rdst, 32, hipMemcpyHostToDevice, stream);
    }

    float* XIN = out;         // [75000,128] f32, layer-0 inputs (types 0-2)
    float* EV  = out;         // [50000,128] f32, event feature chain (in-place)

    const float* xin0[3] = {x_pest, x_dis, x_plant};
    for (int t = 0; t < 3; ++t) {
        gemm_xwt<float, float, 64, 0, 1><<<(NT[t] + 31) / 32, 256, 0, stream>>>(
            xin0[t], proj_W + (size_t)t * 8192, proj_b + (size_t)t * 128,
            XIN + (size_t)OFF[t] * 128, NT[t], nullptr);
    }

    const int eg4 = (E_CNT * 4 + 255) / 256;
    const int eg32 = (E_CNT * 32 + 255) / 256;

    for (int l = 0; l < 3; ++l) {
        const float* kqvW_l = kqv_W + (size_t)l * 12 * 16384;
        const float* kqvb_l = kqv_b + (size_t)l * 12 * 128;

        build_wqa<<<32, 256, 0, stream>>>(kqvW_l, kqvb_l, a_rel + (size_t)l * 8 * 4096, WQA, BQA, RDST);
        build_wvm<<<32, 256, 0, stream>>>(kqvW_l, kqvb_l, m_rel + (size_t)l * 8 * 4096, WVM, BVM, RSRC);

        // feature-GEMM launcher: X = layer-l input features of type tt
        auto feat_gemm = [&](int tt, const float* Wp, const float* Bp, bfu* Yp) {
            int Nn = NT[tt];
            int gb = (Nn + 31) / 32;
            if (l == 0) {
                const float* Xp = (tt < 3) ? (XIN + (size_t)OFF[tt] * 128) : event_emb;
                gemm_xwt<float, bfu, 128, 0, 0><<<gb, 256, 0, stream>>>(Xp, Wp, Bp, Yp, Nn, nullptr);
            } else if (tt == 3) {
                gemm_xwt<float, bfu, 128, 0, 0><<<gb, 256, 0, stream>>>(EV, Wp, Bp, Yp, Nn, nullptr);
            } else {
                const bfu* Xp = (l == 1 ? LK0 : LK1) + (size_t)OFF[tt] * 128;
                gemm_xwt<bfu, bfu, 128, 0, 0><<<gb, 256, 0, stream>>>(Xp, Wp, Bp, Yp, Nn, nullptr);
            }
        };

        // dst-type order; layer 2: {2,0,1} so L2 writes into d_out don't clobber EV before r4/r6 read it
        int order[4] = {0, 1, 2, 3};
        int nord = 4;
        if (l == 2) { order[0] = 2; order[1] = 0; order[2] = 1; nord = 3; }

        for (int oi = 0; oi < nord; ++oi) {
            int dt = order[oi];
            int Ndt = NT[dt];
            hipMemsetAsync(MX, 0, (size_t)Ndt * 4 * 4, stream);
            hipMemsetAsync(DEN, 0, (size_t)Ndt * 4 * 4, stream);
            hipMemsetAsync(AGG, 0, (size_t)Ndt * 128 * 4, stream);

            // pass A: per relation: Qa GEMM, K GEMM, logits+max
            for (int gi = 0; gi < 2; ++gi) {
                int r = DG[dt][gi][0], s = DG[dt][gi][1];
                feat_gemm(dt, WQA + (size_t)r * 16384, BQA + (size_t)r * 128, QA);
                feat_gemm(s, kqvW_l + ((size_t)s * 3 + 0) * 16384,
                          kqvb_l + ((size_t)s * 3 + 0) * 128, KS);
                edge_logits_k<<<eg4, 256, 0, stream>>>(
                    KS, QA, edges + (size_t)(2 * r) * E_CNT, edges + (size_t)(2 * r + 1) * E_CNT,
                    p_rel + (size_t)(l * 8 + r) * 4, LG + (size_t)gi * E_CNT * 4, MX);
            }
            // pass B: per relation: Vm GEMM, scatter
            for (int gi = 0; gi < 2; ++gi) {
                int r = DG[dt][gi][0], s = DG[dt][gi][1];
                feat_gemm(s, WVM + (size_t)r * 16384, BVM + (size_t)r * 128, KS);
                edge_scatter2<<<eg32, 256, 0, stream>>>(
                    KS, edges + (size_t)(2 * r) * E_CNT, edges + (size_t)(2 * r + 1) * E_CNT,
                    LG + (size_t)gi * E_CNT * 4, MX, DEN, AGG);
            }
            // epilogue: normalize+gelu inside GEMM (in-place AGG), then skip+LN+relu
            size_t wi = (size_t)l * 4 + dt;
            gemm_xwt<float, float, 128, 2, 0><<<(Ndt + 31) / 32, 256, 0, stream>>>(
                AGG, out_W + wi * 16384, out_b + wi * 128, AGG, Ndt, DEN);

            int lb = (Ndt + 3) / 4;
            const float* lg_ = blk_ln_g + (size_t)l * 128;
            const float* lb_ = blk_ln_b + (size_t)l * 128;
            const float* sk = skip + wi;
            if (l == 0) {
                if (dt < 3)
                    ln_skip_relu<float, bfu><<<lb, 256, 0, stream>>>(
                        AGG, XIN + (size_t)OFF[dt] * 128, sk, lg_, lb_,
                        LK0 + (size_t)OFF[dt] * 128, Ndt);
                else
                    ln_skip_relu<float, float><<<lb, 256, 0, stream>>>(
                        AGG, event_emb, sk, lg_, lb_, EV, Ndt);
            } else if (l == 1) {
                if (dt < 3)
                    ln_skip_relu<bfu, bfu><<<lb, 256, 0, stream>>>(
                        AGG, LK0 + (size_t)OFF[dt] * 128, sk, lg_, lb_,
                        LK1 + (size_t)OFF[dt] * 128, Ndt);
                else
                    ln_skip_relu<float, float><<<lb, 256, 0, stream>>>(
                        AGG, EV, sk, lg_, lb_, EV, Ndt);  // element-wise in-place: safe
            } else {
                ln_skip_relu<bfu, float><<<lb, 256, 0, stream>>>(
                    AGG, LK1 + (size_t)OFF[dt] * 128, sk, lg_, lb_,
                    out + (size_t)OFF[dt] * 128, Ndt);
            }
        }
    }

    // fusion heads for types 0..2 (L2 aliases out; per-node in-place)
    for (int j = 0; j < 3; ++j) {
        fusion_kernel<<<(NT[j] + 3) / 4, 128, 0, stream>>>(
            LK0 + (size_t)OFF[j] * 128, LK1 + (size_t)OFF[j] * 128,
            out + (size_t)OFF[j] * 128,
            fin_W + (size_t)j * 49152, fin_b + (size_t)j * 384,
            fout_W + (size_t)j * 16384, fout_b + (size_t)j * 128,
            f_ln_g + (size_t)j * 128, f_ln_b + (size_t)j * 128,
            out + (size_t)OFF[j] * 128, NT[j]);
    }
}

// Round 4
// 4760.948 us; speedup vs baseline: 2.6036x; 2.6036x over previous
//
#include <hip/hip_runtime.h>
#include <math.h>

#define E_CNT 200000
typedef unsigned short bfu;

__device__ __forceinline__ float gelu_f(float x) {
    return 0.5f * x * (1.0f + erff(x * 0.70710678118654752f));
}
__device__ __forceinline__ float bf2f(bfu u) { return __uint_as_float(((unsigned)u) << 16); }
__device__ __forceinline__ bfu f2bf(float f) {
    unsigned u = __float_as_uint(f);
    unsigned r = u + 0x7FFFu + ((u >> 16) & 1u);
    return (bfu)(r >> 16);
}

template<typename T> struct VecIO;
template<> struct VecIO<float> {
    static __device__ __forceinline__ float4 ld(const float* p) { return *(const float4*)p; }
    static __device__ __forceinline__ void st(float* p, float4 v) { *(float4*)p = v; }
};
template<> struct VecIO<bfu> {
    static __device__ __forceinline__ float4 ld(const bfu* p) {
        uint2 u = *(const uint2*)p;
        float4 r;
        r.x = __uint_as_float(u.x << 16);
        r.y = __uint_as_float(u.x & 0xFFFF0000u);
        r.z = __uint_as_float(u.y << 16);
        r.w = __uint_as_float(u.y & 0xFFFF0000u);
        return r;
    }
    static __device__ __forceinline__ void st(bfu* p, float4 v) {
        uint2 u;
        u.x = ((unsigned)f2bf(v.x)) | (((unsigned)f2bf(v.y)) << 16);
        u.y = ((unsigned)f2bf(v.z)) | (((unsigned)f2bf(v.w)) << 16);
        *(uint2*)p = u;
    }
};

__global__ __launch_bounds__(256) void fill_val(float* p, int n, float v) {
    int i = blockIdx.x * 256 + threadIdx.x;
    if (i < n) p[i] = v;
}

// ================= CSR build =================
__global__ __launch_bounds__(256) void hist_k(const int* __restrict__ dst, int* __restrict__ rp) {
    int e = blockIdx.x * 256 + threadIdx.x;
    if (e < E_CNT) atomicAdd(&rp[dst[e] + 1], 1);
}
__global__ __launch_bounds__(1024) void scan_k(int* __restrict__ a, int len) {
    __shared__ int lds[1024];
    int t = threadIdx.x;
    int chunk = (len + 1023) >> 10;
    int lo = t * chunk, hi = min(lo + chunk, len);
    int s = 0;
    for (int i = lo; i < hi; ++i) s += a[i];
    lds[t] = s;
    __syncthreads();
    for (int off = 1; off < 1024; off <<= 1) {
        int v = (t >= off) ? lds[t - off] : 0;
        __syncthreads();
        lds[t] += v;
        __syncthreads();
    }
    int pre = lds[t] - s;
    for (int i = lo; i < hi; ++i) { pre += a[i]; a[i] = pre; }
}
__global__ __launch_bounds__(256) void scatter_k(
    const int* __restrict__ src, const int* __restrict__ dst,
    const int* __restrict__ rp, int* __restrict__ cur, int* __restrict__ sidx) {
    int e = blockIdx.x * 256 + threadIdx.x;
    if (e >= E_CNT) return;
    int d = dst[e];
    int pos = rp[d] + atomicAdd(&cur[d], 1);
    sidx[pos] = src[e];
}

// ================= GEMM: Y[N,out 128] = actout(X[N,C] @ W[128,C]^T + b) =================
template<typename TX, typename TY, int C, int ACTOUT>
__global__ __launch_bounds__(256) void gemm_xwt(
    const TX* __restrict__ X, const float* __restrict__ W,
    const float* __restrict__ bias, TY* __restrict__ Y, int N, int ldy)
{
    __shared__ __align__(16) float Wt[32][132];
    __shared__ __align__(16) float Xt[32][36];
    const int tid = threadIdx.x;
    const int r0 = blockIdx.x * 32;
    const int rg = tid >> 5, cg = tid & 31;
    float acc[4][4];
    #pragma unroll
    for (int i = 0; i < 4; ++i)
        #pragma unroll
        for (int j = 0; j < 4; ++j) acc[i][j] = 0.f;

    for (int c0 = 0; c0 < C; c0 += 32) {
        __syncthreads();
        #pragma unroll
        for (int k = 0; k < 4; ++k) {
            int v = tid + k * 256;
            int j = v >> 3, c4 = (v & 7) * 4;
            float4 w = *(const float4*)(W + (size_t)j * C + c0 + c4);
            Wt[c4 + 0][j] = w.x; Wt[c4 + 1][j] = w.y;
            Wt[c4 + 2][j] = w.z; Wt[c4 + 3][j] = w.w;
        }
        {
            int r = tid >> 3, c4 = (tid & 7) * 4;
            int row = r0 + r;
            float4 x = make_float4(0.f, 0.f, 0.f, 0.f);
            if (row < N) x = VecIO<TX>::ld(X + (size_t)row * C + c0 + c4);
            Xt[c4 + 0][r] = x.x; Xt[c4 + 1][r] = x.y;
            Xt[c4 + 2][r] = x.z; Xt[c4 + 3][r] = x.w;
        }
        __syncthreads();
        #pragma unroll
        for (int cc = 0; cc < 32; ++cc) {
            float4 xv = *(const float4*)(&Xt[cc][rg * 4]);
            float4 wv = *(const float4*)(&Wt[cc][cg * 4]);
            acc[0][0] = fmaf(xv.x, wv.x, acc[0][0]);
            acc[0][1] = fmaf(xv.x, wv.y, acc[0][1]);
            acc[0][2] = fmaf(xv.x, wv.z, acc[0][2]);
            acc[0][3] = fmaf(xv.x, wv.w, acc[0][3]);
            acc[1][0] = fmaf(xv.y, wv.x, acc[1][0]);
            acc[1][1] = fmaf(xv.y, wv.y, acc[1][1]);
            acc[1][2] = fmaf(xv.y, wv.z, acc[1][2]);
            acc[1][3] = fmaf(xv.y, wv.w, acc[1][3]);
            acc[2][0] = fmaf(xv.z, wv.x, acc[2][0]);
            acc[2][1] = fmaf(xv.z, wv.y, acc[2][1]);
            acc[2][2] = fmaf(xv.z, wv.z, acc[2][2]);
            acc[2][3] = fmaf(xv.z, wv.w, acc[2][3]);
            acc[3][0] = fmaf(xv.w, wv.x, acc[3][0]);
            acc[3][1] = fmaf(xv.w, wv.y, acc[3][1]);
            acc[3][2] = fmaf(xv.w, wv.z, acc[3][2]);
            acc[3][3] = fmaf(xv.w, wv.w, acc[3][3]);
        }
    }
    float4 bv = *(const float4*)(bias + cg * 4);
    #pragma unroll
    for (int ri = 0; ri < 4; ++ri) {
        int row = r0 + rg * 4 + ri;
        if (row >= N) continue;
        float4 ov;
        ov.x = acc[ri][0] + bv.x; ov.y = acc[ri][1] + bv.y;
        ov.z = acc[ri][2] + bv.z; ov.w = acc[ri][3] + bv.w;
        if (ACTOUT == 1) {
            ov.x = fmaxf(ov.x, 0.f); ov.y = fmaxf(ov.y, 0.f);
            ov.z = fmaxf(ov.z, 0.f); ov.w = fmaxf(ov.w, 0.f);
        }
        VecIO<TY>::st(Y + (size_t)row * ldy + cg * 4, ov);
    }
}

// ====== GEMM with fused epilogue. MODE 0: gelu(X) in, skip+LN+relu out. MODE 1: LN out. ======
template<typename TXR, typename TY, int MODE>
__global__ __launch_bounds__(256) void gemm_epi(
    const float* __restrict__ X, const float* __restrict__ W,
    const float* __restrict__ bias, const TXR* __restrict__ Xr,
    const float* __restrict__ skp, const float* __restrict__ g,
    const float* __restrict__ bb, TY* __restrict__ Y, int N)
{
    __shared__ __align__(16) float Wt[32][132];
    __shared__ __align__(16) float Xt[32][36];
    const int tid = threadIdx.x;
    const int r0 = blockIdx.x * 32;
    const int rg = tid >> 5, cg = tid & 31;
    float acc[4][4];
    #pragma unroll
    for (int i = 0; i < 4; ++i)
        #pragma unroll
        for (int j = 0; j < 4; ++j) acc[i][j] = 0.f;

    for (int c0 = 0; c0 < 128; c0 += 32) {
        __syncthreads();
        #pragma unroll
        for (int k = 0; k < 4; ++k) {
            int v = tid + k * 256;
            int j = v >> 3, c4 = (v & 7) * 4;
            float4 w = *(const float4*)(W + (size_t)j * 128 + c0 + c4);
            Wt[c4 + 0][j] = w.x; Wt[c4 + 1][j] = w.y;
            Wt[c4 + 2][j] = w.z; Wt[c4 + 3][j] = w.w;
        }
        {
            int r = tid >> 3, c4 = (tid & 7) * 4;
            int row = r0 + r;
            float4 x = make_float4(0.f, 0.f, 0.f, 0.f);
            if (row < N) {
                x = *(const float4*)(X + (size_t)row * 128 + c0 + c4);
                if (MODE == 0) {
                    x.x = gelu_f(x.x); x.y = gelu_f(x.y);
                    x.z = gelu_f(x.z); x.w = gelu_f(x.w);
                }
            }
            Xt[c4 + 0][r] = x.x; Xt[c4 + 1][r] = x.y;
            Xt[c4 + 2][r] = x.z; Xt[c4 + 3][r] = x.w;
        }
        __syncthreads();
        #pragma unroll
        for (int cc = 0; cc < 32; ++cc) {
            float4 xv = *(const float4*)(&Xt[cc][rg * 4]);
            float4 wv = *(const float4*)(&Wt[cc][cg * 4]);
            acc[0][0] = fmaf(xv.x, wv.x, acc[0][0]);
            acc[0][1] = fmaf(xv.x, wv.y, acc[0][1]);
            acc[0][2] = fmaf(xv.x, wv.z, acc[0][2]);
            acc[0][3] = fmaf(xv.x, wv.w, acc[0][3]);
            acc[1][0] = fmaf(xv.y, wv.x, acc[1][0]);
            acc[1][1] = fmaf(xv.y, wv.y, acc[1][1]);
            acc[1][2] = fmaf(xv.y, wv.z, acc[1][2]);
            acc[1][3] = fmaf(xv.y, wv.w, acc[1][3]);
            acc[2][0] = fmaf(xv.z, wv.x, acc[2][0]);
            acc[2][1] = fmaf(xv.z, wv.y, acc[2][1]);
            acc[2][2] = fmaf(xv.z, wv.z, acc[2][2]);
            acc[2][3] = fmaf(xv.z, wv.w, acc[2][3]);
            acc[3][0] = fmaf(xv.w, wv.x, acc[3][0]);
            acc[3][1] = fmaf(xv.w, wv.y, acc[3][1]);
            acc[3][2] = fmaf(xv.w, wv.z, acc[3][2]);
            acc[3][3] = fmaf(xv.w, wv.w, acc[3][3]);
        }
    }
    float4 bv = *(const float4*)(bias + cg * 4);
    float sg = 0.f;
    if (MODE == 0) sg = 1.f / (1.f + expf(-skp[0]));
    float4 gv = *(const float4*)(g + cg * 4);
    float4 bbv = *(const float4*)(bb + cg * 4);
    #pragma unroll
    for (int ri = 0; ri < 4; ++ri) {
        int row = r0 + rg * 4 + ri;   // uniform across the 32-lane cg-group
        if (row >= N) continue;
        float z[4];
        z[0] = acc[ri][0] + bv.x; z[1] = acc[ri][1] + bv.y;
        z[2] = acc[ri][2] + bv.z; z[3] = acc[ri][3] + bv.w;
        if (MODE == 0) {
            float4 xr = VecIO<TXR>::ld(Xr + (size_t)row * 128 + cg * 4);
            z[0] = sg * z[0] + (1.f - sg) * xr.x + xr.x;
            z[1] = sg * z[1] + (1.f - sg) * xr.y + xr.y;
            z[2] = sg * z[2] + (1.f - sg) * xr.z + xr.z;
            z[3] = sg * z[3] + (1.f - sg) * xr.w + xr.w;
        }
        float s = z[0] + z[1] + z[2] + z[3];
        float qq = z[0] * z[0] + z[1] * z[1] + z[2] * z[2] + z[3] * z[3];
        #pragma unroll
        for (int off = 1; off <= 16; off <<= 1) {
            s += __shfl_xor(s, off);
            qq += __shfl_xor(qq, off);
        }
        float mean = s * (1.f / 128.f);
        float var = qq * (1.f / 128.f) - mean * mean;
        float inv = rsqrtf(var + 1e-5f);
        float4 y4;
        y4.x = (z[0] - mean) * inv * gv.x + bbv.x;
        y4.y = (z[1] - mean) * inv * gv.y + bbv.y;
        y4.z = (z[2] - mean) * inv * gv.z + bbv.z;
        y4.w = (z[3] - mean) * inv * gv.w + bbv.w;
        if (MODE == 0) {
            y4.x = fmaxf(y4.x, 0.f); y4.y = fmaxf(y4.y, 0.f);
            y4.z = fmaxf(y4.z, 0.f); y4.w = fmaxf(y4.w, 0.f);
        }
        VecIO<TY>::st(Y + (size_t)row * 128 + cg * 4, y4);
    }
}

// ================= relation-folded weight builders (verified round 3) =================
__global__ __launch_bounds__(256) void build_wqa(
    const float* __restrict__ kqvW_l, const float* __restrict__ kqvb_l,
    const float* __restrict__ a_l, float* __restrict__ WQA, float* __restrict__ BQA,
    const int* __restrict__ rdst)
{
    int r = blockIdx.x >> 2, h = blockIdx.x & 3;
    int dt = rdst[r];
    const float* Wq = kqvW_l + ((size_t)dt * 3 + 1) * 16384;
    const float* bq = kqvb_l + ((size_t)dt * 3 + 1) * 128;
    const float* A = a_l + (size_t)r * 4096 + h * 1024;
    __shared__ float As[32][33];
    __shared__ float Ws[32][129];
    int tid = threadIdx.x;
    for (int v = tid; v < 1024; v += 256) As[v >> 5][v & 31] = A[v];
    for (int v = tid; v < 4096; v += 256)
        Ws[v >> 7][v & 127] = Wq[(size_t)(h * 32 + (v >> 7)) * 128 + (v & 127)];
    __syncthreads();
    int c = tid & 127, half = tid >> 7;
    for (int d = half; d < 32; d += 2) {
        float acc = 0.f;
        #pragma unroll
        for (int f = 0; f < 32; ++f) acc = fmaf(As[d][f], Ws[f][c], acc);
        WQA[((size_t)r * 128 + h * 32 + d) * 128 + c] = acc;
    }
    if (tid < 32) {
        int d = tid;
        float acc = 0.f;
        #pragma unroll
        for (int f = 0; f < 32; ++f) acc = fmaf(As[d][f], bq[h * 32 + f], acc);
        BQA[(size_t)r * 128 + h * 32 + d] = acc;
    }
}
__global__ __launch_bounds__(256) void build_wvm(
    const float* __restrict__ kqvW_l, const float* __restrict__ kqvb_l,
    const float* __restrict__ m_l, float* __restrict__ WVM, float* __restrict__ BVM,
    const int* __restrict__ rsrc)
{
    int r = blockIdx.x >> 2, h = blockIdx.x & 3;
    int st = rsrc[r];
    const float* Wv = kqvW_l + ((size_t)st * 3 + 2) * 16384;
    const float* bv = kqvb_l + ((size_t)st * 3 + 2) * 128;
    const float* M = m_l + (size_t)r * 4096 + h * 1024;
    __shared__ float Ms[32][33];
    __shared__ float Ws[32][129];
    int tid = threadIdx.x;
    for (int v = tid; v < 1024; v += 256) Ms[v >> 5][v & 31] = M[v];
    for (int v = tid; v < 4096; v += 256)
        Ws[v >> 7][v & 127] = Wv[(size_t)(h * 32 + (v >> 7)) * 128 + (v & 127)];
    __syncthreads();
    int c = tid & 127, half = tid >> 7;
    for (int f = half; f < 32; f += 2) {
        float acc = 0.f;
        #pragma unroll
        for (int d = 0; d < 32; ++d) acc = fmaf(Ms[d][f], Ws[d][c], acc);
        WVM[((size_t)r * 128 + h * 32 + f) * 128 + c] = acc;
    }
    if (tid < 32) {
        int f = tid;
        float acc = 0.f;
        #pragma unroll
        for (int d = 0; d < 32; ++d) acc = fmaf(Ms[d][f], bv[h * 32 + d], acc);
        BVM[(size_t)r * 128 + h * 32 + f] = acc;
    }
}

// ================= CSR aggregation: wave per dst node =================
// lane l handles feature c=l (head hA=l>>5) and c=l+64 (head 2+hA).
// MD layout: [n][0..3]=running max, [n][4..7]=running den  (stride 8)
template<int FIRST>
__global__ __launch_bounds__(256) void agg_pass1(
    const bfu* __restrict__ QA, const bfu* __restrict__ K,
    const int* __restrict__ rp, const int* __restrict__ sidx,
    const float* __restrict__ prl, float* __restrict__ LG,
    float* __restrict__ MD, int Nn)
{
    int n = blockIdx.x * 4 + (threadIdx.x >> 6);
    int l = threadIdx.x & 63;
    if (n >= Nn) return;
    int hA = l >> 5;
    float pA = prl[hA] * 0.17677669529663687f;
    float pB = prl[2 + hA] * 0.17677669529663687f;
    float q0 = bf2f(QA[(size_t)n * 128 + l]);
    float q1 = bf2f(QA[(size_t)n * 128 + l + 64]);
    float m0, d0, m1, d1;
    if (FIRST) { m0 = m1 = -3.0e38f; d0 = d1 = 0.f; }
    else {
        m0 = MD[n * 8 + hA];     m1 = MD[n * 8 + 2 + hA];
        d0 = MD[n * 8 + 4 + hA]; d1 = MD[n * 8 + 6 + hA];
    }
    int e0 = rp[n], e1 = rp[n + 1];
    for (int i = e0; i < e1; ++i) {
        int s = sidx[i];
        float s0 = bf2f(K[(size_t)s * 128 + l]) * q0;
        float s1 = bf2f(K[(size_t)s * 128 + l + 64]) * q1;
        #pragma unroll
        for (int off = 1; off <= 16; off <<= 1) {
            s0 += __shfl_xor(s0, off);
            s1 += __shfl_xor(s1, off);
        }
        s0 *= pA; s1 *= pB;
        if (l == 0 || l == 32) {
            LG[(size_t)i * 4 + hA] = s0;
            LG[(size_t)i * 4 + 2 + hA] = s1;
        }
        float nm0 = fmaxf(m0, s0);
        d0 = d0 * __expf(m0 - nm0) + __expf(s0 - nm0);
        m0 = nm0;
        float nm1 = fmaxf(m1, s1);
        d1 = d1 * __expf(m1 - nm1) + __expf(s1 - nm1);
        m1 = nm1;
    }
    if (l == 0 || l == 32) {
        MD[n * 8 + hA] = m0;     MD[n * 8 + 2 + hA] = m1;
        MD[n * 8 + 4 + hA] = d0; MD[n * 8 + 6 + hA] = d1;
    }
}

template<int FIRST>
__global__ __launch_bounds__(256) void agg_pass2(
    const bfu* __restrict__ VM, const int* __restrict__ rp,
    const int* __restrict__ sidx, const float* __restrict__ LG,
    const float* __restrict__ MD, float* __restrict__ ACC, int Nn)
{
    int n = blockIdx.x * 4 + (threadIdx.x >> 6);
    int l = threadIdx.x & 63;
    if (n >= Nn) return;
    int hA = l >> 5;
    float mA = MD[n * 8 + hA], mB = MD[n * 8 + 2 + hA];
    float rdA = 1.f / fmaxf(MD[n * 8 + 4 + hA], 1e-16f);
    float rdB = 1.f / fmaxf(MD[n * 8 + 6 + hA], 1e-16f);
    float a0, a1;
    if (FIRST) { a0 = a1 = 0.f; }
    else { a0 = ACC[(size_t)n * 128 + l]; a1 = ACC[(size_t)n * 128 + l + 64]; }
    int e0 = rp[n], e1 = rp[n + 1];
    for (int i = e0; i < e1; ++i) {
        int s = sidx[i];
        float w0 = __expf(LG[(size_t)i * 4 + hA] - mA) * rdA;
        float w1 = __expf(LG[(size_t)i * 4 + 2 + hA] - mB) * rdB;
        a0 = fmaf(w0, bf2f(VM[(size_t)s * 128 + l]), a0);
        a1 = fmaf(w1, bf2f(VM[(size_t)s * 128 + l + 64]), a1);
    }
    ACC[(size_t)n * 128 + l] = a0;
    ACC[(size_t)n * 128 + l + 64] = a1;
}

// ================= fusion attention (3 tokens, 4 heads), wave per node =================
__global__ __launch_bounds__(256) void attn_fuse(
    const bfu* __restrict__ QKV, float* __restrict__ OM, int M)
{
    int n = blockIdx.x * 4 + (threadIdx.x >> 6);
    int l = threadIdx.x & 63;
    if (n >= M) return;
    const bfu* base = QKV + (size_t)n * 1152;
    float q[3][2], k[3][2], v[3][2];
    #pragma unroll
    for (int p = 0; p < 3; ++p) {
        q[p][0] = bf2f(base[(0 * 3 + p) * 128 + l]);
        q[p][1] = bf2f(base[(0 * 3 + p) * 128 + l + 64]);
        k[p][0] = bf2f(base[(1 * 3 + p) * 128 + l]);
        k[p][1] = bf2f(base[(1 * 3 + p) * 128 + l + 64]);
        v[p][0] = bf2f(base[(2 * 3 + p) * 128 + l]);
        v[p][1] = bf2f(base[(2 * 3 + p) * 128 + l + 64]);
    }
    float lgA[3][3], lgB[3][3];
    #pragma unroll
    for (int qi = 0; qi < 3; ++qi)
        #pragma unroll
        for (int ki = 0; ki < 3; ++ki) {
            float s0 = q[qi][0] * k[ki][0];
            float s1 = q[qi][1] * k[ki][1];
            #pragma unroll
            for (int off = 1; off <= 16; off <<= 1) {
                s0 += __shfl_xor(s0, off);
                s1 += __shfl_xor(s1, off);
            }
            lgA[qi][ki] = s0 * 0.17677669529663687f;
            lgB[qi][ki] = s1 * 0.17677669529663687f;
        }
    float oA = 0.f, oB = 0.f;
    #pragma unroll
    for (int qi = 0; qi < 3; ++qi) {
        float mA = fmaxf(lgA[qi][0], fmaxf(lgA[qi][1], lgA[qi][2]));
        float e0 = __expf(lgA[qi][0] - mA), e1 = __expf(lgA[qi][1] - mA), e2 = __expf(lgA[qi][2] - mA);
        float rd = 1.f / (e0 + e1 + e2);
        oA += (e0 * v[0][0] + e1 * v[1][0] + e2 * v[2][0]) * rd;
        float mB = fmaxf(lgB[qi][0], fmaxf(lgB[qi][1], lgB[qi][2]));
        float f0 = __expf(lgB[qi][0] - mB), f1 = __expf(lgB[qi][1] - mB), f2 = __expf(lgB[qi][2] - mB);
        float rdB = 1.f / (f0 + f1 + f2);
        oB += (f0 * v[0][1] + f1 * v[1][1] + f2 * v[2][1]) * rdB;
    }
    OM[(size_t)n * 128 + l] = oA * (1.f / 3.f);
    OM[(size_t)n * 128 + l + 64] = oB * (1.f / 3.f);
}

extern "C" void kernel_launch(void* const* d_in, const int* in_sizes, int n_in,
                              void* d_out, int out_size, void* d_ws, size_t ws_size,
                              hipStream_t stream)
{
    const float* x_pest   = (const float*)d_in[0];
    const float* x_dis    = (const float*)d_in[1];
    const float* x_plant  = (const float*)d_in[2];
    const int*   edges    = (const int*)d_in[3];
    const float* proj_W   = (const float*)d_in[4];
    const float* proj_b   = (const float*)d_in[5];
    const float* event_emb= (const float*)d_in[6];
    const float* kqv_W    = (const float*)d_in[7];
    const float* kqv_b    = (const float*)d_in[8];
    const float* out_W    = (const float*)d_in[9];
    const float* out_b    = (const float*)d_in[10];
    const float* skip     = (const float*)d_in[11];
    const float* a_rel    = (const float*)d_in[12];
    const float* m_rel    = (const float*)d_in[13];
    const float* p_rel    = (const float*)d_in[14];
    const float* blk_ln_g = (const float*)d_in[15];
    const float* blk_ln_b = (const float*)d_in[16];
    const float* fin_W    = (const float*)d_in[17];
    const float* fin_b    = (const float*)d_in[18];
    const float* fout_W   = (const float*)d_in[19];
    const float* fout_b   = (const float*)d_in[20];
    const float* f_ln_g   = (const float*)d_in[21];
    const float* f_ln_b   = (const float*)d_in[22];
    float* out = (float*)d_out;

    static const int NT[4]  = {30000, 20000, 25000, 50000};
    static const int OFF[4] = {0, 30000, 50000, 75000};
    static const int HDST[8] = {1, 0, 1, 2, 0, 3, 2, 3};
    static const int DG[4][2][2] = { {{1,1},{4,3}}, {{0,0},{2,2}}, {{3,1},{6,3}}, {{5,0},{7,2}} };
    const int RPS = 50004;  // rowptr stride per relation

    char* wsb = (char*)d_ws;
    size_t ob = 0;
    auto alc = [&](size_t bytes) -> void* {
        void* p = wsb + ob; ob += (bytes + 255) & ~(size_t)255; return p;
    };
    bfu* LK0 = (bfu*)alc((size_t)75000 * 128 * 2);
    bfu* LK1 = (bfu*)alc((size_t)75000 * 128 * 2);
    bfu* KV  = (bfu*)alc((size_t)50000 * 128 * 2);     // K (pass1) / Vm (pass2); fusion reuse base
    float* ACC = (float*)alc((size_t)50000 * 128 * 4); // f32 agg; QA bf16 aliases its base
    float* MD  = (float*)alc((size_t)50000 * 8 * 4);
    float* LG  = (float*)alc((size_t)2 * E_CNT * 4 * 4);
    float* WQA = (float*)alc((size_t)8 * 16384 * 4);
    float* BQA = (float*)alc((size_t)8 * 128 * 4);
    float* WVM = (float*)alc((size_t)8 * 16384 * 4);
    float* BVM = (float*)alc((size_t)8 * 128 * 4);
    int* RSRC = (int*)alc(8 * 4);
    int* RDST = (int*)alc(8 * 4);
    int* RP   = (int*)alc((size_t)8 * RPS * 4);
    int* SIDX = (int*)alc((size_t)8 * E_CNT * 4);
    int* CUR  = (int*)alc((size_t)50000 * 4);
    if (ws_size < ob) {
        fill_val<<<(out_size + 255) / 256, 256, 0, stream>>>(out, out_size, 1e30f);
        return;
    }
    bfu* QA = (bfu*)ACC;  // alias: QA (pass1 input) dead before ACC (pass2 output) written

    {
        static const int h_rsrc[8] = {0, 1, 2, 1, 3, 0, 3, 2};
        static const int h_rdst[8] = {1, 0, 1, 2, 0, 3, 2, 3};
        hipMemcpyAsync(RSRC, h_rsrc, 32, hipMemcpyHostToDevice, stream);
        hipMemcpyAsync(RDST, h_rdst, 32, hipMemcpyHostToDevice, stream);
    }

    // ---- CSR build (edges identical across layers) ----
    hipMemsetAsync(RP, 0, (size_t)8 * RPS * 4, stream);
    const int eg1 = (E_CNT + 255) / 256;
    for (int r = 0; r < 8; ++r) {
        const int* dstp = edges + (size_t)(2 * r + 1) * E_CNT;
        const int* srcp = edges + (size_t)(2 * r) * E_CNT;
        int* rp = RP + (size_t)r * RPS;
        hist_k<<<eg1, 256, 0, stream>>>(dstp, rp);
        scan_k<<<1, 1024, 0, stream>>>(rp, NT[HDST[r]] + 1);
        hipMemsetAsync(CUR, 0, (size_t)NT[HDST[r]] * 4, stream);
        scatter_k<<<eg1, 256, 0, stream>>>(srcp, dstp, rp, CUR, SIDX + (size_t)r * E_CNT);
    }

    float* XIN = out;   // layer-0 projected inputs (types 0-2) live in d_out
    float* EV  = out;   // event feature chain occupies rows 0..50000 of d_out

    const float* xin0[3] = {x_pest, x_dis, x_plant};
    for (int t = 0; t < 3; ++t) {
        gemm_xwt<float, float, 64, 1><<<(NT[t] + 31) / 32, 256, 0, stream>>>(
            xin0[t], proj_W + (size_t)t * 8192, proj_b + (size_t)t * 128,
            XIN + (size_t)OFF[t] * 128, NT[t], 128);
    }

    for (int l = 0; l < 3; ++l) {
        const float* kqvW_l = kqv_W + (size_t)l * 12 * 16384;
        const float* kqvb_l = kqv_b + (size_t)l * 12 * 128;
        build_wqa<<<32, 256, 0, stream>>>(kqvW_l, kqvb_l, a_rel + (size_t)l * 8 * 4096, WQA, BQA, RDST);
        build_wvm<<<32, 256, 0, stream>>>(kqvW_l, kqvb_l, m_rel + (size_t)l * 8 * 4096, WVM, BVM, RSRC);

        auto feat_gemm = [&](int tt, const float* Wp, const float* Bp, bfu* Yp) {
            int Nn = NT[tt];
            int gb = (Nn + 31) / 32;
            if (l == 0) {
                const float* Xp = (tt < 3) ? (XIN + (size_t)OFF[tt] * 128) : event_emb;
                gemm_xwt<float, bfu, 128, 0><<<gb, 256, 0, stream>>>(Xp, Wp, Bp, Yp, Nn, 128);
            } else if (tt == 3) {
                gemm_xwt<float, bfu, 128, 0><<<gb, 256, 0, stream>>>(EV, Wp, Bp, Yp, Nn, 128);
            } else {
                const bfu* Xp = (l == 1 ? LK0 : LK1) + (size_t)OFF[tt] * 128;
                gemm_xwt<bfu, bfu, 128, 0><<<gb, 256, 0, stream>>>(Xp, Wp, Bp, Yp, Nn, 128);
            }
        };

        int order[4] = {0, 1, 2, 3};
        int nord = 4;
        if (l == 2) { order[0] = 2; order[1] = 0; order[2] = 1; nord = 3; }

        for (int oi = 0; oi < nord; ++oi) {
            int dt = order[oi];
            int Ndt = NT[dt];
            int ab = (Ndt + 3) / 4;
            // pass 1: logits + online max/den (QA aliases ACC base; dead before pass 2)
            for (int gi = 0; gi < 2; ++gi) {
                int r = DG[dt][gi][0], s = DG[dt][gi][1];
                feat_gemm(dt, WQA + (size_t)r * 16384, BQA + (size_t)r * 128, QA);
                feat_gemm(s, kqvW_l + ((size_t)s * 3 + 0) * 16384,
                          kqvb_l + ((size_t)s * 3 + 0) * 128, KV);
                if (gi == 0)
                    agg_pass1<1><<<ab, 256, 0, stream>>>(QA, KV, RP + (size_t)r * RPS,
                        SIDX + (size_t)r * E_CNT, p_rel + (size_t)(l * 8 + r) * 4,
                        LG + (size_t)gi * E_CNT * 4, MD, Ndt);
                else
                    agg_pass1<0><<<ab, 256, 0, stream>>>(QA, KV, RP + (size_t)r * RPS,
                        SIDX + (size_t)r * E_CNT, p_rel + (size_t)(l * 8 + r) * 4,
                        LG + (size_t)gi * E_CNT * 4, MD, Ndt);
            }
            // pass 2: normalized weighted gather
            for (int gi = 0; gi < 2; ++gi) {
                int r = DG[dt][gi][0], s = DG[dt][gi][1];
                feat_gemm(s, WVM + (size_t)r * 16384, BVM + (size_t)r * 128, KV);
                if (gi == 0)
                    agg_pass2<1><<<ab, 256, 0, stream>>>(KV, RP + (size_t)r * RPS,
                        SIDX + (size_t)r * E_CNT, LG + (size_t)gi * E_CNT * 4, MD, ACC, Ndt);
                else
                    agg_pass2<0><<<ab, 256, 0, stream>>>(KV, RP + (size_t)r * RPS,
                        SIDX + (size_t)r * E_CNT, LG + (size_t)gi * E_CNT * 4, MD, ACC, Ndt);
            }
            // epilogue: gelu -> out-proj -> skip -> LN -> relu (all fused)
            size_t wi = (size_t)l * 4 + dt;
            const float* Wo = out_W + wi * 16384;
            const float* bo = out_b + wi * 128;
            const float* sk = skip + wi;
            const float* lg_ = blk_ln_g + (size_t)l * 128;
            const float* lb_ = blk_ln_b + (size_t)l * 128;
            int gb = (Ndt + 31) / 32;
            if (l == 0) {
                if (dt < 3)
                    gemm_epi<float, bfu, 0><<<gb, 256, 0, stream>>>(
                        ACC, Wo, bo, XIN + (size_t)OFF[dt] * 128, sk, lg_, lb_,
                        LK0 + (size_t)OFF[dt] * 128, Ndt);
                else
                    gemm_epi<float, float, 0><<<gb, 256, 0, stream>>>(
                        ACC, Wo, bo, event_emb, sk, lg_, lb_, EV, Ndt);
            } else if (l == 1) {
                if (dt < 3)
                    gemm_epi<bfu, bfu, 0><<<gb, 256, 0, stream>>>(
                        ACC, Wo, bo, LK0 + (size_t)OFF[dt] * 128, sk, lg_, lb_,
                        LK1 + (size_t)OFF[dt] * 128, Ndt);
                else
                    gemm_epi<float, float, 0><<<gb, 256, 0, stream>>>(
                        ACC, Wo, bo, EV, sk, lg_, lb_, EV, Ndt);
            } else {
                gemm_epi<bfu, float, 0><<<gb, 256, 0, stream>>>(
                    ACC, Wo, bo, LK1 + (size_t)OFF[dt] * 128, sk, lg_, lb_,
                    out + (size_t)OFF[dt] * 128, Ndt);
            }
        }
    }

    // ---- fusion heads: QKV GEMMs -> attention -> out-proj+LN ----
    const int CH = 15000;
    bfu* QKVf = KV;                                  // reuse region (KV+ACC+MD+LG)
    float* OMf = (float*)((char*)KV + (size_t)CH * 1152 * 2);
    for (int j = 0; j < 3; ++j) {
        int Nj = NT[j];
        for (int b0 = 0; b0 < Nj; b0 += CH) {
            int M = min(CH, Nj - b0);
            int gb = (M + 31) / 32;
            for (int kk = 0; kk < 3; ++kk) {
                const float* Wk = fin_W + (size_t)j * 49152 + (size_t)kk * 16384;
                const float* bk = fin_b + (size_t)j * 384 + kk * 128;
                gemm_xwt<bfu, bfu, 128, 0><<<gb, 256, 0, stream>>>(
                    LK0 + (size_t)(OFF[j] + b0) * 128, Wk, bk,
                    QKVf + (kk * 3 + 0) * 128, M, 1152);
                gemm_xwt<bfu, bfu, 128, 0><<<gb, 256, 0, stream>>>(
                    LK1 + (size_t)(OFF[j] + b0) * 128, Wk, bk,
                    QKVf + (kk * 3 + 1) * 128, M, 1152);
                gemm_xwt<float, bfu, 128, 0><<<gb, 256, 0, stream>>>(
                    out + (size_t)(OFF[j] + b0) * 128, Wk, bk,
                    QKVf + (kk * 3 + 2) * 128, M, 1152);
            }
            attn_fuse<<<(M + 3) / 4, 256, 0, stream>>>(QKVf, OMf, M);
            gemm_epi<float, float, 1><<<gb, 256, 0, stream>>>(
                OMf, fout_W + (size_t)j * 16384, fout_b + (size_t)j * 128,
                (const float*)nullptr, nullptr,
                f_ln_g + (size_t)j * 128, f_ln_b + (size_t)j * 128,
                out + (size_t)(OFF[j] + b0) * 128, M);
        }
    }
}

// Round 5
// 3693.999 us; speedup vs baseline: 3.3556x; 1.2888x over previous
//
#include <hip/hip_runtime.h>
#include <math.h>

#define E_CNT 200000
typedef unsigned short bfu;
typedef __attribute__((ext_vector_type(8))) short bh8;
typedef __attribute__((ext_vector_type(4))) float f4;

__device__ __forceinline__ float gelu_f(float x) {
    return 0.5f * x * (1.0f + erff(x * 0.70710678118654752f));
}
__device__ __forceinline__ float bf2f(bfu u) { return __uint_as_float(((unsigned)u) << 16); }
__device__ __forceinline__ bfu f2bf(float f) {
    unsigned u = __float_as_uint(f);
    unsigned r = u + 0x7FFFu + ((u >> 16) & 1u);
    return (bfu)(r >> 16);
}
// relation tables: r -> src type / dst type
__device__ __forceinline__ int rsrc_of(int r) {
    const int a[8] = {0, 1, 2, 1, 3, 0, 3, 2}; return a[r];
}
__device__ __forceinline__ int rdst_of(int r) {
    const int a[8] = {1, 0, 1, 2, 0, 3, 2, 3}; return a[r];
}
// packed rowptr offsets per relation (len = Ndst[r]+1)
__device__ __forceinline__ int rpoff_of(int r) {
    const int a[9] = {0, 20001, 50002, 70003, 95004, 125005, 175006, 200007, 250008};
    return a[r];
}

__global__ __launch_bounds__(256) void fill_val(float* p, int n, float v) {
    int i = blockIdx.x * 256 + threadIdx.x;
    if (i < n) p[i] = v;
}

// ---- f32 -> bf16 converts ----
__global__ __launch_bounds__(256) void cvt_f2b(const float* __restrict__ s, bfu* __restrict__ d, int n4) {
    int i = blockIdx.x * 256 + threadIdx.x;
    if (i >= n4) return;
    float4 v = *(const float4*)(s + (size_t)i * 4);
    uint2 u;
    u.x = ((unsigned)f2bf(v.x)) | (((unsigned)f2bf(v.y)) << 16);
    u.y = ((unsigned)f2bf(v.z)) | (((unsigned)f2bf(v.w)) << 16);
    *(uint2*)(d + (size_t)i * 4) = u;
}
// K weights: mat m in 0..11, src = kqv_W[m*3*16384 + off]
__global__ __launch_bounds__(256) void cvt_kw(const float* __restrict__ s, bfu* __restrict__ d) {
    int i = blockIdx.x * 256 + threadIdx.x;
    if (i >= 12 * 4096) return;
    int m = i >> 12, off4 = (i & 4095) * 4;
    float4 v = *(const float4*)(s + (size_t)m * 3 * 16384 + off4);
    uint2 u;
    u.x = ((unsigned)f2bf(v.x)) | (((unsigned)f2bf(v.y)) << 16);
    u.y = ((unsigned)f2bf(v.z)) | (((unsigned)f2bf(v.w)) << 16);
    *(uint2*)(d + (size_t)m * 16384 + off4) = u;
}

// ---- CSR build ----
__global__ __launch_bounds__(256) void hist_all(const int* __restrict__ edges, int* __restrict__ rp) {
    int i = blockIdx.x * 256 + threadIdx.x;
    if (i >= 8 * E_CNT) return;
    int r = i / E_CNT, e = i - r * E_CNT;
    int d = edges[(size_t)(2 * r + 1) * E_CNT + e];
    atomicAdd(&rp[rpoff_of(r) + d + 1], 1);
}
__global__ __launch_bounds__(1024) void scan8(int* __restrict__ RP) {
    __shared__ int lds[1024];
    int r = blockIdx.x;
    int* a = RP + rpoff_of(r);
    int len = rpoff_of(r + 1) - rpoff_of(r);
    int t = threadIdx.x;
    int chunk = (len + 1023) >> 10;
    int lo = t * chunk, hi = min(lo + chunk, len);
    int s = 0;
    for (int i = lo; i < hi; ++i) s += a[i];
    lds[t] = s;
    __syncthreads();
    for (int off = 1; off < 1024; off <<= 1) {
        int v = (t >= off) ? lds[t - off] : 0;
        __syncthreads();
        lds[t] += v;
        __syncthreads();
    }
    int pre = lds[t] - s;
    for (int i = lo; i < hi; ++i) { pre += a[i]; a[i] = pre; }
}
__global__ __launch_bounds__(256) void scatter_all(
    const int* __restrict__ edges, const int* __restrict__ RP,
    int* __restrict__ cur, int* __restrict__ SIDX) {
    int i = blockIdx.x * 256 + threadIdx.x;
    if (i >= 8 * E_CNT) return;
    int r = i / E_CNT, e = i - r * E_CNT;
    int d = edges[(size_t)(2 * r + 1) * E_CNT + e];
    int pos = RP[rpoff_of(r) + d] + atomicAdd(&cur[r * 50000 + d], 1);
    SIDX[(size_t)r * E_CNT + pos] = edges[(size_t)(2 * r) * E_CNT + e];
}

// ---- input projection: f32[N,64] @ W[128,64]^T + b, relu, bf16 out (VALU; small) ----
__global__ __launch_bounds__(256) void proj_gemm(
    const float* __restrict__ X, const float* __restrict__ W,
    const float* __restrict__ bias, bfu* __restrict__ Y, int N)
{
    __shared__ __align__(16) float Wt[32][132];
    __shared__ __align__(16) float Xt[32][36];
    const int tid = threadIdx.x;
    const int r0 = blockIdx.x * 32;
    const int rg = tid >> 5, cg = tid & 31;
    float acc[4][4];
    #pragma unroll
    for (int i = 0; i < 4; ++i)
        #pragma unroll
        for (int j = 0; j < 4; ++j) acc[i][j] = 0.f;
    for (int c0 = 0; c0 < 64; c0 += 32) {
        __syncthreads();
        #pragma unroll
        for (int k = 0; k < 4; ++k) {
            int v = tid + k * 256;
            int j = v >> 3, c4 = (v & 7) * 4;
            float4 w = *(const float4*)(W + (size_t)j * 64 + c0 + c4);
            Wt[c4 + 0][j] = w.x; Wt[c4 + 1][j] = w.y;
            Wt[c4 + 2][j] = w.z; Wt[c4 + 3][j] = w.w;
        }
        {
            int rr = tid >> 3, c4 = (tid & 7) * 4;
            int row = r0 + rr;
            float4 x = make_float4(0.f, 0.f, 0.f, 0.f);
            if (row < N) x = *(const float4*)(X + (size_t)row * 64 + c0 + c4);
            Xt[c4 + 0][rr] = x.x; Xt[c4 + 1][rr] = x.y;
            Xt[c4 + 2][rr] = x.z; Xt[c4 + 3][rr] = x.w;
        }
        __syncthreads();
        #pragma unroll
        for (int cc = 0; cc < 32; ++cc) {
            float4 xv = *(const float4*)(&Xt[cc][rg * 4]);
            float4 wv = *(const float4*)(&Wt[cc][cg * 4]);
            #pragma unroll
            for (int i = 0; i < 4; ++i) {
                float xs = (i == 0) ? xv.x : (i == 1) ? xv.y : (i == 2) ? xv.z : xv.w;
                acc[i][0] = fmaf(xs, wv.x, acc[i][0]);
                acc[i][1] = fmaf(xs, wv.y, acc[i][1]);
                acc[i][2] = fmaf(xs, wv.z, acc[i][2]);
                acc[i][3] = fmaf(xs, wv.w, acc[i][3]);
            }
        }
    }
    float4 bv = *(const float4*)(bias + cg * 4);
    #pragma unroll
    for (int ri = 0; ri < 4; ++ri) {
        int row = r0 + rg * 4 + ri;
        if (row >= N) continue;
        float y0 = fmaxf(acc[ri][0] + bv.x, 0.f);
        float y1 = fmaxf(acc[ri][1] + bv.y, 0.f);
        float y2 = fmaxf(acc[ri][2] + bv.z, 0.f);
        float y3 = fmaxf(acc[ri][3] + bv.w, 0.f);
        uint2 u;
        u.x = ((unsigned)f2bf(y0)) | (((unsigned)f2bf(y1)) << 16);
        u.y = ((unsigned)f2bf(y2)) | (((unsigned)f2bf(y3)) << 16);
        *(uint2*)(Y + (size_t)row * 128 + cg * 4) = u;
    }
}

// ---- MFMA GEMM: Y[N,128] = epi( X[N,128]bf16 @ W[128,128]bf16^T + bias ) ----
// EPI 0: bf16 store (ldy). EPI 1: skip+LN+relu, bf16 store. EPI 2: LN, f32 store.
template<int EPI>
__global__ __launch_bounds__(256) void mgemm(
    const bfu* __restrict__ X, const bfu* __restrict__ W,
    const float* __restrict__ bias, const bfu* __restrict__ Xr,
    const float* __restrict__ skp, const float* __restrict__ g,
    const float* __restrict__ bb, void* __restrict__ Y, int N, int ldy)
{
    const int tid = threadIdx.x;
    const int wave = tid >> 6, lane = tid & 63;
    const int row16 = lane & 15, kgrp = lane >> 4;
    const int r_base = blockIdx.x * 64 + wave * 16;
    const int arow = r_base + row16;

    f4 acc[8];
    #pragma unroll
    for (int n = 0; n < 8; ++n) acc[n] = (f4){0.f, 0.f, 0.f, 0.f};
    bh8 az = {0, 0, 0, 0, 0, 0, 0, 0};

    #pragma unroll
    for (int kb = 0; kb < 4; ++kb) {
        bh8 a = az;
        if (arow < N) a = *(const bh8*)(X + (size_t)arow * 128 + kb * 32 + kgrp * 8);
        #pragma unroll
        for (int n = 0; n < 8; ++n) {
            bh8 b = *(const bh8*)(W + (size_t)(n * 16 + row16) * 128 + kb * 32 + kgrp * 8);
            acc[n] = __builtin_amdgcn_mfma_f32_16x16x32_bf16(a, b, acc[n], 0, 0, 0);
        }
    }

    float bn[8];
    #pragma unroll
    for (int n = 0; n < 8; ++n) bn[n] = bias[n * 16 + row16];
    const int crow0 = r_base + kgrp * 4;

    if (EPI == 0) {
        bfu* Yb = (bfu*)Y;
        #pragma unroll
        for (int n = 0; n < 8; ++n) {
            int col = n * 16 + row16;
            #pragma unroll
            for (int j = 0; j < 4; ++j) {
                int row = crow0 + j;
                if (row < N) Yb[(size_t)row * ldy + col] = f2bf(acc[n][j] + bn[n]);
            }
        }
        return;
    }

    float z[8][4];
    #pragma unroll
    for (int n = 0; n < 8; ++n)
        #pragma unroll
        for (int j = 0; j < 4; ++j) z[n][j] = acc[n][j] + bn[n];

    if (EPI == 1) {
        float sg = 1.f / (1.f + expf(-skp[0]));
        #pragma unroll
        for (int j = 0; j < 4; ++j) {
            int row = crow0 + j;
            if (row >= N) continue;
            #pragma unroll
            for (int n = 0; n < 8; ++n) {
                float xr = bf2f(Xr[(size_t)row * 128 + n * 16 + row16]);
                z[n][j] = sg * z[n][j] + (1.f - sg) * xr + xr;
            }
        }
    }
    float s[4], q[4];
    #pragma unroll
    for (int j = 0; j < 4; ++j) {
        s[j] = 0.f; q[j] = 0.f;
        #pragma unroll
        for (int n = 0; n < 8; ++n) { s[j] += z[n][j]; q[j] += z[n][j] * z[n][j]; }
    }
    #pragma unroll
    for (int off = 1; off <= 8; off <<= 1) {
        #pragma unroll
        for (int j = 0; j < 4; ++j) {
            s[j] += __shfl_xor(s[j], off);
            q[j] += __shfl_xor(q[j], off);
        }
    }
    float gv[8], bv2[8];
    #pragma unroll
    for (int n = 0; n < 8; ++n) {
        gv[n] = g[n * 16 + row16];
        bv2[n] = bb[n * 16 + row16];
    }
    #pragma unroll
    for (int j = 0; j < 4; ++j) {
        int row = crow0 + j;
        if (row >= N) continue;
        float mean = s[j] * (1.f / 128.f);
        float var = q[j] * (1.f / 128.f) - mean * mean;
        float inv = rsqrtf(var + 1e-5f);
        #pragma unroll
        for (int n = 0; n < 8; ++n) {
            float y = (z[n][j] - mean) * inv * gv[n] + bv2[n];
            int col = n * 16 + row16;
            if (EPI == 1) {
                ((bfu*)Y)[(size_t)row * ldy + col] = f2bf(fmaxf(y, 0.f));
            } else {
                ((float*)Y)[(size_t)row * ldy + col] = y;
            }
        }
    }
}

// ---- relation-folded weight builders (bf16 weight out, f32 bias) ----
__global__ __launch_bounds__(256) void build_wqa(
    const float* __restrict__ kqvW_l, const float* __restrict__ kqvb_l,
    const float* __restrict__ a_l, bfu* __restrict__ WQA, float* __restrict__ BQA)
{
    int r = blockIdx.x >> 2, h = blockIdx.x & 3;
    int dt = rdst_of(r);
    const float* Wq = kqvW_l + ((size_t)dt * 3 + 1) * 16384;
    const float* bq = kqvb_l + ((size_t)dt * 3 + 1) * 128;
    const float* A = a_l + (size_t)r * 4096 + h * 1024;
    __shared__ float As[32][33];
    __shared__ float Ws[32][129];
    int tid = threadIdx.x;
    for (int v = tid; v < 1024; v += 256) As[v >> 5][v & 31] = A[v];
    for (int v = tid; v < 4096; v += 256)
        Ws[v >> 7][v & 127] = Wq[(size_t)(h * 32 + (v >> 7)) * 128 + (v & 127)];
    __syncthreads();
    int c = tid & 127, half = tid >> 7;
    for (int d = half; d < 32; d += 2) {
        float acc = 0.f;
        #pragma unroll
        for (int f = 0; f < 32; ++f) acc = fmaf(As[d][f], Ws[f][c], acc);
        WQA[((size_t)r * 128 + h * 32 + d) * 128 + c] = f2bf(acc);
    }
    if (tid < 32) {
        int d = tid;
        float acc = 0.f;
        #pragma unroll
        for (int f = 0; f < 32; ++f) acc = fmaf(As[d][f], bq[h * 32 + f], acc);
        BQA[(size_t)r * 128 + h * 32 + d] = acc;
    }
}
__global__ __launch_bounds__(256) void build_wvm(
    const float* __restrict__ kqvW_l, const float* __restrict__ kqvb_l,
    const float* __restrict__ m_l, bfu* __restrict__ WVM, float* __restrict__ BVM)
{
    int r = blockIdx.x >> 2, h = blockIdx.x & 3;
    int st = rsrc_of(r);
    const float* Wv = kqvW_l + ((size_t)st * 3 + 2) * 16384;
    const float* bv = kqvb_l + ((size_t)st * 3 + 2) * 128;
    const float* M = m_l + (size_t)r * 4096 + h * 1024;
    __shared__ float Ms[32][33];
    __shared__ float Ws[32][129];
    int tid = threadIdx.x;
    for (int v = tid; v < 1024; v += 256) Ms[v >> 5][v & 31] = M[v];
    for (int v = tid; v < 4096; v += 256)
        Ws[v >> 7][v & 127] = Wv[(size_t)(h * 32 + (v >> 7)) * 128 + (v & 127)];
    __syncthreads();
    int c = tid & 127, half = tid >> 7;
    for (int f = half; f < 32; f += 2) {
        float acc = 0.f;
        #pragma unroll
        for (int d = 0; d < 32; ++d) acc = fmaf(Ms[d][f], Ws[d][c], acc);
        WVM[((size_t)r * 128 + h * 32 + f) * 128 + c] = f2bf(acc);
    }
    if (tid < 32) {
        int f = tid;
        float acc = 0.f;
        #pragma unroll
        for (int d = 0; d < 32; ++d) acc = fmaf(Ms[d][f], bv[h * 32 + d], acc);
        BVM[(size_t)r * 128 + h * 32 + f] = acc;
    }
}

// ---- CSR aggregation (wave per dst node) ----
template<int FIRST>
__global__ __launch_bounds__(256) void agg_pass1(
    const bfu* __restrict__ QA, const bfu* __restrict__ K,
    const int* __restrict__ rp, const int* __restrict__ sidx,
    const float* __restrict__ prl, float* __restrict__ LG,
    float* __restrict__ MD, int Nn)
{
    int n = blockIdx.x * 4 + (threadIdx.x >> 6);
    int l = threadIdx.x & 63;
    if (n >= Nn) return;
    int hA = l >> 5;
    float pA = prl[hA] * 0.17677669529663687f;
    float pB = prl[2 + hA] * 0.17677669529663687f;
    float q0 = bf2f(QA[(size_t)n * 128 + l]);
    float q1 = bf2f(QA[(size_t)n * 128 + l + 64]);
    float m0, d0, m1, d1;
    if (FIRST) { m0 = m1 = -3.0e38f; d0 = d1 = 0.f; }
    else {
        m0 = MD[n * 8 + hA];     m1 = MD[n * 8 + 2 + hA];
        d0 = MD[n * 8 + 4 + hA]; d1 = MD[n * 8 + 6 + hA];
    }
    int e0 = rp[n], e1 = rp[n + 1];
    for (int i = e0; i < e1; ++i) {
        int sn = sidx[i];
        float s0 = bf2f(K[(size_t)sn * 128 + l]) * q0;
        float s1 = bf2f(K[(size_t)sn * 128 + l + 64]) * q1;
        #pragma unroll
        for (int off = 1; off <= 16; off <<= 1) {
            s0 += __shfl_xor(s0, off);
            s1 += __shfl_xor(s1, off);
        }
        s0 *= pA; s1 *= pB;
        if (l == 0 || l == 32) {
            LG[(size_t)i * 4 + hA] = s0;
            LG[(size_t)i * 4 + 2 + hA] = s1;
        }
        float nm0 = fmaxf(m0, s0);
        d0 = d0 * __expf(m0 - nm0) + __expf(s0 - nm0);
        m0 = nm0;
        float nm1 = fmaxf(m1, s1);
        d1 = d1 * __expf(m1 - nm1) + __expf(s1 - nm1);
        m1 = nm1;
    }
    if (l == 0 || l == 32) {
        MD[n * 8 + hA] = m0;     MD[n * 8 + 2 + hA] = m1;
        MD[n * 8 + 4 + hA] = d0; MD[n * 8 + 6 + hA] = d1;
    }
}
template<int FIRST>
__global__ __launch_bounds__(256) void agg_pass2(
    const bfu* __restrict__ VM, const int* __restrict__ rp,
    const int* __restrict__ sidx, const float* __restrict__ LG,
    const float* __restrict__ MD, float* __restrict__ ACC, int Nn)
{
    int n = blockIdx.x * 4 + (threadIdx.x >> 6);
    int l = threadIdx.x & 63;
    if (n >= Nn) return;
    int hA = l >> 5;
    float mA = MD[n * 8 + hA], mB = MD[n * 8 + 2 + hA];
    float rdA = 1.f / fmaxf(MD[n * 8 + 4 + hA], 1e-16f);
    float rdB = 1.f / fmaxf(MD[n * 8 + 6 + hA], 1e-16f);
    float a0, a1;
    if (FIRST) { a0 = a1 = 0.f; }
    else { a0 = ACC[(size_t)n * 128 + l]; a1 = ACC[(size_t)n * 128 + l + 64]; }
    int e0 = rp[n], e1 = rp[n + 1];
    for (int i = e0; i < e1; ++i) {
        int sn = sidx[i];
        float w0 = __expf(LG[(size_t)i * 4 + hA] - mA) * rdA;
        float w1 = __expf(LG[(size_t)i * 4 + 2 + hA] - mB) * rdB;
        a0 = fmaf(w0, bf2f(VM[(size_t)sn * 128 + l]), a0);
        a1 = fmaf(w1, bf2f(VM[(size_t)sn * 128 + l + 64]), a1);
    }
    ACC[(size_t)n * 128 + l] = a0;
    ACC[(size_t)n * 128 + l + 64] = a1;
}

// ---- gelu + bf16 convert ----
__global__ __launch_bounds__(256) void gelu_cvt(const float* __restrict__ s, bfu* __restrict__ d, int n4) {
    int i = blockIdx.x * 256 + threadIdx.x;
    if (i >= n4) return;
    float4 v = *(const float4*)(s + (size_t)i * 4);
    v.x = gelu_f(v.x); v.y = gelu_f(v.y); v.z = gelu_f(v.z); v.w = gelu_f(v.w);
    uint2 u;
    u.x = ((unsigned)f2bf(v.x)) | (((unsigned)f2bf(v.y)) << 16);
    u.y = ((unsigned)f2bf(v.z)) | (((unsigned)f2bf(v.w)) << 16);
    *(uint2*)(d + (size_t)i * 4) = u;
}

// ---- fusion attention (3 tokens, 4 heads), wave per node, bf16 out ----
__global__ __launch_bounds__(256) void attn_fuse(
    const bfu* __restrict__ QKV, bfu* __restrict__ OM, int M)
{
    int n = blockIdx.x * 4 + (threadIdx.x >> 6);
    int l = threadIdx.x & 63;
    if (n >= M) return;
    const bfu* base = QKV + (size_t)n * 1152;
    float q[3][2], k[3][2], v[3][2];
    #pragma unroll
    for (int p = 0; p < 3; ++p) {
        q[p][0] = bf2f(base[(0 * 3 + p) * 128 + l]);
        q[p][1] = bf2f(base[(0 * 3 + p) * 128 + l + 64]);
        k[p][0] = bf2f(base[(1 * 3 + p) * 128 + l]);
        k[p][1] = bf2f(base[(1 * 3 + p) * 128 + l + 64]);
        v[p][0] = bf2f(base[(2 * 3 + p) * 128 + l]);
        v[p][1] = bf2f(base[(2 * 3 + p) * 128 + l + 64]);
    }
    float lgA[3][3], lgB[3][3];
    #pragma unroll
    for (int qi = 0; qi < 3; ++qi)
        #pragma unroll
        for (int ki = 0; ki < 3; ++ki) {
            float s0 = q[qi][0] * k[ki][0];
            float s1 = q[qi][1] * k[ki][1];
            #pragma unroll
            for (int off = 1; off <= 16; off <<= 1) {
                s0 += __shfl_xor(s0, off);
                s1 += __shfl_xor(s1, off);
            }
            lgA[qi][ki] = s0 * 0.17677669529663687f;
            lgB[qi][ki] = s1 * 0.17677669529663687f;
        }
    float oA = 0.f, oB = 0.f;
    #pragma unroll
    for (int qi = 0; qi < 3; ++qi) {
        float mA = fmaxf(lgA[qi][0], fmaxf(lgA[qi][1], lgA[qi][2]));
        float e0 = __expf(lgA[qi][0] - mA), e1 = __expf(lgA[qi][1] - mA), e2 = __expf(lgA[qi][2] - mA);
        float rd = 1.f / (e0 + e1 + e2);
        oA += (e0 * v[0][0] + e1 * v[1][0] + e2 * v[2][0]) * rd;
        float mB = fmaxf(lgB[qi][0], fmaxf(lgB[qi][1], lgB[qi][2]));
        float f0 = __expf(lgB[qi][0] - mB), f1 = __expf(lgB[qi][1] - mB), f2 = __expf(lgB[qi][2] - mB);
        float rdB = 1.f / (f0 + f1 + f2);
        oB += (f0 * v[0][1] + f1 * v[1][1] + f2 * v[2][1]) * rdB;
    }
    OM[(size_t)n * 128 + l] = f2bf(oA * (1.f / 3.f));
    OM[(size_t)n * 128 + l + 64] = f2bf(oB * (1.f / 3.f));
}

extern "C" void kernel_launch(void* const* d_in, const int* in_sizes, int n_in,
                              void* d_out, int out_size, void* d_ws, size_t ws_size,
                              hipStream_t stream)
{
    const float* x_pest   = (const float*)d_in[0];
    const float* x_dis    = (const float*)d_in[1];
    const float* x_plant  = (const float*)d_in[2];
    const int*   edges    = (const int*)d_in[3];
    const float* proj_W   = (const float*)d_in[4];
    const float* proj_b   = (const float*)d_in[5];
    const float* event_emb= (const float*)d_in[6];
    const float* kqv_W    = (const float*)d_in[7];
    const float* kqv_b    = (const float*)d_in[8];
    const float* out_W    = (const float*)d_in[9];
    const float* out_b    = (const float*)d_in[10];
    const float* skip     = (const float*)d_in[11];
    const float* a_rel    = (const float*)d_in[12];
    const float* m_rel    = (const float*)d_in[13];
    const float* p_rel    = (const float*)d_in[14];
    const float* blk_ln_g = (const float*)d_in[15];
    const float* blk_ln_b = (const float*)d_in[16];
    const float* fin_W    = (const float*)d_in[17];
    const float* fin_b    = (const float*)d_in[18];
    const float* fout_W   = (const float*)d_in[19];
    const float* fout_b   = (const float*)d_in[20];
    const float* f_ln_g   = (const float*)d_in[21];
    const float* f_ln_b   = (const float*)d_in[22];
    float* out = (float*)d_out;

    static const int NT[4]  = {30000, 20000, 25000, 50000};
    static const int OFF[4] = {0, 30000, 50000, 75000};
    static const int RPOFF[9] = {0, 20001, 50002, 70003, 95004, 125005, 175006, 200007, 250008};
    // per-dst groups: dt -> {(r, src)}
    static const int DG[4][2][2] = { {{1,1},{4,3}}, {{0,0},{2,2}}, {{3,1},{6,3}}, {{5,0},{7,2}} };

    char* wsb = (char*)d_ws;
    size_t ob = 0;
    auto alc = [&](size_t bytes) -> void* {
        void* p = wsb + ob; ob += (bytes + 255) & ~(size_t)255; return p;
    };
    bfu* LK0  = (bfu*)alc((size_t)75000 * 128 * 2);
    bfu* LK1  = (bfu*)alc((size_t)75000 * 128 * 2);
    bfu* KV   = (bfu*)alc((size_t)50000 * 128 * 2);    // K / Vm staging; AGB + fusion QKV alias
    float* ACC = (float*)alc((size_t)50000 * 128 * 4); // f32 agg; QA bf16 aliases base; fusion QKV spans
    float* MD  = (float*)alc((size_t)50000 * 8 * 4);   // max/den; CSR CUR aliases
    float* LG  = (float*)alc((size_t)2 * E_CNT * 4 * 4); // logits; fusion OMB aliases
    bfu* WQAB = (bfu*)alc((size_t)8 * 16384 * 2);
    float* BQA = (float*)alc((size_t)8 * 128 * 4);
    bfu* WVMB = (bfu*)alc((size_t)8 * 16384 * 2);
    float* BVM = (float*)alc((size_t)8 * 128 * 4);
    bfu* KWB  = (bfu*)alc((size_t)12 * 16384 * 2);
    bfu* OWB  = (bfu*)alc((size_t)12 * 16384 * 2);
    bfu* FINWB = (bfu*)alc((size_t)3 * 49152 * 2);
    bfu* FOUTWB = (bfu*)alc((size_t)3 * 16384 * 2);
    int* RP   = (int*)alc((size_t)250008 * 4);
    int* SIDX = (int*)alc((size_t)8 * E_CNT * 4);
    if (ws_size < ob) {
        fill_val<<<(out_size + 255) / 256, 256, 0, stream>>>(out, out_size, 1e30f);
        return;
    }
    bfu* QA  = (bfu*)ACC;   // pass1 input, dead before ACC written
    bfu* AGB = KV;          // gelu'd agg, written after KV's VM is dead
    int* CUR = (int*)MD;    // CSR counters, before MD use
    bfu* QKVf = KV;         // fusion: spans KV+ACC (contiguous, 38.4MB >= 34.6MB)
    bfu* OMB  = (bfu*)LG;   // fusion attention output (3.84MB <= 6.4MB)

    // d_out overlay (time-disjoint): EVB [0,12.8M); XB [12.8M,32M); L2F [19.2M,38.4M)
    bfu* EVB = (bfu*)out;
    bfu* XB  = (bfu*)((char*)out + 12800000);
    bfu* L2F = (bfu*)((char*)out + 19200000);

    // ---- weight converts ----
    cvt_f2b<<<(12 * 4096 + 255) / 256, 256, 0, stream>>>(out_W, OWB, 12 * 4096);
    cvt_kw<<<(12 * 4096 + 255) / 256, 256, 0, stream>>>(kqv_W, KWB);
    cvt_f2b<<<(3 * 12288 + 255) / 256, 256, 0, stream>>>(fin_W, FINWB, 3 * 12288);
    cvt_f2b<<<(3 * 4096 + 255) / 256, 256, 0, stream>>>(fout_W, FOUTWB, 3 * 4096);
    cvt_f2b<<<(50000 * 32 + 255) / 256, 256, 0, stream>>>(event_emb, EVB, 50000 * 32);

    // ---- CSR build ----
    hipMemsetAsync(RP, 0, (size_t)250008 * 4, stream);
    const int eg8 = (8 * E_CNT + 255) / 256;
    hist_all<<<eg8, 256, 0, stream>>>(edges, RP);
    scan8<<<8, 1024, 0, stream>>>(RP);
    hipMemsetAsync(CUR, 0, (size_t)50000 * 8 * 4, stream);
    scatter_all<<<eg8, 256, 0, stream>>>(edges, RP, CUR, SIDX);

    // ---- input projections ----
    const float* xin0[3] = {x_pest, x_dis, x_plant};
    for (int t = 0; t < 3; ++t) {
        proj_gemm<<<(NT[t] + 31) / 32, 256, 0, stream>>>(
            xin0[t], proj_W + (size_t)t * 8192, proj_b + (size_t)t * 128,
            XB + (size_t)OFF[t] * 128, NT[t]);
    }

    for (int l = 0; l < 3; ++l) {
        const float* kqvW_l = kqv_W + (size_t)l * 12 * 16384;
        const float* kqvb_l = kqv_b + (size_t)l * 12 * 128;
        build_wqa<<<32, 256, 0, stream>>>(kqvW_l, kqvb_l, a_rel + (size_t)l * 8 * 4096, WQAB, BQA);
        build_wvm<<<32, 256, 0, stream>>>(kqvW_l, kqvb_l, m_rel + (size_t)l * 8 * 4096, WVMB, BVM);

        auto feat_ptr = [&](int tt) -> const bfu* {
            if (tt == 3) return EVB;
            if (l == 0) return XB + (size_t)OFF[tt] * 128;
            return (l == 1 ? LK0 : LK1) + (size_t)OFF[tt] * 128;
        };

        int nord = (l == 2) ? 3 : 4;
        for (int dt = 0; dt < nord; ++dt) {
            int Ndt = NT[dt];
            int ab = (Ndt + 3) / 4;
            int mg = (Ndt + 63) / 64;
            // pass 1: Qa gemm, K gemm, logits + online max/den
            for (int gi = 0; gi < 2; ++gi) {
                int r = DG[dt][gi][0], s = DG[dt][gi][1];
                int mgs = (NT[s] + 63) / 64;
                mgemm<0><<<mg, 256, 0, stream>>>(
                    feat_ptr(dt), WQAB + (size_t)r * 16384, BQA + (size_t)r * 128,
                    nullptr, nullptr, nullptr, nullptr, QA, Ndt, 128);
                mgemm<0><<<mgs, 256, 0, stream>>>(
                    feat_ptr(s), KWB + (size_t)(l * 4 + s) * 16384,
                    kqvb_l + ((size_t)s * 3 + 0) * 128,
                    nullptr, nullptr, nullptr, nullptr, KV, NT[s], 128);
                if (gi == 0)
                    agg_pass1<1><<<ab, 256, 0, stream>>>(QA, KV, RP + RPOFF[r],
                        SIDX + (size_t)r * E_CNT, p_rel + (size_t)(l * 8 + r) * 4,
                        LG + (size_t)gi * E_CNT * 4, MD, Ndt);
                else
                    agg_pass1<0><<<ab, 256, 0, stream>>>(QA, KV, RP + RPOFF[r],
                        SIDX + (size_t)r * E_CNT, p_rel + (size_t)(l * 8 + r) * 4,
                        LG + (size_t)gi * E_CNT * 4, MD, Ndt);
            }
            // pass 2: Vm gemm + weighted gather
            for (int gi = 0; gi < 2; ++gi) {
                int r = DG[dt][gi][0], s = DG[dt][gi][1];
                int mgs = (NT[s] + 63) / 64;
                mgemm<0><<<mgs, 256, 0, stream>>>(
                    feat_ptr(s), WVMB + (size_t)r * 16384, BVM + (size_t)r * 128,
                    nullptr, nullptr, nullptr, nullptr, KV, NT[s], 128);
                if (gi == 0)
                    agg_pass2<1><<<ab, 256, 0, stream>>>(KV, RP + RPOFF[r],
                        SIDX + (size_t)r * E_CNT, LG + (size_t)gi * E_CNT * 4, MD, ACC, Ndt);
                else
                    agg_pass2<0><<<ab, 256, 0, stream>>>(KV, RP + RPOFF[r],
                        SIDX + (size_t)r * E_CNT, LG + (size_t)gi * E_CNT * 4, MD, ACC, Ndt);
            }
            // gelu + bf16 (into AGB = KV region; VM dead now)
            gelu_cvt<<<(Ndt * 32 + 255) / 256, 256, 0, stream>>>(ACC, AGB, Ndt * 32);
            // epilogue: out-proj + skip + LN + relu (fused, MFMA)
            size_t wi = (size_t)l * 4 + dt;
            const bfu* xr = (dt == 3) ? EVB :
                            (l == 0 ? XB : (l == 1 ? LK0 : LK1)) + (size_t)OFF[dt] * 128;
            bfu* ydst = (dt == 3) ? EVB :
                        (l == 0 ? LK0 : (l == 1 ? LK1 : L2F)) + (size_t)OFF[dt] * 128;
            mgemm<1><<<mg, 256, 0, stream>>>(
                AGB, OWB + wi * 16384, out_b + wi * 128, xr, skip + wi,
                blk_ln_g + (size_t)l * 128, blk_ln_b + (size_t)l * 128, ydst, Ndt, 128);
        }
    }

    // ---- fusion heads ----
    const int CH = 15000;
    for (int j = 0; j < 3; ++j) {
        int Nj = NT[j];
        for (int b0 = 0; b0 < Nj; b0 += CH) {
            int M = min(CH, Nj - b0);
            int mg = (M + 63) / 64;
            for (int kk = 0; kk < 3; ++kk) {
                const bfu* Wk = FINWB + (size_t)j * 49152 + (size_t)kk * 16384;
                const float* bk = fin_b + (size_t)j * 384 + kk * 128;
                const bfu* srcs[3] = {
                    LK0 + (size_t)(OFF[j] + b0) * 128,
                    LK1 + (size_t)(OFF[j] + b0) * 128,
                    L2F + (size_t)(OFF[j] + b0) * 128 };
                for (int p = 0; p < 3; ++p) {
                    mgemm<0><<<mg, 256, 0, stream>>>(
                        srcs[p], Wk, bk, nullptr, nullptr, nullptr, nullptr,
                        QKVf + (size_t)(kk * 3 + p) * 128, M, 1152);
                }
            }
            attn_fuse<<<(M + 3) / 4, 256, 0, stream>>>(QKVf, OMB, M);
            mgemm<2><<<mg, 256, 0, stream>>>(
                OMB, FOUTWB + (size_t)j * 16384, fout_b + (size_t)j * 128,
                nullptr, nullptr, f_ln_g + (size_t)j * 128, f_ln_b + (size_t)j * 128,
                out + (size_t)(OFF[j] + b0) * 128, M, 128);
        }
    }
}

// Round 6
// 2492.428 us; speedup vs baseline: 4.9733x; 1.4821x over previous
//
#include <hip/hip_runtime.h>
#include <math.h>

#define E_CNT 200000
typedef unsigned short bfu;
typedef __attribute__((ext_vector_type(8))) short bh8;
typedef __attribute__((ext_vector_type(4))) float f4;

__device__ __forceinline__ float gelu_f(float x) {
    return 0.5f * x * (1.0f + erff(x * 0.70710678118654752f));
}
__device__ __forceinline__ float bf2f(bfu u) { return __uint_as_float(((unsigned)u) << 16); }
__device__ __forceinline__ bfu f2bf(float f) {
    unsigned u = __float_as_uint(f);
    unsigned r = u + 0x7FFFu + ((u >> 16) & 1u);
    return (bfu)(r >> 16);
}
__device__ __forceinline__ int rsrc_of(int r) {
    const int a[8] = {0, 1, 2, 1, 3, 0, 3, 2}; return a[r];
}
__device__ __forceinline__ int rdst_of(int r) {
    const int a[8] = {1, 0, 1, 2, 0, 3, 2, 3}; return a[r];
}
__device__ __forceinline__ int rpoff_of(int r) {
    const int a[9] = {0, 20001, 50002, 70003, 95004, 125005, 175006, 200007, 250008};
    return a[r];
}

__global__ __launch_bounds__(256) void fill_val(float* p, int n, float v) {
    int i = blockIdx.x * 256 + threadIdx.x;
    if (i < n) p[i] = v;
}

// ---- one-shot f32->bf16 weight/emb converts (5 segments, float4-granular) ----
__global__ __launch_bounds__(256) void cvt_pack(
    const float* __restrict__ out_W, const float* __restrict__ kqv_W,
    const float* __restrict__ fin_W, const float* __restrict__ fout_W,
    const float* __restrict__ event_emb,
    bfu* __restrict__ OWB, bfu* __restrict__ KWB, bfu* __restrict__ FINWB,
    bfu* __restrict__ FOUTWB, bfu* __restrict__ EVB)
{
    int i = blockIdx.x * 256 + threadIdx.x;   // float4 index
    const float* src; bfu* dst; size_t so, dox;
    if (i < 49152) { src = out_W; dst = OWB; so = (size_t)i * 4; dox = so; }
    else if (i < 98304) {
        int j = i - 49152; int m = j >> 12; int o = (j & 4095) * 4;
        src = kqv_W; dst = KWB;
        so = (size_t)m * 3 * 16384 + o; dox = (size_t)m * 16384 + o;
    }
    else if (i < 135168) { int j = i - 98304; src = fin_W; dst = FINWB; so = (size_t)j * 4; dox = so; }
    else if (i < 147456) { int j = i - 135168; src = fout_W; dst = FOUTWB; so = (size_t)j * 4; dox = so; }
    else if (i < 1747456) { int j = i - 147456; src = event_emb; dst = EVB; so = (size_t)j * 4; dox = so; }
    else return;
    float4 v = *(const float4*)(src + so);
    uint2 u;
    u.x = ((unsigned)f2bf(v.x)) | (((unsigned)f2bf(v.y)) << 16);
    u.y = ((unsigned)f2bf(v.z)) | (((unsigned)f2bf(v.w)) << 16);
    *(uint2*)(dst + dox) = u;
}

// ---- CSR build (global concatenated rowptr; carry-in = r*E_CNT absorbed by abs SIDX idx) ----
__global__ __launch_bounds__(256) void hist_all(const int* __restrict__ edges, int* __restrict__ rp) {
    int i = blockIdx.x * 256 + threadIdx.x;
    if (i >= 8 * E_CNT) return;
    int r = i / E_CNT, e = i - r * E_CNT;
    int d = edges[(size_t)(2 * r + 1) * E_CNT + e];
    atomicAdd(&rp[rpoff_of(r) + d + 1], 1);
}
__global__ __launch_bounds__(1024) void scan_part(int* __restrict__ a, int* __restrict__ part, int n) {
    __shared__ int lds[1024];
    int t = threadIdx.x, i = blockIdx.x * 1024 + t;
    int v = (i < n) ? a[i] : 0;
    lds[t] = v;
    __syncthreads();
    for (int off = 1; off < 1024; off <<= 1) {
        int u = (t >= off) ? lds[t - off] : 0;
        __syncthreads();
        lds[t] += u;
        __syncthreads();
    }
    if (i < n) a[i] = lds[t];
    if (t == 1023) part[blockIdx.x] = lds[1023];
}
__global__ __launch_bounds__(256) void scan_tot(int* __restrict__ part, int nb) {
    __shared__ int lds[256];
    int t = threadIdx.x;
    int v = (t < nb) ? part[t] : 0;
    lds[t] = v;
    __syncthreads();
    for (int off = 1; off < 256; off <<= 1) {
        int u = (t >= off) ? lds[t - off] : 0;
        __syncthreads();
        lds[t] += u;
        __syncthreads();
    }
    if (t < nb) part[t] = lds[t];
}
__global__ __launch_bounds__(1024) void scan_add(int* __restrict__ a, const int* __restrict__ part, int n) {
    int b = blockIdx.x + 1;
    int i = b * 1024 + threadIdx.x;
    if (i < n) a[i] += part[b - 1];
}
__global__ __launch_bounds__(256) void scatter_all(
    const int* __restrict__ edges, const int* __restrict__ RP,
    int* __restrict__ cur, int* __restrict__ SIDX) {
    int i = blockIdx.x * 256 + threadIdx.x;
    if (i >= 8 * E_CNT) return;
    int r = i / E_CNT, e = i - r * E_CNT;
    int d = edges[(size_t)(2 * r + 1) * E_CNT + e];
    int pos = RP[rpoff_of(r) + d] + atomicAdd(&cur[r * 50000 + d], 1);
    SIDX[pos] = edges[(size_t)(2 * r) * E_CNT + e];
}

// ---- input projection (f32[N,64] -> relu -> bf16[N,128]) ----
__global__ __launch_bounds__(256) void proj_gemm(
    const float* __restrict__ X, const float* __restrict__ W,
    const float* __restrict__ bias, bfu* __restrict__ Y, int N)
{
    __shared__ __align__(16) float Wt[32][132];
    __shared__ __align__(16) float Xt[32][36];
    const int tid = threadIdx.x;
    const int r0 = blockIdx.x * 32;
    const int rg = tid >> 5, cg = tid & 31;
    float acc[4][4];
    #pragma unroll
    for (int i = 0; i < 4; ++i)
        #pragma unroll
        for (int j = 0; j < 4; ++j) acc[i][j] = 0.f;
    for (int c0 = 0; c0 < 64; c0 += 32) {
        __syncthreads();
        #pragma unroll
        for (int k = 0; k < 4; ++k) {
            int v = tid + k * 256;
            int j = v >> 3, c4 = (v & 7) * 4;
            float4 w = *(const float4*)(W + (size_t)j * 64 + c0 + c4);
            Wt[c4 + 0][j] = w.x; Wt[c4 + 1][j] = w.y;
            Wt[c4 + 2][j] = w.z; Wt[c4 + 3][j] = w.w;
        }
        {
            int rr = tid >> 3, c4 = (tid & 7) * 4;
            int row = r0 + rr;
            float4 x = make_float4(0.f, 0.f, 0.f, 0.f);
            if (row < N) x = *(const float4*)(X + (size_t)row * 64 + c0 + c4);
            Xt[c4 + 0][rr] = x.x; Xt[c4 + 1][rr] = x.y;
            Xt[c4 + 2][rr] = x.z; Xt[c4 + 3][rr] = x.w;
        }
        __syncthreads();
        #pragma unroll
        for (int cc = 0; cc < 32; ++cc) {
            float4 xv = *(const float4*)(&Xt[cc][rg * 4]);
            float4 wv = *(const float4*)(&Wt[cc][cg * 4]);
            #pragma unroll
            for (int i = 0; i < 4; ++i) {
                float xs = (i == 0) ? xv.x : (i == 1) ? xv.y : (i == 2) ? xv.z : xv.w;
                acc[i][0] = fmaf(xs, wv.x, acc[i][0]);
                acc[i][1] = fmaf(xs, wv.y, acc[i][1]);
                acc[i][2] = fmaf(xs, wv.z, acc[i][2]);
                acc[i][3] = fmaf(xs, wv.w, acc[i][3]);
            }
        }
    }
    float4 bv = *(const float4*)(bias + cg * 4);
    #pragma unroll
    for (int ri = 0; ri < 4; ++ri) {
        int row = r0 + rg * 4 + ri;
        if (row >= N) continue;
        float y0 = fmaxf(acc[ri][0] + bv.x, 0.f);
        float y1 = fmaxf(acc[ri][1] + bv.y, 0.f);
        float y2 = fmaxf(acc[ri][2] + bv.z, 0.f);
        float y3 = fmaxf(acc[ri][3] + bv.w, 0.f);
        uint2 u;
        u.x = ((unsigned)f2bf(y0)) | (((unsigned)f2bf(y1)) << 16);
        u.y = ((unsigned)f2bf(y2)) | (((unsigned)f2bf(y3)) << 16);
        *(uint2*)(Y + (size_t)row * 128 + cg * 4) = u;
    }
}

// ---- merged relation-folded weight builder: blocks 0..31 WQA, 32..63 WVM ----
__global__ __launch_bounds__(256) void build_rel(
    const float* __restrict__ kqvW_l, const float* __restrict__ kqvb_l,
    const float* __restrict__ a_l, const float* __restrict__ m_l,
    bfu* __restrict__ WQAB, float* __restrict__ BQA,
    bfu* __restrict__ WVMB, float* __restrict__ BVM)
{
    __shared__ float As[32][33];
    __shared__ float Ws[32][129];
    int tid = threadIdx.x;
    int b = blockIdx.x;
    if (b < 32) {
        int r = b >> 2, h = b & 3;
        int dt = rdst_of(r);
        const float* Wq = kqvW_l + ((size_t)dt * 3 + 1) * 16384;
        const float* bq = kqvb_l + ((size_t)dt * 3 + 1) * 128;
        const float* A = a_l + (size_t)r * 4096 + h * 1024;
        for (int v = tid; v < 1024; v += 256) As[v >> 5][v & 31] = A[v];
        for (int v = tid; v < 4096; v += 256)
            Ws[v >> 7][v & 127] = Wq[(size_t)(h * 32 + (v >> 7)) * 128 + (v & 127)];
        __syncthreads();
        int c = tid & 127, half = tid >> 7;
        for (int d = half; d < 32; d += 2) {
            float acc = 0.f;
            #pragma unroll
            for (int f = 0; f < 32; ++f) acc = fmaf(As[d][f], Ws[f][c], acc);
            WQAB[((size_t)r * 128 + h * 32 + d) * 128 + c] = f2bf(acc);
        }
        if (tid < 32) {
            int d = tid;
            float acc = 0.f;
            #pragma unroll
            for (int f = 0; f < 32; ++f) acc = fmaf(As[d][f], bq[h * 32 + f], acc);
            BQA[(size_t)r * 128 + h * 32 + d] = acc;
        }
    } else {
        int bb2 = b - 32;
        int r = bb2 >> 2, h = bb2 & 3;
        int st = rsrc_of(r);
        const float* Wv = kqvW_l + ((size_t)st * 3 + 2) * 16384;
        const float* bv = kqvb_l + ((size_t)st * 3 + 2) * 128;
        const float* M = m_l + (size_t)r * 4096 + h * 1024;
        for (int v = tid; v < 1024; v += 256) As[v >> 5][v & 31] = M[v];
        for (int v = tid; v < 4096; v += 256)
            Ws[v >> 7][v & 127] = Wv[(size_t)(h * 32 + (v >> 7)) * 128 + (v & 127)];
        __syncthreads();
        int c = tid & 127, half = tid >> 7;
        for (int f = half; f < 32; f += 2) {
            float acc = 0.f;
            #pragma unroll
            for (int d = 0; d < 32; ++d) acc = fmaf(As[d][f], Ws[d][c], acc);
            WVMB[((size_t)r * 128 + h * 32 + f) * 128 + c] = f2bf(acc);
        }
        if (tid < 32) {
            int f = tid;
            float acc = 0.f;
            #pragma unroll
            for (int d = 0; d < 32; ++d) acc = fmaf(As[d][f], bv[h * 32 + d], acc);
            BVM[(size_t)r * 128 + h * 32 + f] = acc;
        }
    }
}

// ---- batched MFMA GEMM: up to 9 descriptors, bf16 in/out, bias, ldy ----
struct GDesc { const bfu* X; const bfu* W; const float* bias; bfu* Y; int N; int ldy; int bend; };
struct GBatch { GDesc d[9]; };

__global__ __launch_bounds__(256) void mgemm_batch(GBatch gb) {
    int b = blockIdx.x;
    int gi = 0;
    #pragma unroll
    for (int k = 0; k < 8; ++k) gi += (b >= gb.d[k].bend) ? 1 : 0;
    const bfu* X = gb.d[0].X; const bfu* W = gb.d[0].W;
    const float* bi = gb.d[0].bias; bfu* Y = gb.d[0].Y;
    int N = gb.d[0].N, ldy = gb.d[0].ldy, bstart = 0;
    #pragma unroll
    for (int k = 1; k < 9; ++k) {
        if (gi == k) {
            X = gb.d[k].X; W = gb.d[k].W; bi = gb.d[k].bias; Y = gb.d[k].Y;
            N = gb.d[k].N; ldy = gb.d[k].ldy; bstart = gb.d[k - 1].bend;
        }
    }
    int bloc = b - bstart;
    const int tid = threadIdx.x;
    const int wave = tid >> 6, lane = tid & 63;
    const int row16 = lane & 15, kgrp = lane >> 4;
    const int r_base = bloc * 64 + wave * 16;
    const int arow = r_base + row16;
    f4 acc[8];
    #pragma unroll
    for (int n = 0; n < 8; ++n) acc[n] = (f4){0.f, 0.f, 0.f, 0.f};
    bh8 az = {0, 0, 0, 0, 0, 0, 0, 0};
    #pragma unroll
    for (int kb = 0; kb < 4; ++kb) {
        bh8 a = az;
        if (arow < N) a = *(const bh8*)(X + (size_t)arow * 128 + kb * 32 + kgrp * 8);
        #pragma unroll
        for (int n = 0; n < 8; ++n) {
            bh8 bv = *(const bh8*)(W + (size_t)(n * 16 + row16) * 128 + kb * 32 + kgrp * 8);
            acc[n] = __builtin_amdgcn_mfma_f32_16x16x32_bf16(a, bv, acc[n], 0, 0, 0);
        }
    }
    const int crow0 = r_base + kgrp * 4;
    #pragma unroll
    for (int n = 0; n < 8; ++n) {
        int col = n * 16 + row16;
        float bn = bi[col];
        #pragma unroll
        for (int j = 0; j < 4; ++j) {
            int row = crow0 + j;
            if (row < N) Y[(size_t)row * ldy + col] = f2bf(acc[n][j] + bn);
        }
    }
}

// ---- flash-style fused aggregation: online softmax + weighted V, per dst node wave ----
template<int FIRST>
__global__ __launch_bounds__(256) void agg_fused(
    const bfu* __restrict__ QA, const bfu* __restrict__ K, const bfu* __restrict__ VM,
    const int* __restrict__ rp, const int* __restrict__ sidx,
    const float* __restrict__ prl, float* __restrict__ Mb, float* __restrict__ Db,
    bfu* __restrict__ ACCB, int Nn)
{
    int n = blockIdx.x * 4 + (threadIdx.x >> 6);
    int l = threadIdx.x & 63;
    if (n >= Nn) return;
    int hA = l >> 5;
    float pA = prl[hA] * 0.17677669529663687f;
    float pB = prl[2 + hA] * 0.17677669529663687f;
    float q0 = bf2f(QA[(size_t)n * 128 + l]);
    float q1 = bf2f(QA[(size_t)n * 128 + l + 64]);
    float m0, d0, a0, m1, d1, a1;
    if (FIRST) { m0 = m1 = -3.0e38f; d0 = d1 = 0.f; a0 = a1 = 0.f; }
    else {
        m0 = Mb[n * 4 + hA]; m1 = Mb[n * 4 + 2 + hA];
        d0 = Db[n * 4 + hA]; d1 = Db[n * 4 + 2 + hA];
        a0 = bf2f(ACCB[(size_t)n * 128 + l]);
        a1 = bf2f(ACCB[(size_t)n * 128 + l + 64]);
    }
    int e1 = rp[n + 1];
    for (int i = rp[n]; i < e1; ++i) {
        int sn = sidx[i];
        float s0 = bf2f(K[(size_t)sn * 128 + l]) * q0;
        float s1 = bf2f(K[(size_t)sn * 128 + l + 64]) * q1;
        #pragma unroll
        for (int off = 1; off <= 16; off <<= 1) {
            s0 += __shfl_xor(s0, off);
            s1 += __shfl_xor(s1, off);
        }
        s0 *= pA; s1 *= pB;
        float v0 = bf2f(VM[(size_t)sn * 128 + l]);
        float v1 = bf2f(VM[(size_t)sn * 128 + l + 64]);
        float nm0 = fmaxf(m0, s0);
        float sc0 = __expf(m0 - nm0), w0 = __expf(s0 - nm0);
        d0 = d0 * sc0 + w0; a0 = fmaf(w0, v0, a0 * sc0); m0 = nm0;
        float nm1 = fmaxf(m1, s1);
        float sc1 = __expf(m1 - nm1), w1 = __expf(s1 - nm1);
        d1 = d1 * sc1 + w1; a1 = fmaf(w1, v1, a1 * sc1); m1 = nm1;
    }
    if (l == 0 || l == 32) {
        Mb[n * 4 + hA] = m0; Mb[n * 4 + 2 + hA] = m1;
        Db[n * 4 + hA] = d0; Db[n * 4 + 2 + hA] = d1;
    }
    ACCB[(size_t)n * 128 + l] = f2bf(a0);
    ACCB[(size_t)n * 128 + l + 64] = f2bf(a1);
}

// ---- layer epilogue: A = gelu(acc/den) (fused in A-load); out-proj; skip+LN+relu; bf16 out ----
__global__ __launch_bounds__(256) void mgemm_epi_layer(
    const bfu* __restrict__ ACCB, const float* __restrict__ Db,
    const bfu* __restrict__ W, const float* __restrict__ bias,
    const bfu* __restrict__ Xr, const float* __restrict__ skp,
    const float* __restrict__ g, const float* __restrict__ bb,
    bfu* __restrict__ Y, int N)
{
    const int tid = threadIdx.x;
    const int wave = tid >> 6, lane = tid & 63;
    const int row16 = lane & 15, kgrp = lane >> 4;
    const int r_base = blockIdx.x * 64 + wave * 16;
    const int arow = r_base + row16;
    f4 acc[8];
    #pragma unroll
    for (int n = 0; n < 8; ++n) acc[n] = (f4){0.f, 0.f, 0.f, 0.f};
    bh8 az = {0, 0, 0, 0, 0, 0, 0, 0};
    #pragma unroll
    for (int kb = 0; kb < 4; ++kb) {
        bh8 a = az;
        if (arow < N) {
            float rd = 1.f / fmaxf(Db[arow * 4 + kb], 1e-16f);
            bh8 raw = *(const bh8*)(ACCB + (size_t)arow * 128 + kb * 32 + kgrp * 8);
            #pragma unroll
            for (int e = 0; e < 8; ++e) {
                float x = bf2f((bfu)(unsigned short)raw[e]);
                a[e] = (short)f2bf(gelu_f(x * rd));
            }
        }
        #pragma unroll
        for (int n = 0; n < 8; ++n) {
            bh8 bv = *(const bh8*)(W + (size_t)(n * 16 + row16) * 128 + kb * 32 + kgrp * 8);
            acc[n] = __builtin_amdgcn_mfma_f32_16x16x32_bf16(a, bv, acc[n], 0, 0, 0);
        }
    }
    const int crow0 = r_base + kgrp * 4;
    float sg = 1.f / (1.f + expf(-skp[0]));
    float z[8][4];
    #pragma unroll
    for (int n = 0; n < 8; ++n) {
        float bn = bias[n * 16 + row16];
        #pragma unroll
        for (int j = 0; j < 4; ++j) z[n][j] = acc[n][j] + bn;
    }
    #pragma unroll
    for (int j = 0; j < 4; ++j) {
        int row = crow0 + j;
        if (row >= N) continue;
        #pragma unroll
        for (int n = 0; n < 8; ++n) {
            float xr = bf2f(Xr[(size_t)row * 128 + n * 16 + row16]);
            z[n][j] = sg * z[n][j] + (1.f - sg) * xr + xr;
        }
    }
    float s[4], q[4];
    #pragma unroll
    for (int j = 0; j < 4; ++j) {
        s[j] = 0.f; q[j] = 0.f;
        #pragma unroll
        for (int n = 0; n < 8; ++n) { s[j] += z[n][j]; q[j] += z[n][j] * z[n][j]; }
    }
    #pragma unroll
    for (int off = 1; off <= 8; off <<= 1) {
        #pragma unroll
        for (int j = 0; j < 4; ++j) {
            s[j] += __shfl_xor(s[j], off);
            q[j] += __shfl_xor(q[j], off);
        }
    }
    #pragma unroll
    for (int j = 0; j < 4; ++j) {
        int row = crow0 + j;
        if (row >= N) continue;
        float mean = s[j] * (1.f / 128.f);
        float var = q[j] * (1.f / 128.f) - mean * mean;
        float inv = rsqrtf(var + 1e-5f);
        #pragma unroll
        for (int n = 0; n < 8; ++n) {
            int col = n * 16 + row16;
            float y = (z[n][j] - mean) * inv * g[col] + bb[col];
            Y[(size_t)row * 128 + col] = f2bf(fmaxf(y, 0.f));
        }
    }
}

// ---- fusion final: A bf16 plain; out-proj; LN; f32 out ----
__global__ __launch_bounds__(256) void mgemm_epi_ln(
    const bfu* __restrict__ X, const bfu* __restrict__ W, const float* __restrict__ bias,
    const float* __restrict__ g, const float* __restrict__ bb,
    float* __restrict__ Y, int N)
{
    const int tid = threadIdx.x;
    const int wave = tid >> 6, lane = tid & 63;
    const int row16 = lane & 15, kgrp = lane >> 4;
    const int r_base = blockIdx.x * 64 + wave * 16;
    const int arow = r_base + row16;
    f4 acc[8];
    #pragma unroll
    for (int n = 0; n < 8; ++n) acc[n] = (f4){0.f, 0.f, 0.f, 0.f};
    bh8 az = {0, 0, 0, 0, 0, 0, 0, 0};
    #pragma unroll
    for (int kb = 0; kb < 4; ++kb) {
        bh8 a = az;
        if (arow < N) a = *(const bh8*)(X + (size_t)arow * 128 + kb * 32 + kgrp * 8);
        #pragma unroll
        for (int n = 0; n < 8; ++n) {
            bh8 bv = *(const bh8*)(W + (size_t)(n * 16 + row16) * 128 + kb * 32 + kgrp * 8);
            acc[n] = __builtin_amdgcn_mfma_f32_16x16x32_bf16(a, bv, acc[n], 0, 0, 0);
        }
    }
    const int crow0 = r_base + kgrp * 4;
    float z[8][4];
    #pragma unroll
    for (int n = 0; n < 8; ++n) {
        float bn = bias[n * 16 + row16];
        #pragma unroll
        for (int j = 0; j < 4; ++j) z[n][j] = acc[n][j] + bn;
    }
    float s[4], q[4];
    #pragma unroll
    for (int j = 0; j < 4; ++j) {
        s[j] = 0.f; q[j] = 0.f;
        #pragma unroll
        for (int n = 0; n < 8; ++n) { s[j] += z[n][j]; q[j] += z[n][j] * z[n][j]; }
    }
    #pragma unroll
    for (int off = 1; off <= 8; off <<= 1) {
        #pragma unroll
        for (int j = 0; j < 4; ++j) {
            s[j] += __shfl_xor(s[j], off);
            q[j] += __shfl_xor(q[j], off);
        }
    }
    #pragma unroll
    for (int j = 0; j < 4; ++j) {
        int row = crow0 + j;
        if (row >= N) continue;
        float mean = s[j] * (1.f / 128.f);
        float var = q[j] * (1.f / 128.f) - mean * mean;
        float inv = rsqrtf(var + 1e-5f);
        #pragma unroll
        for (int n = 0; n < 8; ++n) {
            int col = n * 16 + row16;
            Y[(size_t)row * 128 + col] = (z[n][j] - mean) * inv * g[col] + bb[col];
        }
    }
}

// ---- fusion attention (3 tokens, 4 heads), wave per node, bf16 out ----
__global__ __launch_bounds__(256) void attn_fuse(
    const bfu* __restrict__ QKV, bfu* __restrict__ OM, int M)
{
    int n = blockIdx.x * 4 + (threadIdx.x >> 6);
    int l = threadIdx.x & 63;
    if (n >= M) return;
    const bfu* base = QKV + (size_t)n * 1152;
    float q[3][2], k[3][2], v[3][2];
    #pragma unroll
    for (int p = 0; p < 3; ++p) {
        q[p][0] = bf2f(base[(0 * 3 + p) * 128 + l]);
        q[p][1] = bf2f(base[(0 * 3 + p) * 128 + l + 64]);
        k[p][0] = bf2f(base[(1 * 3 + p) * 128 + l]);
        k[p][1] = bf2f(base[(1 * 3 + p) * 128 + l + 64]);
        v[p][0] = bf2f(base[(2 * 3 + p) * 128 + l]);
        v[p][1] = bf2f(base[(2 * 3 + p) * 128 + l + 64]);
    }
    float lgA[3][3], lgB[3][3];
    #pragma unroll
    for (int qi = 0; qi < 3; ++qi)
        #pragma unroll
        for (int ki = 0; ki < 3; ++ki) {
            float s0 = q[qi][0] * k[ki][0];
            float s1 = q[qi][1] * k[ki][1];
            #pragma unroll
            for (int off = 1; off <= 16; off <<= 1) {
                s0 += __shfl_xor(s0, off);
                s1 += __shfl_xor(s1, off);
            }
            lgA[qi][ki] = s0 * 0.17677669529663687f;
            lgB[qi][ki] = s1 * 0.17677669529663687f;
        }
    float oA = 0.f, oB = 0.f;
    #pragma unroll
    for (int qi = 0; qi < 3; ++qi) {
        float mA = fmaxf(lgA[qi][0], fmaxf(lgA[qi][1], lgA[qi][2]));
        float e0 = __expf(lgA[qi][0] - mA), e1 = __expf(lgA[qi][1] - mA), e2 = __expf(lgA[qi][2] - mA);
        float rd = 1.f / (e0 + e1 + e2);
        oA += (e0 * v[0][0] + e1 * v[1][0] + e2 * v[2][0]) * rd;
        float mB = fmaxf(lgB[qi][0], fmaxf(lgB[qi][1], lgB[qi][2]));
        float f0 = __expf(lgB[qi][0] - mB), f1 = __expf(lgB[qi][1] - mB), f2 = __expf(lgB[qi][2] - mB);
        float rdB = 1.f / (f0 + f1 + f2);
        oB += (f0 * v[0][1] + f1 * v[1][1] + f2 * v[2][1]) * rdB;
    }
    OM[(size_t)n * 128 + l] = f2bf(oA * (1.f / 3.f));
    OM[(size_t)n * 128 + l + 64] = f2bf(oB * (1.f / 3.f));
}

extern "C" void kernel_launch(void* const* d_in, const int* in_sizes, int n_in,
                              void* d_out, int out_size, void* d_ws, size_t ws_size,
                              hipStream_t stream)
{
    const float* x_pest   = (const float*)d_in[0];
    const float* x_dis    = (const float*)d_in[1];
    const float* x_plant  = (const float*)d_in[2];
    const int*   edges    = (const int*)d_in[3];
    const float* proj_W   = (const float*)d_in[4];
    const float* proj_b   = (const float*)d_in[5];
    const float* event_emb= (const float*)d_in[6];
    const float* kqv_W    = (const float*)d_in[7];
    const float* kqv_b    = (const float*)d_in[8];
    const float* out_W    = (const float*)d_in[9];
    const float* out_b    = (const float*)d_in[10];
    const float* skip     = (const float*)d_in[11];
    const float* a_rel    = (const float*)d_in[12];
    const float* m_rel    = (const float*)d_in[13];
    const float* p_rel    = (const float*)d_in[14];
    const float* blk_ln_g = (const float*)d_in[15];
    const float* blk_ln_b = (const float*)d_in[16];
    const float* fin_W    = (const float*)d_in[17];
    const float* fin_b    = (const float*)d_in[18];
    const float* fout_W   = (const float*)d_in[19];
    const float* fout_b   = (const float*)d_in[20];
    const float* f_ln_g   = (const float*)d_in[21];
    const float* f_ln_b   = (const float*)d_in[22];
    float* out = (float*)d_out;

    static const int NT[4]  = {30000, 20000, 25000, 50000};
    static const int OFF[4] = {0, 30000, 50000, 75000};
    static const int RPOFF[9] = {0, 20001, 50002, 70003, 95004, 125005, 175006, 200007, 250008};
    static const int DG[4][2][2] = { {{1,1},{4,3}}, {{0,0},{2,2}}, {{3,1},{6,3}}, {{5,0},{7,2}} };

    char* wsb = (char*)d_ws;
    size_t ob = 0;
    auto alc = [&](size_t bytes) -> void* {
        void* p = wsb + ob; ob += (bytes + 255) & ~(size_t)255; return p;
    };
    bfu* LK0  = (bfu*)alc((size_t)75000 * 128 * 2);
    bfu* LK1  = (bfu*)alc((size_t)75000 * 128 * 2);
    bfu* QAb  = (bfu*)alc((size_t)50000 * 128 * 2);   // POOL: QA | K | VM (fusion QKV spans)
    bfu* Kb   = (bfu*)alc((size_t)50000 * 128 * 2);
    bfu* VMb  = (bfu*)alc((size_t)50000 * 128 * 2);
    bfu* ACCB = (bfu*)alc((size_t)50000 * 128 * 2);   // bf16 running agg; fusion OMB
    float* Mb = (float*)alc((size_t)50000 * 4 * 4);   // running max; CUR aliases Mb+Db
    float* Db = (float*)alc((size_t)50000 * 4 * 4);   // running den
    bfu* WQAB = (bfu*)alc((size_t)8 * 16384 * 2);
    float* BQA = (float*)alc((size_t)8 * 128 * 4);
    bfu* WVMB = (bfu*)alc((size_t)8 * 16384 * 2);
    float* BVM = (float*)alc((size_t)8 * 128 * 4);
    bfu* KWB  = (bfu*)alc((size_t)12 * 16384 * 2);
    bfu* OWB  = (bfu*)alc((size_t)12 * 16384 * 2);
    bfu* FINWB = (bfu*)alc((size_t)3 * 49152 * 2);
    bfu* FOUTWB = (bfu*)alc((size_t)3 * 16384 * 2);
    int* RP   = (int*)alc((size_t)250008 * 4);
    int* PART = (int*)alc(1024);
    int* SIDX = (int*)alc((size_t)8 * E_CNT * 4);
    if (ws_size < ob) {
        fill_val<<<(out_size + 255) / 256, 256, 0, stream>>>(out, out_size, 1e30f);
        return;
    }
    int* CUR = (int*)Mb;        // CSR counters (1.6MB = Mb+Db), used before Mb/Db
    bfu* QKVf = QAb;            // fusion QKV spans QAb..VMb (34.56MB <= 38.4MB)
    bfu* OMB  = ACCB;           // fusion attn output (3.84MB <= 12.8MB)

    // d_out overlay (time-disjoint): EVB [0,12.8M); XB [12.8,32.0M); L2F [19.2,38.4M)
    bfu* EVB = (bfu*)out;
    bfu* XB  = (bfu*)((char*)out + 12800000);
    bfu* L2F = (bfu*)((char*)out + 19200000);

    // ---- converts (one launch) ----
    cvt_pack<<<(1747456 + 255) / 256, 256, 0, stream>>>(
        out_W, kqv_W, fin_W, fout_W, event_emb, OWB, KWB, FINWB, FOUTWB, EVB);

    // ---- CSR build ----
    hipMemsetAsync(RP, 0, (size_t)250008 * 4, stream);
    const int eg8 = (8 * E_CNT + 255) / 256;
    hist_all<<<eg8, 256, 0, stream>>>(edges, RP);
    scan_part<<<245, 1024, 0, stream>>>(RP, PART, 250008);
    scan_tot<<<1, 256, 0, stream>>>(PART, 245);
    scan_add<<<244, 1024, 0, stream>>>(RP, PART, 250008);
    hipMemsetAsync(CUR, 0, (size_t)8 * 50000 * 4, stream);
    scatter_all<<<eg8, 256, 0, stream>>>(edges, RP, CUR, SIDX);

    // ---- input projections ----
    const float* xin0[3] = {x_pest, x_dis, x_plant};
    for (int t = 0; t < 3; ++t) {
        proj_gemm<<<(NT[t] + 31) / 32, 256, 0, stream>>>(
            xin0[t], proj_W + (size_t)t * 8192, proj_b + (size_t)t * 128,
            XB + (size_t)OFF[t] * 128, NT[t]);
    }

    auto launch_batch = [&](GDesc* ds, int cnt) {
        GBatch gb;
        int acc = 0;
        for (int i = 0; i < cnt; ++i) {
            gb.d[i] = ds[i];
            acc += (ds[i].N + 63) / 64;
            gb.d[i].bend = acc;
        }
        for (int i = cnt; i < 9; ++i) { gb.d[i] = gb.d[cnt - 1]; gb.d[i].bend = acc; }
        mgemm_batch<<<acc, 256, 0, stream>>>(gb);
    };

    for (int l = 0; l < 3; ++l) {
        const float* kqvW_l = kqv_W + (size_t)l * 12 * 16384;
        const float* kqvb_l = kqv_b + (size_t)l * 12 * 128;
        build_rel<<<64, 256, 0, stream>>>(kqvW_l, kqvb_l,
            a_rel + (size_t)l * 8 * 4096, m_rel + (size_t)l * 8 * 4096,
            WQAB, BQA, WVMB, BVM);

        auto feat_ptr = [&](int tt) -> const bfu* {
            if (tt == 3) return EVB;
            if (l == 0) return XB + (size_t)OFF[tt] * 128;
            return (l == 1 ? LK0 : LK1) + (size_t)OFF[tt] * 128;
        };

        int nord = (l == 2) ? 3 : 4;
        for (int dt = 0; dt < nord; ++dt) {
            int Ndt = NT[dt];
            for (int gi = 0; gi < 2; ++gi) {
                int r = DG[dt][gi][0], s = DG[dt][gi][1];
                GDesc ds[3];
                ds[0] = { feat_ptr(dt), WQAB + (size_t)r * 16384, BQA + (size_t)r * 128,
                          QAb, Ndt, 128, 0 };
                ds[1] = { feat_ptr(s), KWB + (size_t)(l * 4 + s) * 16384,
                          kqvb_l + ((size_t)s * 3 + 0) * 128, Kb, NT[s], 128, 0 };
                ds[2] = { feat_ptr(s), WVMB + (size_t)r * 16384, BVM + (size_t)r * 128,
                          VMb, NT[s], 128, 0 };
                launch_batch(ds, 3);
                if (gi == 0)
                    agg_fused<1><<<(Ndt + 3) / 4, 256, 0, stream>>>(
                        QAb, Kb, VMb, RP + RPOFF[r], SIDX,
                        p_rel + (size_t)(l * 8 + r) * 4, Mb, Db, ACCB, Ndt);
                else
                    agg_fused<0><<<(Ndt + 3) / 4, 256, 0, stream>>>(
                        QAb, Kb, VMb, RP + RPOFF[r], SIDX,
                        p_rel + (size_t)(l * 8 + r) * 4, Mb, Db, ACCB, Ndt);
            }
            size_t wi = (size_t)l * 4 + dt;
            const bfu* xr = feat_ptr(dt);
            bfu* ydst = (dt == 3) ? EVB :
                        (l == 0 ? LK0 : (l == 1 ? LK1 : L2F)) + (size_t)OFF[dt] * 128;
            mgemm_epi_layer<<<(Ndt + 63) / 64, 256, 0, stream>>>(
                ACCB, Db, OWB + wi * 16384, out_b + wi * 128, xr, skip + wi,
                blk_ln_g + (size_t)l * 128, blk_ln_b + (size_t)l * 128, ydst, Ndt);
        }
    }

    // ---- fusion heads ----
    const int CH = 15000;
    for (int j = 0; j < 3; ++j) {
        int Nj = NT[j];
        for (int b0 = 0; b0 < Nj; b0 += CH) {
            int M = min(CH, Nj - b0);
            const bfu* srcs[3] = {
                LK0 + (size_t)(OFF[j] + b0) * 128,
                LK1 + (size_t)(OFF[j] + b0) * 128,
                L2F + (size_t)(OFF[j] + b0) * 128 };
            GDesc ds[9];
            int di = 0;
            for (int kk = 0; kk < 3; ++kk)
                for (int p = 0; p < 3; ++p) {
                    ds[di++] = { srcs[p], FINWB + (size_t)j * 49152 + (size_t)kk * 16384,
                                 fin_b + (size_t)j * 384 + kk * 128,
                                 QKVf + (size_t)(kk * 3 + p) * 128, M, 1152, 0 };
                }
            launch_batch(ds, 9);
            attn_fuse<<<(M + 3) / 4, 256, 0, stream>>>(QKVf, OMB, M);
            mgemm_epi_ln<<<(M + 63) / 64, 256, 0, stream>>>(
                OMB, FOUTWB + (size_t)j * 16384, fout_b + (size_t)j * 128,
                f_ln_g + (size_t)j * 128, f_ln_b + (size_t)j * 128,
                out + (size_t)(OFF[j] + b0) * 128, M);
        }
    }
}

// Round 8
// 2119.255 us; speedup vs baseline: 5.8490x; 1.1761x over previous
//
#include <hip/hip_runtime.h>
#include <math.h>

#define E_CNT 200000
typedef unsigned short bfu;
typedef unsigned short u16;
typedef __attribute__((ext_vector_type(8))) short bh8;
typedef __attribute__((ext_vector_type(4))) float f4;

__device__ __forceinline__ float gelu_f(float x) {
    return 0.5f * x * (1.0f + erff(x * 0.70710678118654752f));
}
__device__ __forceinline__ float bf2f(bfu u) { return __uint_as_float(((unsigned)u) << 16); }
__device__ __forceinline__ bfu f2bf(float f) {
    unsigned u = __float_as_uint(f);
    unsigned r = u + 0x7FFFu + ((u >> 16) & 1u);
    return (bfu)(r >> 16);
}
__device__ __forceinline__ int rsrc_of(int r) {
    const int a[8] = {0, 1, 2, 1, 3, 0, 3, 2}; return a[r];
}
__device__ __forceinline__ int rdst_of(int r) {
    const int a[8] = {1, 0, 1, 2, 0, 3, 2, 3}; return a[r];
}
__device__ __forceinline__ int rpoff_of(int r) {
    const int a[9] = {0, 20001, 50002, 70003, 95004, 125005, 175006, 200007, 250008};
    return a[r];
}

__global__ __launch_bounds__(256) void fill_val(float* p, int n, float v) {
    int i = blockIdx.x * 256 + threadIdx.x;
    if (i < n) p[i] = v;
}

// ---- one-shot f32->bf16 weight/emb converts ----
__global__ __launch_bounds__(256) void cvt_pack(
    const float* __restrict__ out_W, const float* __restrict__ kqv_W,
    const float* __restrict__ fin_W, const float* __restrict__ fout_W,
    const float* __restrict__ event_emb,
    bfu* __restrict__ OWB, bfu* __restrict__ KWB, bfu* __restrict__ FINWB,
    bfu* __restrict__ FOUTWB, bfu* __restrict__ EVB)
{
    int i = blockIdx.x * 256 + threadIdx.x;
    const float* src; bfu* dst; size_t so, dox;
    if (i < 49152) { src = out_W; dst = OWB; so = (size_t)i * 4; dox = so; }
    else if (i < 98304) {
        int j = i - 49152; int m = j >> 12; int o = (j & 4095) * 4;
        src = kqv_W; dst = KWB;
        so = (size_t)m * 3 * 16384 + o; dox = (size_t)m * 16384 + o;
    }
    else if (i < 135168) { int j = i - 98304; src = fin_W; dst = FINWB; so = (size_t)j * 4; dox = so; }
    else if (i < 147456) { int j = i - 135168; src = fout_W; dst = FOUTWB; so = (size_t)j * 4; dox = so; }
    else if (i < 1747456) { int j = i - 147456; src = event_emb; dst = EVB; so = (size_t)j * 4; dox = so; }
    else return;
    float4 v = *(const float4*)(src + so);
    uint2 u;
    u.x = ((unsigned)f2bf(v.x)) | (((unsigned)f2bf(v.y)) << 16);
    u.y = ((unsigned)f2bf(v.z)) | (((unsigned)f2bf(v.w)) << 16);
    *(uint2*)(dst + dox) = u;
}

// ---- CSR build ----
__global__ __launch_bounds__(256) void hist_all(const int* __restrict__ edges, int* __restrict__ rp) {
    int i = blockIdx.x * 256 + threadIdx.x;
    if (i >= 8 * E_CNT) return;
    int r = i / E_CNT, e = i - r * E_CNT;
    int d = edges[(size_t)(2 * r + 1) * E_CNT + e];
    atomicAdd(&rp[rpoff_of(r) + d + 1], 1);
}
__global__ __launch_bounds__(1024) void scan_part(int* __restrict__ a, int* __restrict__ part, int n) {
    __shared__ int lds[1024];
    int t = threadIdx.x, i = blockIdx.x * 1024 + t;
    int v = (i < n) ? a[i] : 0;
    lds[t] = v;
    __syncthreads();
    for (int off = 1; off < 1024; off <<= 1) {
        int u = (t >= off) ? lds[t - off] : 0;
        __syncthreads();
        lds[t] += u;
        __syncthreads();
    }
    if (i < n) a[i] = lds[t];
    if (t == 1023) part[blockIdx.x] = lds[1023];
}
__global__ __launch_bounds__(256) void scan_tot(int* __restrict__ part, int nb) {
    __shared__ int lds[256];
    int t = threadIdx.x;
    int v = (t < nb) ? part[t] : 0;
    lds[t] = v;
    __syncthreads();
    for (int off = 1; off < 256; off <<= 1) {
        int u = (t >= off) ? lds[t - off] : 0;
        __syncthreads();
        lds[t] += u;
        __syncthreads();
    }
    if (t < nb) part[t] = lds[t];
}
__global__ __launch_bounds__(1024) void scan_add(int* __restrict__ a, const int* __restrict__ part, int n) {
    int b = blockIdx.x + 1;
    int i = b * 1024 + threadIdx.x;
    if (i < n) a[i] += part[b - 1];
}
__global__ __launch_bounds__(256) void scatter_all(
    const int* __restrict__ edges, const int* __restrict__ RP,
    int* __restrict__ cur, u16* __restrict__ SIDX) {
    int i = blockIdx.x * 256 + threadIdx.x;
    if (i >= 8 * E_CNT) return;
    int r = i / E_CNT, e = i - r * E_CNT;
    int d = edges[(size_t)(2 * r + 1) * E_CNT + e];
    int pos = RP[rpoff_of(r) + d] + atomicAdd(&cur[r * 50000 + d], 1);
    SIDX[pos] = (u16)edges[(size_t)(2 * r) * E_CNT + e];
}

// ---- input projection (f32[N,64] -> relu -> bf16[N,128]) ----
__global__ __launch_bounds__(256) void proj_gemm(
    const float* __restrict__ X, const float* __restrict__ W,
    const float* __restrict__ bias, bfu* __restrict__ Y, int N)
{
    __shared__ __align__(16) float Wt[32][132];
    __shared__ __align__(16) float Xt[32][36];
    const int tid = threadIdx.x;
    const int r0 = blockIdx.x * 32;
    const int rg = tid >> 5, cg = tid & 31;
    float acc[4][4];
    #pragma unroll
    for (int i = 0; i < 4; ++i)
        #pragma unroll
        for (int j = 0; j < 4; ++j) acc[i][j] = 0.f;
    for (int c0 = 0; c0 < 64; c0 += 32) {
        __syncthreads();
        #pragma unroll
        for (int k = 0; k < 4; ++k) {
            int v = tid + k * 256;
            int j = v >> 3, c4 = (v & 7) * 4;
            float4 w = *(const float4*)(W + (size_t)j * 64 + c0 + c4);
            Wt[c4 + 0][j] = w.x; Wt[c4 + 1][j] = w.y;
            Wt[c4 + 2][j] = w.z; Wt[c4 + 3][j] = w.w;
        }
        {
            int rr = tid >> 3, c4 = (tid & 7) * 4;
            int row = r0 + rr;
            float4 x = make_float4(0.f, 0.f, 0.f, 0.f);
            if (row < N) x = *(const float4*)(X + (size_t)row * 64 + c0 + c4);
            Xt[c4 + 0][rr] = x.x; Xt[c4 + 1][rr] = x.y;
            Xt[c4 + 2][rr] = x.z; Xt[c4 + 3][rr] = x.w;
        }
        __syncthreads();
        #pragma unroll
        for (int cc = 0; cc < 32; ++cc) {
            float4 xv = *(const float4*)(&Xt[cc][rg * 4]);
            float4 wv = *(const float4*)(&Wt[cc][cg * 4]);
            #pragma unroll
            for (int i = 0; i < 4; ++i) {
                float xs = (i == 0) ? xv.x : (i == 1) ? xv.y : (i == 2) ? xv.z : xv.w;
                acc[i][0] = fmaf(xs, wv.x, acc[i][0]);
                acc[i][1] = fmaf(xs, wv.y, acc[i][1]);
                acc[i][2] = fmaf(xs, wv.z, acc[i][2]);
                acc[i][3] = fmaf(xs, wv.w, acc[i][3]);
            }
        }
    }
    float4 bv = *(const float4*)(bias + cg * 4);
    #pragma unroll
    for (int ri = 0; ri < 4; ++ri) {
        int row = r0 + rg * 4 + ri;
        if (row >= N) continue;
        float y0 = fmaxf(acc[ri][0] + bv.x, 0.f);
        float y1 = fmaxf(acc[ri][1] + bv.y, 0.f);
        float y2 = fmaxf(acc[ri][2] + bv.z, 0.f);
        float y3 = fmaxf(acc[ri][3] + bv.w, 0.f);
        uint2 u;
        u.x = ((unsigned)f2bf(y0)) | (((unsigned)f2bf(y1)) << 16);
        u.y = ((unsigned)f2bf(y2)) | (((unsigned)f2bf(y3)) << 16);
        *(uint2*)(Y + (size_t)row * 128 + cg * 4) = u;
    }
}

// ---- merged relation-folded weight builder ----
__global__ __launch_bounds__(256) void build_rel(
    const float* __restrict__ kqvW_l, const float* __restrict__ kqvb_l,
    const float* __restrict__ a_l, const float* __restrict__ m_l,
    bfu* __restrict__ WQAB, float* __restrict__ BQA,
    bfu* __restrict__ WVMB, float* __restrict__ BVM)
{
    __shared__ float As[32][33];
    __shared__ float Ws[32][129];
    int tid = threadIdx.x;
    int b = blockIdx.x;
    if (b < 32) {
        int r = b >> 2, h = b & 3;
        int dt = rdst_of(r);
        const float* Wq = kqvW_l + ((size_t)dt * 3 + 1) * 16384;
        const float* bq = kqvb_l + ((size_t)dt * 3 + 1) * 128;
        const float* A = a_l + (size_t)r * 4096 + h * 1024;
        for (int v = tid; v < 1024; v += 256) As[v >> 5][v & 31] = A[v];
        for (int v = tid; v < 4096; v += 256)
            Ws[v >> 7][v & 127] = Wq[(size_t)(h * 32 + (v >> 7)) * 128 + (v & 127)];
        __syncthreads();
        int c = tid & 127, half = tid >> 7;
        for (int d = half; d < 32; d += 2) {
            float acc = 0.f;
            #pragma unroll
            for (int f = 0; f < 32; ++f) acc = fmaf(As[d][f], Ws[f][c], acc);
            WQAB[((size_t)r * 128 + h * 32 + d) * 128 + c] = f2bf(acc);
        }
        if (tid < 32) {
            int d = tid;
            float acc = 0.f;
            #pragma unroll
            for (int f = 0; f < 32; ++f) acc = fmaf(As[d][f], bq[h * 32 + f], acc);
            BQA[(size_t)r * 128 + h * 32 + d] = acc;
        }
    } else {
        int bb2 = b - 32;
        int r = bb2 >> 2, h = bb2 & 3;
        int st = rsrc_of(r);
        const float* Wv = kqvW_l + ((size_t)st * 3 + 2) * 16384;
        const float* bv = kqvb_l + ((size_t)st * 3 + 2) * 128;
        const float* M = m_l + (size_t)r * 4096 + h * 1024;
        for (int v = tid; v < 1024; v += 256) As[v >> 5][v & 31] = M[v];  // As holds M here
        for (int v = tid; v < 4096; v += 256)
            Ws[v >> 7][v & 127] = Wv[(size_t)(h * 32 + (v >> 7)) * 128 + (v & 127)];
        __syncthreads();
        int c = tid & 127, half = tid >> 7;
        for (int f = half; f < 32; f += 2) {
            float acc = 0.f;
            #pragma unroll
            for (int d = 0; d < 32; ++d) acc = fmaf(As[d][f], Ws[d][c], acc);
            WVMB[((size_t)r * 128 + h * 32 + f) * 128 + c] = f2bf(acc);
        }
        if (tid < 32) {
            int f = tid;
            float acc = 0.f;
            #pragma unroll
            for (int d = 0; d < 32; ++d) acc = fmaf(As[d][f], bv[h * 32 + d], acc);
            BVM[(size_t)r * 128 + h * 32 + f] = acc;
        }
    }
}

// ---- batched MFMA GEMM: up to 9 descriptors, 32 rows/wave, 128 rows/block ----
struct GDesc { const bfu* X; const bfu* W; const float* bias; bfu* Y; int N; int ldy; int bend; };
struct GBatch { GDesc d[9]; };

__global__ __launch_bounds__(256) void mgemm_batch(GBatch gb) {
    int b = blockIdx.x;
    int gi = 0;
    #pragma unroll
    for (int k = 0; k < 8; ++k) gi += (b >= gb.d[k].bend) ? 1 : 0;
    const bfu* X = gb.d[0].X; const bfu* W = gb.d[0].W;
    const float* bi = gb.d[0].bias; bfu* Y = gb.d[0].Y;
    int N = gb.d[0].N, ldy = gb.d[0].ldy, bstart = 0;
    #pragma unroll
    for (int k = 1; k < 9; ++k) {
        if (gi == k) {
            X = gb.d[k].X; W = gb.d[k].W; bi = gb.d[k].bias; Y = gb.d[k].Y;
            N = gb.d[k].N; ldy = gb.d[k].ldy; bstart = gb.d[k - 1].bend;
        }
    }
    int bloc = b - bstart;
    const int tid = threadIdx.x;
    const int wave = tid >> 6, lane = tid & 63;
    const int row16 = lane & 15, kgrp = lane >> 4;
    const int r_base = bloc * 128 + wave * 32;
    f4 acc[2][8];
    #pragma unroll
    for (int t = 0; t < 2; ++t)
        #pragma unroll
        for (int n = 0; n < 8; ++n) acc[t][n] = (f4){0.f, 0.f, 0.f, 0.f};
    bh8 az = {0, 0, 0, 0, 0, 0, 0, 0};
    #pragma unroll
    for (int kb = 0; kb < 4; ++kb) {
        int ar0 = r_base + row16, ar1 = r_base + 16 + row16;
        bh8 a0 = az, a1 = az;
        if (ar0 < N) a0 = *(const bh8*)(X + (size_t)ar0 * 128 + kb * 32 + kgrp * 8);
        if (ar1 < N) a1 = *(const bh8*)(X + (size_t)ar1 * 128 + kb * 32 + kgrp * 8);
        #pragma unroll
        for (int n = 0; n < 8; ++n) {
            bh8 bv = *(const bh8*)(W + (size_t)(n * 16 + row16) * 128 + kb * 32 + kgrp * 8);
            acc[0][n] = __builtin_amdgcn_mfma_f32_16x16x32_bf16(a0, bv, acc[0][n], 0, 0, 0);
            acc[1][n] = __builtin_amdgcn_mfma_f32_16x16x32_bf16(a1, bv, acc[1][n], 0, 0, 0);
        }
    }
    #pragma unroll
    for (int t = 0; t < 2; ++t) {
        const int crow0 = r_base + t * 16 + kgrp * 4;
        #pragma unroll
        for (int n = 0; n < 8; ++n) {
            int col = n * 16 + row16;
            float bn = bi[col];
            #pragma unroll
            for (int j = 0; j < 4; ++j) {
                int row = crow0 + j;
                if (row < N) Y[(size_t)row * ldy + col] = f2bf(acc[t][n][j] + bn);
            }
        }
    }
}

// ---- dual-relation flash aggregation: 2 waves per node (feature halves) ----
// output: ACC[n][c] = bf16( gelu( a/d ) ), ACC aliases QAA (row-owner-safe)
__global__ __launch_bounds__(256) void agg_dual(
    const bfu* QAA, const bfu* __restrict__ QAB,
    const bfu* __restrict__ KA, const bfu* __restrict__ VMA,
    const bfu* __restrict__ KB, const bfu* __restrict__ VMB,
    const int* __restrict__ rpA, const int* __restrict__ rpB,
    const u16* __restrict__ sidx,
    const float* __restrict__ prlA, const float* __restrict__ prlB,
    bfu* ACC, int Nn)
{
    int n = blockIdx.x * 2 + (threadIdx.x >> 7);
    if (n >= Nn) return;
    int half = (threadIdx.x >> 6) & 1;
    int l = threadIdx.x & 63;
    int c = half * 64 + l;
    int h = c >> 5;
    const float inv = 0.17677669529663687f;

    float m0 = -3.0e38f, d0 = 0.f, a0 = 0.f;
    float m1 = -3.0e38f, d1 = 0.f, a1 = 0.f;

    // ---- relation A ----
    {
        float q = bf2f(QAA[(size_t)n * 128 + c]);
        float ph = prlA[h] * inv;
        int i = rpA[n], e1 = rpA[n + 1];
        for (; i + 1 < e1; i += 2) {
            int s0i = sidx[i], s1i = sidx[i + 1];
            float k0 = bf2f(KA[(size_t)s0i * 128 + c]);
            float k1 = bf2f(KA[(size_t)s1i * 128 + c]);
            float v0 = bf2f(VMA[(size_t)s0i * 128 + c]);
            float v1 = bf2f(VMA[(size_t)s1i * 128 + c]);
            float s0 = k0 * q, s1 = k1 * q;
            #pragma unroll
            for (int off = 1; off <= 16; off <<= 1) {
                s0 += __shfl_xor(s0, off);
                s1 += __shfl_xor(s1, off);
            }
            s0 *= ph; s1 *= ph;
            float nm0 = fmaxf(m0, s0);
            float sc0 = __expf(m0 - nm0), w0 = __expf(s0 - nm0);
            d0 = d0 * sc0 + w0; a0 = fmaf(w0, v0, a0 * sc0); m0 = nm0;
            float nm1 = fmaxf(m1, s1);
            float sc1 = __expf(m1 - nm1), w1 = __expf(s1 - nm1);
            d1 = d1 * sc1 + w1; a1 = fmaf(w1, v1, a1 * sc1); m1 = nm1;
        }
        if (i < e1) {
            int si = sidx[i];
            float k0 = bf2f(KA[(size_t)si * 128 + c]);
            float v0 = bf2f(VMA[(size_t)si * 128 + c]);
            float s0 = k0 * q;
            #pragma unroll
            for (int off = 1; off <= 16; off <<= 1) s0 += __shfl_xor(s0, off);
            s0 *= ph;
            float nm0 = fmaxf(m0, s0);
            float sc0 = __expf(m0 - nm0), w0 = __expf(s0 - nm0);
            d0 = d0 * sc0 + w0; a0 = fmaf(w0, v0, a0 * sc0); m0 = nm0;
        }
    }
    // ---- relation B ----
    {
        float q = bf2f(QAB[(size_t)n * 128 + c]);
        float ph = prlB[h] * inv;
        int i = rpB[n], e1 = rpB[n + 1];
        for (; i + 1 < e1; i += 2) {
            int s0i = sidx[i], s1i = sidx[i + 1];
            float k0 = bf2f(KB[(size_t)s0i * 128 + c]);
            float k1 = bf2f(KB[(size_t)s1i * 128 + c]);
            float v0 = bf2f(VMB[(size_t)s0i * 128 + c]);
            float v1 = bf2f(VMB[(size_t)s1i * 128 + c]);
            float s0 = k0 * q, s1 = k1 * q;
            #pragma unroll
            for (int off = 1; off <= 16; off <<= 1) {
                s0 += __shfl_xor(s0, off);
                s1 += __shfl_xor(s1, off);
            }
            s0 *= ph; s1 *= ph;
            float nm0 = fmaxf(m0, s0);
            float sc0 = __expf(m0 - nm0), w0 = __expf(s0 - nm0);
            d0 = d0 * sc0 + w0; a0 = fmaf(w0, v0, a0 * sc0); m0 = nm0;
            float nm1 = fmaxf(m1, s1);
            float sc1 = __expf(m1 - nm1), w1 = __expf(s1 - nm1);
            d1 = d1 * sc1 + w1; a1 = fmaf(w1, v1, a1 * sc1); m1 = nm1;
        }
        if (i < e1) {
            int si = sidx[i];
            float k0 = bf2f(KB[(size_t)si * 128 + c]);
            float v0 = bf2f(VMB[(size_t)si * 128 + c]);
            float s0 = k0 * q;
            #pragma unroll
            for (int off = 1; off <= 16; off <<= 1) s0 += __shfl_xor(s0, off);
            s0 *= ph;
            float nm0 = fmaxf(m0, s0);
            float sc0 = __expf(m0 - nm0), w0 = __expf(s0 - nm0);
            d0 = d0 * sc0 + w0; a0 = fmaf(w0, v0, a0 * sc0); m0 = nm0;
        }
    }
    // merge the two chains
    float nm = fmaxf(m0, m1);
    float sA = __expf(m0 - nm), sB = __expf(m1 - nm);
    float d = d0 * sA + d1 * sB;
    float a = a0 * sA + a1 * sB;
    float y = gelu_f(a / fmaxf(d, 1e-16f));
    ACC[(size_t)n * 128 + c] = f2bf(y);
}

// ---- layer epilogue: plain A (already gelu'd); out-proj; skip+LN+relu; bf16 out ----
__global__ __launch_bounds__(256) void mgemm_epi_layer(
    const bfu* __restrict__ A, const bfu* __restrict__ W, const float* __restrict__ bias,
    const bfu* __restrict__ Xr, const float* __restrict__ skp,
    const float* __restrict__ g, const float* __restrict__ bb,
    bfu* __restrict__ Y, int N)
{
    const int tid = threadIdx.x;
    const int wave = tid >> 6, lane = tid & 63;
    const int row16 = lane & 15, kgrp = lane >> 4;
    const int r_base = blockIdx.x * 64 + wave * 16;
    const int arow = r_base + row16;
    f4 acc[8];
    #pragma unroll
    for (int n = 0; n < 8; ++n) acc[n] = (f4){0.f, 0.f, 0.f, 0.f};
    bh8 az = {0, 0, 0, 0, 0, 0, 0, 0};
    #pragma unroll
    for (int kb = 0; kb < 4; ++kb) {
        bh8 a = az;
        if (arow < N) a = *(const bh8*)(A + (size_t)arow * 128 + kb * 32 + kgrp * 8);
        #pragma unroll
        for (int n = 0; n < 8; ++n) {
            bh8 bv = *(const bh8*)(W + (size_t)(n * 16 + row16) * 128 + kb * 32 + kgrp * 8);
            acc[n] = __builtin_amdgcn_mfma_f32_16x16x32_bf16(a, bv, acc[n], 0, 0, 0);
        }
    }
    const int crow0 = r_base + kgrp * 4;
    float sg = 1.f / (1.f + expf(-skp[0]));
    float z[8][4];
    #pragma unroll
    for (int n = 0; n < 8; ++n) {
        float bn = bias[n * 16 + row16];
        #pragma unroll
        for (int j = 0; j < 4; ++j) z[n][j] = acc[n][j] + bn;
    }
    #pragma unroll
    for (int j = 0; j < 4; ++j) {
        int row = crow0 + j;
        if (row >= N) continue;
        #pragma unroll
        for (int n = 0; n < 8; ++n) {
            float xr = bf2f(Xr[(size_t)row * 128 + n * 16 + row16]);
            z[n][j] = sg * z[n][j] + (1.f - sg) * xr + xr;
        }
    }
    float s[4], q[4];
    #pragma unroll
    for (int j = 0; j < 4; ++j) {
        s[j] = 0.f; q[j] = 0.f;
        #pragma unroll
        for (int n = 0; n < 8; ++n) { s[j] += z[n][j]; q[j] += z[n][j] * z[n][j]; }
    }
    #pragma unroll
    for (int off = 1; off <= 8; off <<= 1) {
        #pragma unroll
        for (int j = 0; j < 4; ++j) {
            s[j] += __shfl_xor(s[j], off);
            q[j] += __shfl_xor(q[j], off);
        }
    }
    #pragma unroll
    for (int j = 0; j < 4; ++j) {
        int row = crow0 + j;
        if (row >= N) continue;
        float mean = s[j] * (1.f / 128.f);
        float var = q[j] * (1.f / 128.f) - mean * mean;
        float inv = rsqrtf(var + 1e-5f);
        #pragma unroll
        for (int n = 0; n < 8; ++n) {
            int col = n * 16 + row16;
            float y = (z[n][j] - mean) * inv * g[col] + bb[col];
            Y[(size_t)row * 128 + col] = f2bf(fmaxf(y, 0.f));
        }
    }
}

// ---- fusion final: out-proj; LN; f32 out ----
__global__ __launch_bounds__(256) void mgemm_epi_ln(
    const bfu* __restrict__ X, const bfu* __restrict__ W, const float* __restrict__ bias,
    const float* __restrict__ g, const float* __restrict__ bb,
    float* __restrict__ Y, int N)
{
    const int tid = threadIdx.x;
    const int wave = tid >> 6, lane = tid & 63;
    const int row16 = lane & 15, kgrp = lane >> 4;
    const int r_base = blockIdx.x * 64 + wave * 16;
    const int arow = r_base + row16;
    f4 acc[8];
    #pragma unroll
    for (int n = 0; n < 8; ++n) acc[n] = (f4){0.f, 0.f, 0.f, 0.f};
    bh8 az = {0, 0, 0, 0, 0, 0, 0, 0};
    #pragma unroll
    for (int kb = 0; kb < 4; ++kb) {
        bh8 a = az;
        if (arow < N) a = *(const bh8*)(X + (size_t)arow * 128 + kb * 32 + kgrp * 8);
        #pragma unroll
        for (int n = 0; n < 8; ++n) {
            bh8 bv = *(const bh8*)(W + (size_t)(n * 16 + row16) * 128 + kb * 32 + kgrp * 8);
            acc[n] = __builtin_amdgcn_mfma_f32_16x16x32_bf16(a, bv, acc[n], 0, 0, 0);
        }
    }
    const int crow0 = r_base + kgrp * 4;
    float z[8][4];
    #pragma unroll
    for (int n = 0; n < 8; ++n) {
        float bn = bias[n * 16 + row16];
        #pragma unroll
        for (int j = 0; j < 4; ++j) z[n][j] = acc[n][j] + bn;
    }
    float s[4], q[4];
    #pragma unroll
    for (int j = 0; j < 4; ++j) {
        s[j] = 0.f; q[j] = 0.f;
        #pragma unroll
        for (int n = 0; n < 8; ++n) { s[j] += z[n][j]; q[j] += z[n][j] * z[n][j]; }
    }
    #pragma unroll
    for (int off = 1; off <= 8; off <<= 1) {
        #pragma unroll
        for (int j = 0; j < 4; ++j) {
            s[j] += __shfl_xor(s[j], off);
            q[j] += __shfl_xor(q[j], off);
        }
    }
    #pragma unroll
    for (int j = 0; j < 4; ++j) {
        int row = crow0 + j;
        if (row >= N) continue;
        float mean = s[j] * (1.f / 128.f);
        float var = q[j] * (1.f / 128.f) - mean * mean;
        float inv = rsqrtf(var + 1e-5f);
        #pragma unroll
        for (int n = 0; n < 8; ++n) {
            int col = n * 16 + row16;
            Y[(size_t)row * 128 + col] = (z[n][j] - mean) * inv * g[col] + bb[col];
        }
    }
}

// ---- fusion attention (3 tokens, 4 heads), wave per node, bf16 out ----
__global__ __launch_bounds__(256) void attn_fuse(
    const bfu* __restrict__ QKV, bfu* __restrict__ OM, int M)
{
    int n = blockIdx.x * 4 + (threadIdx.x >> 6);
    int l = threadIdx.x & 63;
    if (n >= M) return;
    const bfu* base = QKV + (size_t)n * 1152;
    float q[3][2], k[3][2], v[3][2];
    #pragma unroll
    for (int p = 0; p < 3; ++p) {
        q[p][0] = bf2f(base[(0 * 3 + p) * 128 + l]);
        q[p][1] = bf2f(base[(0 * 3 + p) * 128 + l + 64]);
        k[p][0] = bf2f(base[(1 * 3 + p) * 128 + l]);
        k[p][1] = bf2f(base[(1 * 3 + p) * 128 + l + 64]);
        v[p][0] = bf2f(base[(2 * 3 + p) * 128 + l]);
        v[p][1] = bf2f(base[(2 * 3 + p) * 128 + l + 64]);
    }
    float lgA[3][3], lgB[3][3];
    #pragma unroll
    for (int qi = 0; qi < 3; ++qi)
        #pragma unroll
        for (int ki = 0; ki < 3; ++ki) {
            float s0 = q[qi][0] * k[ki][0];
            float s1 = q[qi][1] * k[ki][1];
            #pragma unroll
            for (int off = 1; off <= 16; off <<= 1) {
                s0 += __shfl_xor(s0, off);
                s1 += __shfl_xor(s1, off);
            }
            lgA[qi][ki] = s0 * 0.17677669529663687f;
            lgB[qi][ki] = s1 * 0.17677669529663687f;
        }
    float oA = 0.f, oB = 0.f;
    #pragma unroll
    for (int qi = 0; qi < 3; ++qi) {
        float mA = fmaxf(lgA[qi][0], fmaxf(lgA[qi][1], lgA[qi][2]));
        float e0 = __expf(lgA[qi][0] - mA), e1 = __expf(lgA[qi][1] - mA), e2 = __expf(lgA[qi][2] - mA);
        float rd = 1.f / (e0 + e1 + e2);
        oA += (e0 * v[0][0] + e1 * v[1][0] + e2 * v[2][0]) * rd;
        float mB = fmaxf(lgB[qi][0], fmaxf(lgB[qi][1], lgB[qi][2]));
        float f0 = __expf(lgB[qi][0] - mB), f1 = __expf(lgB[qi][1] - mB), f2 = __expf(lgB[qi][2] - mB);
        float rdB = 1.f / (f0 + f1 + f2);
        oB += (f0 * v[0][1] + f1 * v[1][1] + f2 * v[2][1]) * rdB;
    }
    OM[(size_t)n * 128 + l] = f2bf(oA * (1.f / 3.f));
    OM[(size_t)n * 128 + l + 64] = f2bf(oB * (1.f / 3.f));
}

extern "C" void kernel_launch(void* const* d_in, const int* in_sizes, int n_in,
                              void* d_out, int out_size, void* d_ws, size_t ws_size,
                              hipStream_t stream)
{
    const float* x_pest   = (const float*)d_in[0];
    const float* x_dis    = (const float*)d_in[1];
    const float* x_plant  = (const float*)d_in[2];
    const int*   edges    = (const int*)d_in[3];
    const float* proj_W   = (const float*)d_in[4];
    const float* proj_b   = (const float*)d_in[5];
    const float* event_emb= (const float*)d_in[6];
    const float* kqv_W    = (const float*)d_in[7];
    const float* kqv_b    = (const float*)d_in[8];
    const float* out_W    = (const float*)d_in[9];
    const float* out_b    = (const float*)d_in[10];
    const float* skip     = (const float*)d_in[11];
    const float* a_rel    = (const float*)d_in[12];
    const float* m_rel    = (const float*)d_in[13];
    const float* p_rel    = (const float*)d_in[14];
    const float* blk_ln_g = (const float*)d_in[15];
    const float* blk_ln_b = (const float*)d_in[16];
    const float* fin_W    = (const float*)d_in[17];
    const float* fin_b    = (const float*)d_in[18];
    const float* fout_W   = (const float*)d_in[19];
    const float* fout_b   = (const float*)d_in[20];
    const float* f_ln_g   = (const float*)d_in[21];
    const float* f_ln_b   = (const float*)d_in[22];
    float* out = (float*)d_out;

    static const int NT[4]  = {30000, 20000, 25000, 50000};
    static const int OFF[4] = {0, 30000, 50000, 75000};
    static const int RPOFF[9] = {0, 20001, 50002, 70003, 95004, 125005, 175006, 200007, 250008};
    static const int DG[4][2][2] = { {{1,1},{4,3}}, {{0,0},{2,2}}, {{3,1},{6,3}}, {{5,0},{7,2}} };

    char* wsb = (char*)d_ws;
    size_t ob = 0;
    auto alc = [&](size_t bytes) -> void* {
        void* p = wsb + ob; ob += (bytes + 255) & ~(size_t)255; return p;
    };
    bfu* LK0  = (bfu*)alc((size_t)75000 * 128 * 2);
    bfu* LK1  = (bfu*)alc((size_t)75000 * 128 * 2);
    bfu* POOL = (bfu*)alc((size_t)210000 * 128 * 2);   // QA_A/QA_B/K/VM pool; fusion QKV; CUR
    bfu* WQAB = (bfu*)alc((size_t)8 * 16384 * 2);
    float* BQA = (float*)alc((size_t)8 * 128 * 4);
    bfu* WVMB = (bfu*)alc((size_t)8 * 16384 * 2);
    float* BVM = (float*)alc((size_t)8 * 128 * 4);
    bfu* KWB  = (bfu*)alc((size_t)12 * 16384 * 2);
    bfu* OWB  = (bfu*)alc((size_t)12 * 16384 * 2);
    bfu* FINWB = (bfu*)alc((size_t)3 * 49152 * 2);
    bfu* FOUTWB = (bfu*)alc((size_t)3 * 16384 * 2);
    int* RP   = (int*)alc((size_t)250008 * 4);
    int* PART = (int*)alc(1024);
    u16* SIDX = (u16*)alc((size_t)8 * E_CNT * 2);
    if (ws_size < ob) {
        fill_val<<<(out_size + 255) / 256, 256, 0, stream>>>(out, out_size, 1e30f);
        return;
    }
    int* CUR = (int*)POOL;       // CSR counters (1.6MB), used before pool
    bfu* QKVf = POOL;            // fusion QKV (CH*1152*2 <= 46.08MB <= 53.76MB)
    bfu* OMB  = POOL + (size_t)20000 * 1152;  // attn out (5.12MB, ends at 51.2MB)

    // d_out overlay (time-disjoint): EVB [0,12.8M); XB [12.8,32.0M); L2F [19.2,38.4M)
    bfu* EVB = (bfu*)out;
    bfu* XB  = (bfu*)((char*)out + 12800000);
    bfu* L2F = (bfu*)((char*)out + 19200000);

    cvt_pack<<<(1747456 + 255) / 256, 256, 0, stream>>>(
        out_W, kqv_W, fin_W, fout_W, event_emb, OWB, KWB, FINWB, FOUTWB, EVB);

    // ---- CSR build ----
    hipMemsetAsync(RP, 0, (size_t)250008 * 4, stream);
    const int eg8 = (8 * E_CNT + 255) / 256;
    hist_all<<<eg8, 256, 0, stream>>>(edges, RP);
    scan_part<<<245, 1024, 0, stream>>>(RP, PART, 250008);
    scan_tot<<<1, 256, 0, stream>>>(PART, 245);
    scan_add<<<244, 1024, 0, stream>>>(RP, PART, 250008);
    hipMemsetAsync(CUR, 0, (size_t)8 * 50000 * 4, stream);
    scatter_all<<<eg8, 256, 0, stream>>>(edges, RP, CUR, SIDX);

    // ---- input projections ----
    const float* xin0[3] = {x_pest, x_dis, x_plant};
    for (int t = 0; t < 3; ++t) {
        proj_gemm<<<(NT[t] + 31) / 32, 256, 0, stream>>>(
            xin0[t], proj_W + (size_t)t * 8192, proj_b + (size_t)t * 128,
            XB + (size_t)OFF[t] * 128, NT[t]);
    }

    auto launch_batch = [&](GDesc* ds, int cnt) {
        GBatch gb;
        int acc = 0;
        for (int i = 0; i < cnt; ++i) {
            gb.d[i] = ds[i];
            acc += (ds[i].N + 127) / 128;
            gb.d[i].bend = acc;
        }
        for (int i = cnt; i < 9; ++i) { gb.d[i] = gb.d[cnt - 1]; gb.d[i].bend = acc; }
        mgemm_batch<<<acc, 256, 0, stream>>>(gb);
    };

    for (int l = 0; l < 3; ++l) {
        const float* kqvW_l = kqv_W + (size_t)l * 12 * 16384;
        const float* kqvb_l = kqv_b + (size_t)l * 12 * 128;
        build_rel<<<64, 256, 0, stream>>>(kqvW_l, kqvb_l,
            a_rel + (size_t)l * 8 * 4096, m_rel + (size_t)l * 8 * 4096,
            WQAB, BQA, WVMB, BVM);

        auto feat_ptr = [&](int tt) -> const bfu* {
            if (tt == 3) return EVB;
            if (l == 0) return XB + (size_t)OFF[tt] * 128;
            return (l == 1 ? LK0 : LK1) + (size_t)OFF[tt] * 128;
        };

        int nord = (l == 2) ? 3 : 4;
        for (int dt = 0; dt < nord; ++dt) {
            int Ndt = NT[dt];
            int rA = DG[dt][0][0], sA = DG[dt][0][1];
            int rB = DG[dt][1][0], sB = DG[dt][1][1];
            int NsA = NT[sA], NsB = NT[sB];
            // pool layout (rows of 128 bf16): QA_A | QA_B | K_A | VM_A | K_B | VM_B
            bfu* QA_A = POOL;
            bfu* QA_B = QA_A + (size_t)Ndt * 128;
            bfu* K_A  = QA_B + (size_t)Ndt * 128;
            bfu* VM_A = K_A + (size_t)NsA * 128;
            bfu* K_B  = VM_A + (size_t)NsA * 128;
            bfu* VM_B = K_B + (size_t)NsB * 128;

            GDesc ds[6];
            ds[0] = { feat_ptr(dt), WQAB + (size_t)rA * 16384, BQA + (size_t)rA * 128, QA_A, Ndt, 128, 0 };
            ds[1] = { feat_ptr(dt), WQAB + (size_t)rB * 16384, BQA + (size_t)rB * 128, QA_B, Ndt, 128, 0 };
            ds[2] = { feat_ptr(sA), KWB + (size_t)(l * 4 + sA) * 16384,
                      kqvb_l + ((size_t)sA * 3 + 0) * 128, K_A, NsA, 128, 0 };
            ds[3] = { feat_ptr(sA), WVMB + (size_t)rA * 16384, BVM + (size_t)rA * 128, VM_A, NsA, 128, 0 };
            ds[4] = { feat_ptr(sB), KWB + (size_t)(l * 4 + sB) * 16384,
                      kqvb_l + ((size_t)sB * 3 + 0) * 128, K_B, NsB, 128, 0 };
            ds[5] = { feat_ptr(sB), WVMB + (size_t)rB * 16384, BVM + (size_t)rB * 128, VM_B, NsB, 128, 0 };
            launch_batch(ds, 6);

            agg_dual<<<(Ndt + 1) / 2, 256, 0, stream>>>(
                QA_A, QA_B, K_A, VM_A, K_B, VM_B,
                RP + RPOFF[rA], RP + RPOFF[rB], SIDX,
                p_rel + (size_t)(l * 8 + rA) * 4, p_rel + (size_t)(l * 8 + rB) * 4,
                QA_A /*ACC alias*/, Ndt);

            size_t wi = (size_t)l * 4 + dt;
            const bfu* xr = feat_ptr(dt);
            bfu* ydst = (dt == 3) ? EVB :
                        (l == 0 ? LK0 : (l == 1 ? LK1 : L2F)) + (size_t)OFF[dt] * 128;
            mgemm_epi_layer<<<(Ndt + 63) / 64, 256, 0, stream>>>(
                QA_A, OWB + wi * 16384, out_b + wi * 128, xr, skip + wi,
                blk_ln_g + (size_t)l * 128, blk_ln_b + (size_t)l * 128, ydst, Ndt);
        }
    }

    // ---- fusion heads ----
    const int CH = 20000;
    for (int j = 0; j < 3; ++j) {
        int Nj = NT[j];
        for (int b0 = 0; b0 < Nj; b0 += CH) {
            int M = min(CH, Nj - b0);
            const bfu* srcs[3] = {
                LK0 + (size_t)(OFF[j] + b0) * 128,
                LK1 + (size_t)(OFF[j] + b0) * 128,
                L2F + (size_t)(OFF[j] + b0) * 128 };
            GDesc ds[9];
            int di = 0;
            for (int kk = 0; kk < 3; ++kk)
                for (int p = 0; p < 3; ++p) {
                    ds[di++] = { srcs[p], FINWB + (size_t)j * 49152 + (size_t)kk * 16384,
                                 fin_b + (size_t)j * 384 + kk * 128,
                                 QKVf + (size_t)(kk * 3 + p) * 128, M, 1152, 0 };
                }
            launch_batch(ds, 9);
            attn_fuse<<<(M + 3) / 4, 256, 0, stream>>>(QKVf, OMB, M);
            mgemm_epi_ln<<<(M + 63) / 64, 256, 0, stream>>>(
                OMB, FOUTWB + (size_t)j * 16384, fout_b + (size_t)j * 128,
                f_ln_g + (size_t)j * 128, f_ln_b + (size_t)j * 128,
                out + (size_t)(OFF[j] + b0) * 128, M);
        }
    }
}

// Round 9
// 1801.864 us; speedup vs baseline: 6.8793x; 1.1761x over previous
//
#include <hip/hip_runtime.h>
#include <math.h>

#define E_CNT 200000
typedef unsigned short bfu;
typedef unsigned short u16;
typedef __attribute__((ext_vector_type(8))) short bh8;
typedef __attribute__((ext_vector_type(4))) float f4;

__device__ __forceinline__ float gelu_f(float x) {
    return 0.5f * x * (1.0f + erff(x * 0.70710678118654752f));
}
__device__ __forceinline__ float bf2f(bfu u) { return __uint_as_float(((unsigned)u) << 16); }
__device__ __forceinline__ bfu f2bf(float f) {
    unsigned u = __float_as_uint(f);
    unsigned r = u + 0x7FFFu + ((u >> 16) & 1u);
    return (bfu)(r >> 16);
}
__device__ __forceinline__ int rsrc_of(int r) {
    const int a[8] = {0, 1, 2, 1, 3, 0, 3, 2}; return a[r];
}
__device__ __forceinline__ int rdst_of(int r) {
    const int a[8] = {1, 0, 1, 2, 0, 3, 2, 3}; return a[r];
}
__device__ __forceinline__ int rpoff_of(int r) {
    const int a[9] = {0, 20001, 50002, 70003, 95004, 125005, 175006, 200007, 250008};
    return a[r];
}

__global__ __launch_bounds__(256) void fill_val(float* p, int n, float v) {
    int i = blockIdx.x * 256 + threadIdx.x;
    if (i < n) p[i] = v;
}

// ---- one-shot f32->bf16 weight/emb converts ----
__global__ __launch_bounds__(256) void cvt_pack(
    const float* __restrict__ out_W, const float* __restrict__ kqv_W,
    const float* __restrict__ fin_W, const float* __restrict__ fout_W,
    const float* __restrict__ event_emb,
    bfu* __restrict__ OWB, bfu* __restrict__ KWB, bfu* __restrict__ FINWB,
    bfu* __restrict__ FOUTWB, bfu* __restrict__ EVB)
{
    int i = blockIdx.x * 256 + threadIdx.x;
    const float* src; bfu* dst; size_t so, dox;
    if (i < 49152) { src = out_W; dst = OWB; so = (size_t)i * 4; dox = so; }
    else if (i < 98304) {
        int j = i - 49152; int m = j >> 12; int o = (j & 4095) * 4;
        src = kqv_W; dst = KWB;
        so = (size_t)m * 3 * 16384 + o; dox = (size_t)m * 16384 + o;
    }
    else if (i < 135168) { int j = i - 98304; src = fin_W; dst = FINWB; so = (size_t)j * 4; dox = so; }
    else if (i < 147456) { int j = i - 135168; src = fout_W; dst = FOUTWB; so = (size_t)j * 4; dox = so; }
    else if (i < 1747456) { int j = i - 147456; src = event_emb; dst = EVB; so = (size_t)j * 4; dox = so; }
    else return;
    float4 v = *(const float4*)(src + so);
    uint2 u;
    u.x = ((unsigned)f2bf(v.x)) | (((unsigned)f2bf(v.y)) << 16);
    u.y = ((unsigned)f2bf(v.z)) | (((unsigned)f2bf(v.w)) << 16);
    *(uint2*)(dst + dox) = u;
}

// ---- CSR build ----
__global__ __launch_bounds__(256) void hist_all(const int* __restrict__ edges, int* __restrict__ rp) {
    int i = blockIdx.x * 256 + threadIdx.x;
    if (i >= 8 * E_CNT) return;
    int r = i / E_CNT, e = i - r * E_CNT;
    int d = edges[(size_t)(2 * r + 1) * E_CNT + e];
    atomicAdd(&rp[rpoff_of(r) + d + 1], 1);
}
__global__ __launch_bounds__(1024) void scan_part(int* __restrict__ a, int* __restrict__ part, int n) {
    __shared__ int lds[1024];
    int t = threadIdx.x, i = blockIdx.x * 1024 + t;
    int v = (i < n) ? a[i] : 0;
    lds[t] = v;
    __syncthreads();
    for (int off = 1; off < 1024; off <<= 1) {
        int u = (t >= off) ? lds[t - off] : 0;
        __syncthreads();
        lds[t] += u;
        __syncthreads();
    }
    if (i < n) a[i] = lds[t];
    if (t == 1023) part[blockIdx.x] = lds[1023];
}
__global__ __launch_bounds__(256) void scan_tot(int* __restrict__ part, int nb) {
    __shared__ int lds[256];
    int t = threadIdx.x;
    int v = (t < nb) ? part[t] : 0;
    lds[t] = v;
    __syncthreads();
    for (int off = 1; off < 256; off <<= 1) {
        int u = (t >= off) ? lds[t - off] : 0;
        __syncthreads();
        lds[t] += u;
        __syncthreads();
    }
    if (t < nb) part[t] = lds[t];
}
__global__ __launch_bounds__(1024) void scan_add(int* __restrict__ a, const int* __restrict__ part, int n) {
    int b = blockIdx.x + 1;
    int i = b * 1024 + threadIdx.x;
    if (i < n) a[i] += part[b - 1];
}
__global__ __launch_bounds__(256) void scatter_all(
    const int* __restrict__ edges, const int* __restrict__ RP,
    int* __restrict__ cur, u16* __restrict__ SIDX) {
    int i = blockIdx.x * 256 + threadIdx.x;
    if (i >= 8 * E_CNT) return;
    int r = i / E_CNT, e = i - r * E_CNT;
    int d = edges[(size_t)(2 * r + 1) * E_CNT + e];
    int pos = RP[rpoff_of(r) + d] + atomicAdd(&cur[r * 50000 + d], 1);
    SIDX[pos] = (u16)edges[(size_t)(2 * r) * E_CNT + e];
}

// ---- input projection (f32[N,64] -> relu -> bf16[N,128]) ----
__global__ __launch_bounds__(256) void proj_gemm(
    const float* __restrict__ X, const float* __restrict__ W,
    const float* __restrict__ bias, bfu* __restrict__ Y, int N)
{
    __shared__ __align__(16) float Wt[32][132];
    __shared__ __align__(16) float Xt[32][36];
    const int tid = threadIdx.x;
    const int r0 = blockIdx.x * 32;
    const int rg = tid >> 5, cg = tid & 31;
    float acc[4][4];
    #pragma unroll
    for (int i = 0; i < 4; ++i)
        #pragma unroll
        for (int j = 0; j < 4; ++j) acc[i][j] = 0.f;
    for (int c0 = 0; c0 < 64; c0 += 32) {
        __syncthreads();
        #pragma unroll
        for (int k = 0; k < 4; ++k) {
            int v = tid + k * 256;
            int j = v >> 3, c4 = (v & 7) * 4;
            float4 w = *(const float4*)(W + (size_t)j * 64 + c0 + c4);
            Wt[c4 + 0][j] = w.x; Wt[c4 + 1][j] = w.y;
            Wt[c4 + 2][j] = w.z; Wt[c4 + 3][j] = w.w;
        }
        {
            int rr = tid >> 3, c4 = (tid & 7) * 4;
            int row = r0 + rr;
            float4 x = make_float4(0.f, 0.f, 0.f, 0.f);
            if (row < N) x = *(const float4*)(X + (size_t)row * 64 + c0 + c4);
            Xt[c4 + 0][rr] = x.x; Xt[c4 + 1][rr] = x.y;
            Xt[c4 + 2][rr] = x.z; Xt[c4 + 3][rr] = x.w;
        }
        __syncthreads();
        #pragma unroll
        for (int cc = 0; cc < 32; ++cc) {
            float4 xv = *(const float4*)(&Xt[cc][rg * 4]);
            float4 wv = *(const float4*)(&Wt[cc][cg * 4]);
            #pragma unroll
            for (int i = 0; i < 4; ++i) {
                float xs = (i == 0) ? xv.x : (i == 1) ? xv.y : (i == 2) ? xv.z : xv.w;
                acc[i][0] = fmaf(xs, wv.x, acc[i][0]);
                acc[i][1] = fmaf(xs, wv.y, acc[i][1]);
                acc[i][2] = fmaf(xs, wv.z, acc[i][2]);
                acc[i][3] = fmaf(xs, wv.w, acc[i][3]);
            }
        }
    }
    float4 bv = *(const float4*)(bias + cg * 4);
    #pragma unroll
    for (int ri = 0; ri < 4; ++ri) {
        int row = r0 + rg * 4 + ri;
        if (row >= N) continue;
        float y0 = fmaxf(acc[ri][0] + bv.x, 0.f);
        float y1 = fmaxf(acc[ri][1] + bv.y, 0.f);
        float y2 = fmaxf(acc[ri][2] + bv.z, 0.f);
        float y3 = fmaxf(acc[ri][3] + bv.w, 0.f);
        uint2 u;
        u.x = ((unsigned)f2bf(y0)) | (((unsigned)f2bf(y1)) << 16);
        u.y = ((unsigned)f2bf(y2)) | (((unsigned)f2bf(y3)) << 16);
        *(uint2*)(Y + (size_t)row * 128 + cg * 4) = u;
    }
}

// ---- merged relation-folded weight builder ----
__global__ __launch_bounds__(256) void build_rel(
    const float* __restrict__ kqvW_l, const float* __restrict__ kqvb_l,
    const float* __restrict__ a_l, const float* __restrict__ m_l,
    bfu* __restrict__ WQAB, float* __restrict__ BQA,
    bfu* __restrict__ WVMB, float* __restrict__ BVM)
{
    __shared__ float As[32][33];
    __shared__ float Ws[32][129];
    int tid = threadIdx.x;
    int b = blockIdx.x;
    if (b < 32) {
        int r = b >> 2, h = b & 3;
        int dt = rdst_of(r);
        const float* Wq = kqvW_l + ((size_t)dt * 3 + 1) * 16384;
        const float* bq = kqvb_l + ((size_t)dt * 3 + 1) * 128;
        const float* A = a_l + (size_t)r * 4096 + h * 1024;
        for (int v = tid; v < 1024; v += 256) As[v >> 5][v & 31] = A[v];
        for (int v = tid; v < 4096; v += 256)
            Ws[v >> 7][v & 127] = Wq[(size_t)(h * 32 + (v >> 7)) * 128 + (v & 127)];
        __syncthreads();
        int c = tid & 127, half = tid >> 7;
        for (int d = half; d < 32; d += 2) {
            float acc = 0.f;
            #pragma unroll
            for (int f = 0; f < 32; ++f) acc = fmaf(As[d][f], Ws[f][c], acc);
            WQAB[((size_t)r * 128 + h * 32 + d) * 128 + c] = f2bf(acc);
        }
        if (tid < 32) {
            int d = tid;
            float acc = 0.f;
            #pragma unroll
            for (int f = 0; f < 32; ++f) acc = fmaf(As[d][f], bq[h * 32 + f], acc);
            BQA[(size_t)r * 128 + h * 32 + d] = acc;
        }
    } else {
        int bb2 = b - 32;
        int r = bb2 >> 2, h = bb2 & 3;
        int st = rsrc_of(r);
        const float* Wv = kqvW_l + ((size_t)st * 3 + 2) * 16384;
        const float* bv = kqvb_l + ((size_t)st * 3 + 2) * 128;
        const float* M = m_l + (size_t)r * 4096 + h * 1024;
        for (int v = tid; v < 1024; v += 256) As[v >> 5][v & 31] = M[v];  // As holds M here
        for (int v = tid; v < 4096; v += 256)
            Ws[v >> 7][v & 127] = Wv[(size_t)(h * 32 + (v >> 7)) * 128 + (v & 127)];
        __syncthreads();
        int c = tid & 127, half = tid >> 7;
        for (int f = half; f < 32; f += 2) {
            float acc = 0.f;
            #pragma unroll
            for (int d = 0; d < 32; ++d) acc = fmaf(As[d][f], Ws[d][c], acc);
            WVMB[((size_t)r * 128 + h * 32 + f) * 128 + c] = f2bf(acc);
        }
        if (tid < 32) {
            int f = tid;
            float acc = 0.f;
            #pragma unroll
            for (int d = 0; d < 32; ++d) acc = fmaf(As[d][f], bv[h * 32 + d], acc);
            BVM[(size_t)r * 128 + h * 32 + f] = acc;
        }
    }
}

// ---- batched MFMA GEMM: up to 9 descriptors, 32 rows/wave, 128 rows/block ----
struct GDesc { const bfu* X; const bfu* W; const float* bias; bfu* Y; int N; int ldy; int bend; };
struct GBatch { GDesc d[9]; };

__global__ __launch_bounds__(256) void mgemm_batch(GBatch gb) {
    int b = blockIdx.x;
    int gi = 0;
    #pragma unroll
    for (int k = 0; k < 8; ++k) gi += (b >= gb.d[k].bend) ? 1 : 0;
    const bfu* X = gb.d[0].X; const bfu* W = gb.d[0].W;
    const float* bi = gb.d[0].bias; bfu* Y = gb.d[0].Y;
    int N = gb.d[0].N, ldy = gb.d[0].ldy, bstart = 0;
    #pragma unroll
    for (int k = 1; k < 9; ++k) {
        if (gi == k) {
            X = gb.d[k].X; W = gb.d[k].W; bi = gb.d[k].bias; Y = gb.d[k].Y;
            N = gb.d[k].N; ldy = gb.d[k].ldy; bstart = gb.d[k - 1].bend;
        }
    }
    int bloc = b - bstart;
    const int tid = threadIdx.x;
    const int wave = tid >> 6, lane = tid & 63;
    const int row16 = lane & 15, kgrp = lane >> 4;
    const int r_base = bloc * 128 + wave * 32;
    f4 acc[2][8];
    #pragma unroll
    for (int t = 0; t < 2; ++t)
        #pragma unroll
        for (int n = 0; n < 8; ++n) acc[t][n] = (f4){0.f, 0.f, 0.f, 0.f};
    bh8 az = {0, 0, 0, 0, 0, 0, 0, 0};
    #pragma unroll
    for (int kb = 0; kb < 4; ++kb) {
        int ar0 = r_base + row16, ar1 = r_base + 16 + row16;
        bh8 a0 = az, a1 = az;
        if (ar0 < N) a0 = *(const bh8*)(X + (size_t)ar0 * 128 + kb * 32 + kgrp * 8);
        if (ar1 < N) a1 = *(const bh8*)(X + (size_t)ar1 * 128 + kb * 32 + kgrp * 8);
        #pragma unroll
        for (int n = 0; n < 8; ++n) {
            bh8 bv = *(const bh8*)(W + (size_t)(n * 16 + row16) * 128 + kb * 32 + kgrp * 8);
            acc[0][n] = __builtin_amdgcn_mfma_f32_16x16x32_bf16(a0, bv, acc[0][n], 0, 0, 0);
            acc[1][n] = __builtin_amdgcn_mfma_f32_16x16x32_bf16(a1, bv, acc[1][n], 0, 0, 0);
        }
    }
    #pragma unroll
    for (int t = 0; t < 2; ++t) {
        const int crow0 = r_base + t * 16 + kgrp * 4;
        #pragma unroll
        for (int n = 0; n < 8; ++n) {
            int col = n * 16 + row16;
            float bn = bi[col];
            #pragma unroll
            for (int j = 0; j < 4; ++j) {
                int row = crow0 + j;
                if (row < N) Y[(size_t)row * ldy + col] = f2bf(acc[t][n][j] + bn);
            }
        }
    }
}

// ---- dual-relation flash aggregation: ONE wave per node, 4B loads ----
// lane l: features c0=2l, c1=2l+1; head h = l>>4 (16-lane groups).
// Single online softmax chain across both relations. Output = gelu(a/d) bf16.
// ACC aliases QAA (row-owner-safe: wave reads its QAA row before writing it).
__global__ __launch_bounds__(256) void agg_dual(
    const bfu* QAA, const bfu* __restrict__ QAB,
    const bfu* __restrict__ KA, const bfu* __restrict__ VMA,
    const bfu* __restrict__ KB, const bfu* __restrict__ VMB,
    const int* __restrict__ rpA, const int* __restrict__ rpB,
    const u16* __restrict__ sidx,
    const float* __restrict__ prlA, const float* __restrict__ prlB,
    bfu* ACC, int Nn)
{
    int n = blockIdx.x * 4 + (threadIdx.x >> 6);
    if (n >= Nn) return;
    int l = threadIdx.x & 63;
    int h = l >> 4;
    const float scl = 0.17677669529663687f;

    float m = -3.0e38f, d = 0.f, a0 = 0.f, a1 = 0.f;

    auto upd = [&](float s, unsigned vu) {
        float nm = fmaxf(m, s);
        float sc = __expf(m - nm), w = __expf(s - nm);
        d = d * sc + w;
        a0 = fmaf(w, bf2f((bfu)vu), a0 * sc);
        a1 = fmaf(w, bf2f((bfu)(vu >> 16)), a1 * sc);
        m = nm;
    };

    // ---- relation A ----
    {
        unsigned qu = *(const unsigned*)(QAA + (size_t)n * 128 + 2 * l);
        float q0 = bf2f((bfu)qu), q1 = bf2f((bfu)(qu >> 16));
        float ph = prlA[h] * scl;
        int i = rpA[n], e1 = rpA[n + 1];
        for (; i + 1 < e1; i += 2) {
            int sa = sidx[i], sb = sidx[i + 1];
            unsigned ka = *(const unsigned*)(KA + (size_t)sa * 128 + 2 * l);
            unsigned kb = *(const unsigned*)(KA + (size_t)sb * 128 + 2 * l);
            unsigned va = *(const unsigned*)(VMA + (size_t)sa * 128 + 2 * l);
            unsigned vb = *(const unsigned*)(VMA + (size_t)sb * 128 + 2 * l);
            float s0 = fmaf(bf2f((bfu)ka), q0, bf2f((bfu)(ka >> 16)) * q1);
            float s1 = fmaf(bf2f((bfu)kb), q0, bf2f((bfu)(kb >> 16)) * q1);
            #pragma unroll
            for (int off = 1; off <= 8; off <<= 1) {
                s0 += __shfl_xor(s0, off);
                s1 += __shfl_xor(s1, off);
            }
            upd(s0 * ph, va);
            upd(s1 * ph, vb);
        }
        if (i < e1) {
            int sa = sidx[i];
            unsigned ka = *(const unsigned*)(KA + (size_t)sa * 128 + 2 * l);
            unsigned va = *(const unsigned*)(VMA + (size_t)sa * 128 + 2 * l);
            float s0 = fmaf(bf2f((bfu)ka), q0, bf2f((bfu)(ka >> 16)) * q1);
            #pragma unroll
            for (int off = 1; off <= 8; off <<= 1) s0 += __shfl_xor(s0, off);
            upd(s0 * ph, va);
        }
    }
    // ---- relation B (same chain continues) ----
    {
        unsigned qu = *(const unsigned*)(QAB + (size_t)n * 128 + 2 * l);
        float q0 = bf2f((bfu)qu), q1 = bf2f((bfu)(qu >> 16));
        float ph = prlB[h] * scl;
        int i = rpB[n], e1 = rpB[n + 1];
        for (; i + 1 < e1; i += 2) {
            int sa = sidx[i], sb = sidx[i + 1];
            unsigned ka = *(const unsigned*)(KB + (size_t)sa * 128 + 2 * l);
            unsigned kb = *(const unsigned*)(KB + (size_t)sb * 128 + 2 * l);
            unsigned va = *(const unsigned*)(VMB + (size_t)sa * 128 + 2 * l);
            unsigned vb = *(const unsigned*)(VMB + (size_t)sb * 128 + 2 * l);
            float s0 = fmaf(bf2f((bfu)ka), q0, bf2f((bfu)(ka >> 16)) * q1);
            float s1 = fmaf(bf2f((bfu)kb), q0, bf2f((bfu)(kb >> 16)) * q1);
            #pragma unroll
            for (int off = 1; off <= 8; off <<= 1) {
                s0 += __shfl_xor(s0, off);
                s1 += __shfl_xor(s1, off);
            }
            upd(s0 * ph, va);
            upd(s1 * ph, vb);
        }
        if (i < e1) {
            int sa = sidx[i];
            unsigned ka = *(const unsigned*)(KB + (size_t)sa * 128 + 2 * l);
            unsigned va = *(const unsigned*)(VMB + (size_t)sa * 128 + 2 * l);
            float s0 = fmaf(bf2f((bfu)ka), q0, bf2f((bfu)(ka >> 16)) * q1);
            #pragma unroll
            for (int off = 1; off <= 8; off <<= 1) s0 += __shfl_xor(s0, off);
            upd(s0 * ph, va);
        }
    }
    float rd = 1.f / fmaxf(d, 1e-16f);
    float y0 = gelu_f(a0 * rd);
    float y1 = gelu_f(a1 * rd);
    unsigned ou = ((unsigned)f2bf(y0)) | (((unsigned)f2bf(y1)) << 16);
    *(unsigned*)(ACC + (size_t)n * 128 + 2 * l) = ou;
}

// ---- layer epilogue: plain A (already gelu'd); out-proj; skip+LN+relu; bf16 out ----
__global__ __launch_bounds__(256) void mgemm_epi_layer(
    const bfu* __restrict__ A, const bfu* __restrict__ W, const float* __restrict__ bias,
    const bfu* __restrict__ Xr, const float* __restrict__ skp,
    const float* __restrict__ g, const float* __restrict__ bb,
    bfu* __restrict__ Y, int N)
{
    const int tid = threadIdx.x;
    const int wave = tid >> 6, lane = tid & 63;
    const int row16 = lane & 15, kgrp = lane >> 4;
    const int r_base = blockIdx.x * 64 + wave * 16;
    const int arow = r_base + row16;
    f4 acc[8];
    #pragma unroll
    for (int n = 0; n < 8; ++n) acc[n] = (f4){0.f, 0.f, 0.f, 0.f};
    bh8 az = {0, 0, 0, 0, 0, 0, 0, 0};
    #pragma unroll
    for (int kb = 0; kb < 4; ++kb) {
        bh8 a = az;
        if (arow < N) a = *(const bh8*)(A + (size_t)arow * 128 + kb * 32 + kgrp * 8);
        #pragma unroll
        for (int n = 0; n < 8; ++n) {
            bh8 bv = *(const bh8*)(W + (size_t)(n * 16 + row16) * 128 + kb * 32 + kgrp * 8);
            acc[n] = __builtin_amdgcn_mfma_f32_16x16x32_bf16(a, bv, acc[n], 0, 0, 0);
        }
    }
    const int crow0 = r_base + kgrp * 4;
    float sg = 1.f / (1.f + expf(-skp[0]));
    float z[8][4];
    #pragma unroll
    for (int n = 0; n < 8; ++n) {
        float bn = bias[n * 16 + row16];
        #pragma unroll
        for (int j = 0; j < 4; ++j) z[n][j] = acc[n][j] + bn;
    }
    #pragma unroll
    for (int j = 0; j < 4; ++j) {
        int row = crow0 + j;
        if (row >= N) continue;
        #pragma unroll
        for (int n = 0; n < 8; ++n) {
            float xr = bf2f(Xr[(size_t)row * 128 + n * 16 + row16]);
            z[n][j] = sg * z[n][j] + (1.f - sg) * xr + xr;
        }
    }
    float s[4], q[4];
    #pragma unroll
    for (int j = 0; j < 4; ++j) {
        s[j] = 0.f; q[j] = 0.f;
        #pragma unroll
        for (int n = 0; n < 8; ++n) { s[j] += z[n][j]; q[j] += z[n][j] * z[n][j]; }
    }
    #pragma unroll
    for (int off = 1; off <= 8; off <<= 1) {
        #pragma unroll
        for (int j = 0; j < 4; ++j) {
            s[j] += __shfl_xor(s[j], off);
            q[j] += __shfl_xor(q[j], off);
        }
    }
    #pragma unroll
    for (int j = 0; j < 4; ++j) {
        int row = crow0 + j;
        if (row >= N) continue;
        float mean = s[j] * (1.f / 128.f);
        float var = q[j] * (1.f / 128.f) - mean * mean;
        float inv = rsqrtf(var + 1e-5f);
        #pragma unroll
        for (int n = 0; n < 8; ++n) {
            int col = n * 16 + row16;
            float y = (z[n][j] - mean) * inv * g[col] + bb[col];
            Y[(size_t)row * 128 + col] = f2bf(fmaxf(y, 0.f));
        }
    }
}

// ---- fusion final: out-proj; LN; f32 out ----
__global__ __launch_bounds__(256) void mgemm_epi_ln(
    const bfu* __restrict__ X, const bfu* __restrict__ W, const float* __restrict__ bias,
    const float* __restrict__ g, const float* __restrict__ bb,
    float* __restrict__ Y, int N)
{
    const int tid = threadIdx.x;
    const int wave = tid >> 6, lane = tid & 63;
    const int row16 = lane & 15, kgrp = lane >> 4;
    const int r_base = blockIdx.x * 64 + wave * 16;
    const int arow = r_base + row16;
    f4 acc[8];
    #pragma unroll
    for (int n = 0; n < 8; ++n) acc[n] = (f4){0.f, 0.f, 0.f, 0.f};
    bh8 az = {0, 0, 0, 0, 0, 0, 0, 0};
    #pragma unroll
    for (int kb = 0; kb < 4; ++kb) {
        bh8 a = az;
        if (arow < N) a = *(const bh8*)(X + (size_t)arow * 128 + kb * 32 + kgrp * 8);
        #pragma unroll
        for (int n = 0; n < 8; ++n) {
            bh8 bv = *(const bh8*)(W + (size_t)(n * 16 + row16) * 128 + kb * 32 + kgrp * 8);
            acc[n] = __builtin_amdgcn_mfma_f32_16x16x32_bf16(a, bv, acc[n], 0, 0, 0);
        }
    }
    const int crow0 = r_base + kgrp * 4;
    float z[8][4];
    #pragma unroll
    for (int n = 0; n < 8; ++n) {
        float bn = bias[n * 16 + row16];
        #pragma unroll
        for (int j = 0; j < 4; ++j) z[n][j] = acc[n][j] + bn;
    }
    float s[4], q[4];
    #pragma unroll
    for (int j = 0; j < 4; ++j) {
        s[j] = 0.f; q[j] = 0.f;
        #pragma unroll
        for (int n = 0; n < 8; ++n) { s[j] += z[n][j]; q[j] += z[n][j] * z[n][j]; }
    }
    #pragma unroll
    for (int off = 1; off <= 8; off <<= 1) {
        #pragma unroll
        for (int j = 0; j < 4; ++j) {
            s[j] += __shfl_xor(s[j], off);
            q[j] += __shfl_xor(q[j], off);
        }
    }
    #pragma unroll
    for (int j = 0; j < 4; ++j) {
        int row = crow0 + j;
        if (row >= N) continue;
        float mean = s[j] * (1.f / 128.f);
        float var = q[j] * (1.f / 128.f) - mean * mean;
        float inv = rsqrtf(var + 1e-5f);
        #pragma unroll
        for (int n = 0; n < 8; ++n) {
            int col = n * 16 + row16;
            Y[(size_t)row * 128 + col] = (z[n][j] - mean) * inv * g[col] + bb[col];
        }
    }
}

// ---- fusion attention (3 tokens, 4 heads), wave per node, bf16 out ----
__global__ __launch_bounds__(256) void attn_fuse(
    const bfu* __restrict__ QKV, bfu* __restrict__ OM, int M)
{
    int n = blockIdx.x * 4 + (threadIdx.x >> 6);
    int l = threadIdx.x & 63;
    if (n >= M) return;
    const bfu* base = QKV + (size_t)n * 1152;
    float q[3][2], k[3][2], v[3][2];
    #pragma unroll
    for (int p = 0; p < 3; ++p) {
        q[p][0] = bf2f(base[(0 * 3 + p) * 128 + l]);
        q[p][1] = bf2f(base[(0 * 3 + p) * 128 + l + 64]);
        k[p][0] = bf2f(base[(1 * 3 + p) * 128 + l]);
        k[p][1] = bf2f(base[(1 * 3 + p) * 128 + l + 64]);
        v[p][0] = bf2f(base[(2 * 3 + p) * 128 + l]);
        v[p][1] = bf2f(base[(2 * 3 + p) * 128 + l + 64]);
    }
    float lgA[3][3], lgB[3][3];
    #pragma unroll
    for (int qi = 0; qi < 3; ++qi)
        #pragma unroll
        for (int ki = 0; ki < 3; ++ki) {
            float s0 = q[qi][0] * k[ki][0];
            float s1 = q[qi][1] * k[ki][1];
            #pragma unroll
            for (int off = 1; off <= 16; off <<= 1) {
                s0 += __shfl_xor(s0, off);
                s1 += __shfl_xor(s1, off);
            }
            lgA[qi][ki] = s0 * 0.17677669529663687f;
            lgB[qi][ki] = s1 * 0.17677669529663687f;
        }
    float oA = 0.f, oB = 0.f;
    #pragma unroll
    for (int qi = 0; qi < 3; ++qi) {
        float mA = fmaxf(lgA[qi][0], fmaxf(lgA[qi][1], lgA[qi][2]));
        float e0 = __expf(lgA[qi][0] - mA), e1 = __expf(lgA[qi][1] - mA), e2 = __expf(lgA[qi][2] - mA);
        float rd = 1.f / (e0 + e1 + e2);
        oA += (e0 * v[0][0] + e1 * v[1][0] + e2 * v[2][0]) * rd;
        float mB = fmaxf(lgB[qi][0], fmaxf(lgB[qi][1], lgB[qi][2]));
        float f0 = __expf(lgB[qi][0] - mB), f1 = __expf(lgB[qi][1] - mB), f2 = __expf(lgB[qi][2] - mB);
        float rdB = 1.f / (f0 + f1 + f2);
        oB += (f0 * v[0][1] + f1 * v[1][1] + f2 * v[2][1]) * rdB;
    }
    OM[(size_t)n * 128 + l] = f2bf(oA * (1.f / 3.f));
    OM[(size_t)n * 128 + l + 64] = f2bf(oB * (1.f / 3.f));
}

extern "C" void kernel_launch(void* const* d_in, const int* in_sizes, int n_in,
                              void* d_out, int out_size, void* d_ws, size_t ws_size,
                              hipStream_t stream)
{
    const float* x_pest   = (const float*)d_in[0];
    const float* x_dis    = (const float*)d_in[1];
    const float* x_plant  = (const float*)d_in[2];
    const int*   edges    = (const int*)d_in[3];
    const float* proj_W   = (const float*)d_in[4];
    const float* proj_b   = (const float*)d_in[5];
    const float* event_emb= (const float*)d_in[6];
    const float* kqv_W    = (const float*)d_in[7];
    const float* kqv_b    = (const float*)d_in[8];
    const float* out_W    = (const float*)d_in[9];
    const float* out_b    = (const float*)d_in[10];
    const float* skip     = (const float*)d_in[11];
    const float* a_rel    = (const float*)d_in[12];
    const float* m_rel    = (const float*)d_in[13];
    const float* p_rel    = (const float*)d_in[14];
    const float* blk_ln_g = (const float*)d_in[15];
    const float* blk_ln_b = (const float*)d_in[16];
    const float* fin_W    = (const float*)d_in[17];
    const float* fin_b    = (const float*)d_in[18];
    const float* fout_W   = (const float*)d_in[19];
    const float* fout_b   = (const float*)d_in[20];
    const float* f_ln_g   = (const float*)d_in[21];
    const float* f_ln_b   = (const float*)d_in[22];
    float* out = (float*)d_out;

    static const int NT[4]  = {30000, 20000, 25000, 50000};
    static const int OFF[4] = {0, 30000, 50000, 75000};
    static const int RPOFF[9] = {0, 20001, 50002, 70003, 95004, 125005, 175006, 200007, 250008};
    static const int DG[4][2][2] = { {{1,1},{4,3}}, {{0,0},{2,2}}, {{3,1},{6,3}}, {{5,0},{7,2}} };

    char* wsb = (char*)d_ws;
    size_t ob = 0;
    auto alc = [&](size_t bytes) -> void* {
        void* p = wsb + ob; ob += (bytes + 255) & ~(size_t)255; return p;
    };
    bfu* LK0  = (bfu*)alc((size_t)75000 * 128 * 2);
    bfu* LK1  = (bfu*)alc((size_t)75000 * 128 * 2);
    bfu* POOL = (bfu*)alc((size_t)210000 * 128 * 2);   // QA_A/QA_B/K/VM pool; fusion QKV; CUR
    bfu* WQAB = (bfu*)alc((size_t)8 * 16384 * 2);
    float* BQA = (float*)alc((size_t)8 * 128 * 4);
    bfu* WVMB = (bfu*)alc((size_t)8 * 16384 * 2);
    float* BVM = (float*)alc((size_t)8 * 128 * 4);
    bfu* KWB  = (bfu*)alc((size_t)12 * 16384 * 2);
    bfu* OWB  = (bfu*)alc((size_t)12 * 16384 * 2);
    bfu* FINWB = (bfu*)alc((size_t)3 * 49152 * 2);
    bfu* FOUTWB = (bfu*)alc((size_t)3 * 16384 * 2);
    int* RP   = (int*)alc((size_t)250008 * 4);
    int* PART = (int*)alc(1024);
    u16* SIDX = (u16*)alc((size_t)8 * E_CNT * 2);
    if (ws_size < ob) {
        fill_val<<<(out_size + 255) / 256, 256, 0, stream>>>(out, out_size, 1e30f);
        return;
    }
    int* CUR = (int*)POOL;       // CSR counters (1.6MB), used before pool
    bfu* QKVf = POOL;            // fusion QKV (CH*1152*2 <= 46.08MB <= 53.76MB)
    bfu* OMB  = POOL + (size_t)20000 * 1152;  // attn out (5.12MB, ends at 51.2MB)

    // d_out overlay (time-disjoint): EVB [0,12.8M); XB [12.8,32.0M); L2F [19.2,38.4M)
    bfu* EVB = (bfu*)out;
    bfu* XB  = (bfu*)((char*)out + 12800000);
    bfu* L2F = (bfu*)((char*)out + 19200000);

    cvt_pack<<<(1747456 + 255) / 256, 256, 0, stream>>>(
        out_W, kqv_W, fin_W, fout_W, event_emb, OWB, KWB, FINWB, FOUTWB, EVB);

    // ---- CSR build ----
    hipMemsetAsync(RP, 0, (size_t)250008 * 4, stream);
    const int eg8 = (8 * E_CNT + 255) / 256;
    hist_all<<<eg8, 256, 0, stream>>>(edges, RP);
    scan_part<<<245, 1024, 0, stream>>>(RP, PART, 250008);
    scan_tot<<<1, 256, 0, stream>>>(PART, 245);
    scan_add<<<244, 1024, 0, stream>>>(RP, PART, 250008);
    hipMemsetAsync(CUR, 0, (size_t)8 * 50000 * 4, stream);
    scatter_all<<<eg8, 256, 0, stream>>>(edges, RP, CUR, SIDX);

    // ---- input projections ----
    const float* xin0[3] = {x_pest, x_dis, x_plant};
    for (int t = 0; t < 3; ++t) {
        proj_gemm<<<(NT[t] + 31) / 32, 256, 0, stream>>>(
            xin0[t], proj_W + (size_t)t * 8192, proj_b + (size_t)t * 128,
            XB + (size_t)OFF[t] * 128, NT[t]);
    }

    auto launch_batch = [&](GDesc* ds, int cnt) {
        GBatch gb;
        int acc = 0;
        for (int i = 0; i < cnt; ++i) {
            gb.d[i] = ds[i];
            acc += (ds[i].N + 127) / 128;
            gb.d[i].bend = acc;
        }
        for (int i = cnt; i < 9; ++i) { gb.d[i] = gb.d[cnt - 1]; gb.d[i].bend = acc; }
        mgemm_batch<<<acc, 256, 0, stream>>>(gb);
    };

    for (int l = 0; l < 3; ++l) {
        const float* kqvW_l = kqv_W + (size_t)l * 12 * 16384;
        const float* kqvb_l = kqv_b + (size_t)l * 12 * 128;
        build_rel<<<64, 256, 0, stream>>>(kqvW_l, kqvb_l,
            a_rel + (size_t)l * 8 * 4096, m_rel + (size_t)l * 8 * 4096,
            WQAB, BQA, WVMB, BVM);

        auto feat_ptr = [&](int tt) -> const bfu* {
            if (tt == 3) return EVB;
            if (l == 0) return XB + (size_t)OFF[tt] * 128;
            return (l == 1 ? LK0 : LK1) + (size_t)OFF[tt] * 128;
        };

        int nord = (l == 2) ? 3 : 4;
        for (int dt = 0; dt < nord; ++dt) {
            int Ndt = NT[dt];
            int rA = DG[dt][0][0], sA = DG[dt][0][1];
            int rB = DG[dt][1][0], sB = DG[dt][1][1];
            int NsA = NT[sA], NsB = NT[sB];
            // pool layout (rows of 128 bf16): QA_A | QA_B | K_A | VM_A | K_B | VM_B
            bfu* QA_A = POOL;
            bfu* QA_B = QA_A + (size_t)Ndt * 128;
            bfu* K_A  = QA_B + (size_t)Ndt * 128;
            bfu* VM_A = K_A + (size_t)NsA * 128;
            bfu* K_B  = VM_A + (size_t)NsA * 128;
            bfu* VM_B = K_B + (size_t)NsB * 128;

            GDesc ds[6];
            ds[0] = { feat_ptr(dt), WQAB + (size_t)rA * 16384, BQA + (size_t)rA * 128, QA_A, Ndt, 128, 0 };
            ds[1] = { feat_ptr(dt), WQAB + (size_t)rB * 16384, BQA + (size_t)rB * 128, QA_B, Ndt, 128, 0 };
            ds[2] = { feat_ptr(sA), KWB + (size_t)(l * 4 + sA) * 16384,
                      kqvb_l + ((size_t)sA * 3 + 0) * 128, K_A, NsA, 128, 0 };
            ds[3] = { feat_ptr(sA), WVMB + (size_t)rA * 16384, BVM + (size_t)rA * 128, VM_A, NsA, 128, 0 };
            ds[4] = { feat_ptr(sB), KWB + (size_t)(l * 4 + sB) * 16384,
                      kqvb_l + ((size_t)sB * 3 + 0) * 128, K_B, NsB, 128, 0 };
            ds[5] = { feat_ptr(sB), WVMB + (size_t)rB * 16384, BVM + (size_t)rB * 128, VM_B, NsB, 128, 0 };
            launch_batch(ds, 6);

            agg_dual<<<(Ndt + 3) / 4, 256, 0, stream>>>(
                QA_A, QA_B, K_A, VM_A, K_B, VM_B,
                RP + RPOFF[rA], RP + RPOFF[rB], SIDX,
                p_rel + (size_t)(l * 8 + rA) * 4, p_rel + (size_t)(l * 8 + rB) * 4,
                QA_A /*ACC alias*/, Ndt);

            size_t wi = (size_t)l * 4 + dt;
            const bfu* xr = feat_ptr(dt);
            bfu* ydst = (dt == 3) ? EVB :
                        (l == 0 ? LK0 : (l == 1 ? LK1 : L2F)) + (size_t)OFF[dt] * 128;
            mgemm_epi_layer<<<(Ndt + 63) / 64, 256, 0, stream>>>(
                QA_A, OWB + wi * 16384, out_b + wi * 128, xr, skip + wi,
                blk_ln_g + (size_t)l * 128, blk_ln_b + (size_t)l * 128, ydst, Ndt);
        }
    }

    // ---- fusion heads ----
    const int CH = 20000;
    for (int j = 0; j < 3; ++j) {
        int Nj = NT[j];
        for (int b0 = 0; b0 < Nj; b0 += CH) {
            int M = min(CH, Nj - b0);
            const bfu* srcs[3] = {
                LK0 + (size_t)(OFF[j] + b0) * 128,
                LK1 + (size_t)(OFF[j] + b0) * 128,
                L2F + (size_t)(OFF[j] + b0) * 128 };
            GDesc ds[9];
            int di = 0;
            for (int kk = 0; kk < 3; ++kk)
                for (int p = 0; p < 3; ++p) {
                    ds[di++] = { srcs[p], FINWB + (size_t)j * 49152 + (size_t)kk * 16384,
                                 fin_b + (size_t)j * 384 + kk * 128,
                                 QKVf + (size_t)(kk * 3 + p) * 128, M, 1152, 0 };
                }
            launch_batch(ds, 9);
            attn_fuse<<<(M + 3) / 4, 256, 0, stream>>>(QKVf, OMB, M);
            mgemm_epi_ln<<<(M + 63) / 64, 256, 0, stream>>>(
                OMB, FOUTWB + (size_t)j * 16384, fout_b + (size_t)j * 128,
                f_ln_g + (size_t)j * 128, f_ln_b + (size_t)j * 128,
                out + (size_t)(OFF[j] + b0) * 128, M);
        }
    }
}